// Round 6
// baseline (657.330 us; speedup 1.0000x reference)
//
#include <hip/hip_runtime.h>
#include <math.h>

#define N_NODES 10000
#define ND 64
#define H 128
#define LAYERS 4
#define KNN 16
#define TD 16
#define E_EDGES (N_NODES * KNN)
#define QSPLIT 4
#define QRANGE 2500  // N_NODES / QSPLIT
#define TILE_E 128   // edges per block in edge_mfma_kernel

typedef __attribute__((ext_vector_type(8))) short short8;
typedef __attribute__((ext_vector_type(4))) float f32x4;

__device__ __forceinline__ float silu(float x) { return x / (1.0f + __expf(-x)); }

__device__ __forceinline__ unsigned short f2bf(float f) {
  unsigned int u = __float_as_uint(f);
  u += 0x7fffu + ((u >> 16) & 1u);  // RNE
  return (unsigned short)(u >> 16);
}
__device__ __forceinline__ float bf2f(unsigned short h) {
  return __uint_as_float(((unsigned int)h) << 16);
}

// ---------------------------------------------------------------------------
// pos4 precompute: [x,y,z, x^2+y^2+z^2] per node
// ---------------------------------------------------------------------------
__global__ __launch_bounds__(256) void pos4_kernel(const float* __restrict__ pos,
                                                   float4* __restrict__ pos4) {
  int i = blockIdx.x * 256 + threadIdx.x;
  if (i >= N_NODES) return;
  float x = pos[i * 3 + 0], y = pos[i * 3 + 1], z = pos[i * 3 + 2];
  pos4[i] = make_float4(x, y, z, x * x + y * y + z * z);
}

// ---------------------------------------------------------------------------
// Weight precast: bf16 transposed copies of ew2, nw1, nw2, ew1 ([l][out][in]).
// ---------------------------------------------------------------------------
__global__ __launch_bounds__(256) void wcvt_kernel(
    const float* __restrict__ ew2, const float* __restrict__ nw1,
    const float* __restrict__ nw2, const float* __restrict__ ew1,
    unsigned short* __restrict__ w2T, unsigned short* __restrict__ nw1T,
    unsigned short* __restrict__ nw2T, unsigned short* __restrict__ ew1T) {
  int i = blockIdx.x * 256 + threadIdx.x;  // 393216 total
  if (i < 65536) {  // w2T: [l][o][c] <- ew2[l][c][o]
    int l = i >> 14, rem = i & 16383, o = rem >> 7, c = rem & 127;
    w2T[i] = f2bf(ew2[l * 16384 + c * 128 + o]);
  } else if (i < 196608) {  // nw1T: [l][o][c2] <- nw1[l][c2][o]
    int j = i - 65536;
    int l = j >> 15, rem = j & 32767, o = rem >> 8, c2 = rem & 255;
    nw1T[j] = f2bf(nw1[l * 32768 + c2 * 128 + o]);
  } else if (i < 262144) {  // nw2T: [l][o][c] <- nw2[l][c][o]
    int j = i - 196608;
    int l = j >> 14, rem = j & 16383, o = rem >> 7, c = rem & 127;
    nw2T[j] = f2bf(nw2[l * 16384 + c * 128 + o]);
  } else {  // ew1T: [l][o(256)][c(128)] <- ew1[l][c + 128*(o>=128)][o&127]
    int j = i - 262144;
    int l = j >> 15, rem = j & 32767, o = rem >> 7, c = rem & 127;
    ew1T[j] = f2bf(ew1[l * 257 * 128 + (c + ((o >> 7) << 7)) * 128 + (o & 127)]);
  }
}

// ---------------------------------------------------------------------------
// KNN: one query per BLOCK; 4 waves each scan a quarter of the candidates
// (streamed from L2, no LDS staging). Each wave keeps a distributed sorted
// top-16 in lanes 0..15; wave 0 merges the 4 sorted lists (quarter-ascending
// order + strict-<-threshold + stay-on-equal preserves lowest-index-wins).
// ---------------------------------------------------------------------------
__global__ __launch_bounds__(256) void knn_kernel(const float4* __restrict__ pos4,
                                                  int* __restrict__ nbr) {
  __shared__ float mvs[QSPLIT][KNN];
  __shared__ int mis[QSPLIT][KNN];
  int tid = threadIdx.x;
  int lane = tid & 63;
  int w = tid >> 6;
  int i = blockIdx.x;
  float4 q = pos4[i];
  float v = __builtin_inff();
  int vid = 0;
  float thresh = __builtin_inff();
  int base = w * QRANGE;
  for (int j0 = 0; j0 < QRANGE; j0 += 64) {
    int jl = base + j0 + lane;
    float d2 = __builtin_inff();
    if (j0 + lane < QRANGE) {
      float4 p = pos4[jl];
      d2 = q.w + p.w - 2.0f * (q.x * p.x + q.y * p.y + q.z * p.z);
      if (jl == i) d2 = __builtin_inff();
    }
    unsigned long long mask = __ballot(d2 < thresh);
    while (mask) {
      int sl = __ffsll((long long)mask) - 1;
      mask &= mask - 1;
      float d2b = __shfl(d2, sl, 64);
      if (d2b >= thresh) continue;  // wave-uniform (thresh tightened)
      int gjb = base + j0 + sl;
      float prevv = __shfl_up(v, 1, 64);
      int previd = __shfl_up(vid, 1, 64);
      bool stay = (v <= d2b);
      bool takenew = (lane == 0) || (prevv <= d2b);
      v = stay ? v : (takenew ? d2b : prevv);
      vid = stay ? vid : (takenew ? gjb : previd);
      thresh = __shfl(v, 15, 64);
    }
  }
  if (w && lane < KNN) { mvs[w][lane] = v; mis[w][lane] = vid; }
  __syncthreads();
  if (w == 0) {
    for (int qtr = 1; qtr < QSPLIT; ++qtr) {
#pragma unroll 1
      for (int k2 = 0; k2 < KNN; ++k2) {
        float d2b = mvs[qtr][k2];
        if (d2b >= thresh) break;  // partner list sorted ascending
        int gjb = mis[qtr][k2];
        float prevv = __shfl_up(v, 1, 64);
        int previd = __shfl_up(vid, 1, 64);
        bool stay = (v <= d2b);
        bool takenew = (lane == 0) || (prevv <= d2b);
        v = stay ? v : (takenew ? d2b : prevv);
        vid = stay ? vid : (takenew ? gjb : previd);
        thresh = __shfl(v, 15, 64);
      }
    }
    if (lane < KNN) nbr[i * KNN + lane] = vid;
  }
}

// ---------------------------------------------------------------------------
// CSR build (deterministic): count -> scan -> scatter(+dstof) -> per-node sort
// ---------------------------------------------------------------------------
__global__ void deg_count_kernel(const int* __restrict__ nbr, int* __restrict__ degi) {
  int e = blockIdx.x * 256 + threadIdx.x;
  if (e < E_EDGES) atomicAdd(&degi[nbr[e]], 1);
}

__global__ __launch_bounds__(1024) void scan_kernel(const int* __restrict__ degi,
                                                    int* __restrict__ off,
                                                    int* __restrict__ cursor) {
  __shared__ int part[1024];
  int t = threadIdx.x;
  int base = t * 10;
  int sum = 0;
  if (t < 1000)
    for (int i = 0; i < 10; ++i) sum += degi[base + i];
  part[t] = sum;
  __syncthreads();
  for (int stp = 1; stp < 1024; stp <<= 1) {
    int v = (t >= stp) ? part[t - stp] : 0;
    __syncthreads();
    part[t] += v;
    __syncthreads();
  }
  if (t < 1000) {
    int run = (t == 0) ? 0 : part[t - 1];
    for (int i = 0; i < 10; ++i) {
      off[base + i] = run;
      cursor[base + i] = run;
      run += degi[base + i];
    }
  }
  if (t == 0) off[N_NODES] = E_EDGES;
}

__global__ void scatter_kernel(const int* __restrict__ nbr, int* __restrict__ cursor,
                               int* __restrict__ eid, int* __restrict__ dstof) {
  int e = blockIdx.x * 256 + threadIdx.x;
  if (e < E_EDGES) {
    int d = nbr[e];
    int p = atomicAdd(&cursor[d], 1);
    eid[p] = e;
    dstof[p] = d;
  }
}

__global__ void sort_kernel(const int* __restrict__ off, int* __restrict__ eid) {
  int n = blockIdx.x * 256 + threadIdx.x;
  if (n >= N_NODES) return;
  int a = off[n], b = off[n + 1];
  for (int i = a + 1; i < b; ++i) {
    int v = eid[i];
    int j = i - 1;
    while (j >= a && eid[j] > v) { eid[j + 1] = eid[j]; --j; }
    eid[j + 1] = v;
  }
}

// ---------------------------------------------------------------------------
// Input projection
// ---------------------------------------------------------------------------
__global__ __launch_bounds__(256) void proj_kernel(const float* __restrict__ x,
                                                   const float* __restrict__ s,
                                                   const float* __restrict__ tptr,
                                                   const float* __restrict__ pw,
                                                   const float* __restrict__ pb,
                                                   float* __restrict__ h) {
  __shared__ float inp[2][81];
  int tid = threadIdx.x;
  int g = tid >> 7;
  int o = tid & 127;
  int node = blockIdx.x * 2 + g;
  float t = tptr[0];
  if (o < 64) inp[g][o] = x[node * ND + o];
  else if (o == 64) inp[g][64] = s[node];
  else if (o < 81) {
    int j = o - 65;
    int jj = (j < 8) ? j : (j - 8);
    float f = __expf(-4.0f * (float)jj / 7.0f);
    float a = t * f;
    inp[g][o] = (j < 8) ? sinf(a) : cosf(a);
  }
  __syncthreads();
  float acc = pb[o];
#pragma unroll
  for (int c = 0; c < 81; ++c) acc = fmaf(inp[g][c], pw[c * H + o], acc);
  h[node * H + o] = acc;
}

// ---------------------------------------------------------------------------
// Layer-0 A/B via MFMA: 16 nodes/block; A=h@ew1[0:128]+eb1, B=h@ew1[128:256].
// Wave w covers out cols [64w, 64w+64) of the 256-wide [A||B] output (bf16).
// ---------------------------------------------------------------------------
__global__ __launch_bounds__(256) void ab_mfma_kernel(
    const float* __restrict__ h, const unsigned short* __restrict__ ew1T,
    const float* __restrict__ eb1, unsigned short* __restrict__ Abf,
    unsigned short* __restrict__ Bbf) {
  __shared__ unsigned short hb[16][136];
  int tid = threadIdx.x;
  int n0 = blockIdx.x * 16;
  for (int idx = tid; idx < 16 * H; idx += 256) {
    int n = idx >> 7, c = idx & 127;
    hb[n][c] = f2bf(h[(n0 + n) * H + c]);
  }
  __syncthreads();
  int w = tid >> 6, lane = tid & 63, fr = lane & 15, kg = lane >> 4;
  f32x4 acc[4];
#pragma unroll
  for (int nt = 0; nt < 4; ++nt) acc[nt] = (f32x4){0.f, 0.f, 0.f, 0.f};
#pragma unroll
  for (int ks = 0; ks < 4; ++ks) {
    int k = ks * 32 + kg * 8;
    short8 a = *(const short8*)&hb[fr][k];
#pragma unroll
    for (int nt = 0; nt < 4; ++nt) {
      int col = w * 64 + nt * 16 + fr;
      short8 b = *(const short8*)&ew1T[col * H + k];
      acc[nt] = __builtin_amdgcn_mfma_f32_16x16x32_bf16(a, b, acc[nt], 0, 0, 0);
    }
  }
#pragma unroll
  for (int nt = 0; nt < 4; ++nt) {
    int col = w * 64 + nt * 16 + fr;
    float bias = (col < H) ? eb1[col] : 0.0f;
#pragma unroll
    for (int r = 0; r < 4; ++r) {
      int row = kg * 4 + r;
      float val = acc[nt][r] + bias;
      if (col < H) Abf[(n0 + row) * H + col] = f2bf(val);
      else Bbf[(n0 + row) * H + (col - H)] = f2bf(val);
    }
  }
}

// ---------------------------------------------------------------------------
// Edge phase, MFMA: 128 CSR positions per block. A/B gathered as bf16.
// ---------------------------------------------------------------------------
__global__ __launch_bounds__(256) void edge_mfma_kernel(
    const unsigned short* __restrict__ Abf, const unsigned short* __restrict__ Bbf,
    const float* __restrict__ p, const float* __restrict__ s,
    const int* __restrict__ csr_off, const int* __restrict__ eid,
    const int* __restrict__ dstof, const float* __restrict__ wr,
    const unsigned short* __restrict__ w2T, const float* __restrict__ eb2,
    const float* __restrict__ cw, const float* __restrict__ cbp,
    float* __restrict__ msA, float* __restrict__ msB,
    float* __restrict__ cuA, float* __restrict__ cuB) {
  __shared__ unsigned short t1s[TILE_E][136];  // t1 (bf16), later reused for m
  __shared__ float r2A[TILE_E], sA[TILE_E], dirA[TILE_E][3], gA[TILE_E];
  __shared__ int srcA[TILE_E], dstA[TILE_E];
  __shared__ float wrs[H], b2s[H], cws[H];

  int tid = threadIdx.x;
  int P0 = blockIdx.x * TILE_E;
  int P1 = P0 + TILE_E;

  if (tid < H) { wrs[tid] = wr[tid]; b2s[tid] = eb2[tid]; cws[tid] = cw[tid]; }
  if (tid < TILE_E) {
    int e = tid;
    int edge = eid[P0 + e];
    int src = edge >> 4;  // edge / KNN
    int d = dstof[P0 + e];
    srcA[e] = src;
    dstA[e] = d;
    float dx = p[d * 3 + 0] - p[src * 3 + 0];
    float dy = p[d * 3 + 1] - p[src * 3 + 1];
    float dz = p[d * 3 + 2] - p[src * 3 + 2];
    float r2 = dx * dx + dy * dy + dz * dz;
    r2A[e] = r2;
    float rinv = 1.0f / sqrtf(r2 + 1e-8f);
    dirA[e][0] = dx * rinv;
    dirA[e][1] = dy * rinv;
    dirA[e][2] = dz * rinv;
    sA[e] = s[src];
  }
  __syncthreads();

  int nA = dstA[0], nB = dstA[TILE_E - 1];
  int nn = nB - nA + 1;

  // stage 1: t1 tile (bf16); 4 cols per thread, coalesced uint2 gathers
  for (int idx = tid; idx < TILE_E * 32; idx += 256) {
    int e = idx >> 5, cp = (idx & 31) * 4;
    uint2 au = *(const uint2*)&Abf[dstA[e] * H + cp];
    uint2 bu = *(const uint2*)&Bbf[srcA[e] * H + cp];
    float r2v = r2A[e];
    float pr0 = silu(bf2f((unsigned short)(au.x & 0xffffu)) +
                     bf2f((unsigned short)(bu.x & 0xffffu)) + r2v * wrs[cp]);
    float pr1 = silu(bf2f((unsigned short)(au.x >> 16)) +
                     bf2f((unsigned short)(bu.x >> 16)) + r2v * wrs[cp + 1]);
    float pr2 = silu(bf2f((unsigned short)(au.y & 0xffffu)) +
                     bf2f((unsigned short)(bu.y & 0xffffu)) + r2v * wrs[cp + 2]);
    float pr3 = silu(bf2f((unsigned short)(au.y >> 16)) +
                     bf2f((unsigned short)(bu.y >> 16)) + r2v * wrs[cp + 3]);
    uint2 o;
    o.x = ((unsigned int)f2bf(pr1) << 16) | (unsigned int)f2bf(pr0);
    o.y = ((unsigned int)f2bf(pr3) << 16) | (unsigned int)f2bf(pr2);
    *(uint2*)&t1s[e][cp] = o;
  }
  __syncthreads();

  // stage 2: GEMM m_pre = t1 @ w2. Wave w -> out cols [w*32, w*32+32).
  int w = tid >> 6, lane = tid & 63;
  int fr = lane & 15, kg = lane >> 4;
  f32x4 acc[8][2];
#pragma unroll
  for (int mt = 0; mt < 8; ++mt)
#pragma unroll
    for (int nt = 0; nt < 2; ++nt) acc[mt][nt] = (f32x4){0.f, 0.f, 0.f, 0.f};
#pragma unroll
  for (int ks = 0; ks < 4; ++ks) {
    int k = ks * 32 + kg * 8;
    short8 bf0 = *(const short8*)&w2T[(w * 32 + fr) * H + k];
    short8 bf1 = *(const short8*)&w2T[(w * 32 + 16 + fr) * H + k];
#pragma unroll
    for (int mt = 0; mt < 8; ++mt) {
      short8 a = *(const short8*)&t1s[mt * 16 + fr][k];
      acc[mt][0] = __builtin_amdgcn_mfma_f32_16x16x32_bf16(a, bf0, acc[mt][0], 0, 0, 0);
      acc[mt][1] = __builtin_amdgcn_mfma_f32_16x16x32_bf16(a, bf1, acc[mt][1], 0, 0, 0);
    }
  }
  __syncthreads();  // all t1s reads done

  // epilogue: m = silu(acc + b2) * s[src] -> back into t1s (bf16)
#pragma unroll
  for (int mt = 0; mt < 8; ++mt) {
#pragma unroll
    for (int nt = 0; nt < 2; ++nt) {
      int col = w * 32 + nt * 16 + fr;
      float b2v = b2s[col];
#pragma unroll
      for (int r = 0; r < 4; ++r) {
        int row = mt * 16 + kg * 4 + r;
        float mv = silu(acc[mt][nt][r] + b2v) * sA[row];
        t1s[row][col] = f2bf(mv);
      }
    }
  }
  __syncthreads();

  // gamma per edge (ascending col order)
  if (tid < TILE_E) {
    float g = 0.f;
    for (int c = 0; c < H; c += 4) {
      uint2 u = *(const uint2*)&t1s[tid][c];
      g = fmaf(bf2f((unsigned short)(u.x & 0xffffu)), cws[c], g);
      g = fmaf(bf2f((unsigned short)(u.x >> 16)), cws[c + 1], g);
      g = fmaf(bf2f((unsigned short)(u.y & 0xffffu)), cws[c + 2], g);
      g = fmaf(bf2f((unsigned short)(u.y >> 16)), cws[c + 3], g);
    }
    gA[tid] = g + cbp[0];
  }
  __syncthreads();

  // per-node partial msum -> slots
  for (int idx = tid; idx < nn * H; idx += 256) {
    int ni = idx >> 7, c = idx & 127;
    int n = nA + ni;
    int o0 = csr_off[n], o1 = csr_off[n + 1];
    int lo = max(o0, P0), hi = min(o1, P1);
    float sum = 0.f;
    for (int pos = lo; pos < hi; ++pos) sum += bf2f(t1s[pos - P0][c]);
    if (o0 >= P0) {
      msA[n * H + c] = sum;
      if (o1 <= P1) msB[n * H + c] = 0.0f;
    } else {
      msB[n * H + c] = sum;
    }
  }
  // per-node partial cu -> slots
  for (int idx = tid; idx < nn * 3; idx += 256) {
    int ni = idx / 3, comp = idx - ni * 3;
    int n = nA + ni;
    int o0 = csr_off[n], o1 = csr_off[n + 1];
    int lo = max(o0, P0), hi = min(o1, P1);
    float sum = 0.f;
    for (int pos = lo; pos < hi; ++pos)
      sum += gA[pos - P0] * dirA[pos - P0][comp];
    if (o0 >= P0) {
      cuA[n * 3 + comp] = sum;
      if (o1 <= P1) cuB[n * 3 + comp] = 0.0f;
    } else {
      cuB[n * 3 + comp] = sum;
    }
  }
}

// ---------------------------------------------------------------------------
// Node update via MFMA: 16 nodes/block, 4 waves.
// GEMM1 (K=256) -> silu -> GEMM2 (K=128) -> h_out; optionally fused A/B GEMM
// (K=128 -> N=256, ew1T of the NEXT layer) writing bf16 Abf/Bbf.
// ---------------------------------------------------------------------------
__global__ __launch_bounds__(256) void node_mfma_kernel(
    const float* __restrict__ h, const float* __restrict__ msA,
    const float* __restrict__ msB, const int* __restrict__ degi,
    const float* __restrict__ cuA, const float* __restrict__ cuB,
    const float* __restrict__ p_in, const unsigned short* __restrict__ w1T,
    const float* __restrict__ nb1, const unsigned short* __restrict__ w2T,
    const float* __restrict__ nb2, const unsigned short* __restrict__ ew1Tn,
    const float* __restrict__ eb1n, int doab, float* __restrict__ h_out,
    float* __restrict__ p_out, unsigned short* __restrict__ Abf,
    unsigned short* __restrict__ Bbf) {
  __shared__ unsigned short insb[16][264];
  __shared__ unsigned short hnsb[16][136];
  int tid = threadIdx.x;
  int n0 = blockIdx.x * 16;
  for (int idx = tid; idx < 16 * H; idx += 256) {
    int n = idx >> 7, c = idx & 127;
    int gn = n0 + n;
    float hv = h[gn * H + c];
    int dg = degi[gn];
    float ms = 0.f;
    if (dg > 0) ms = (msA[gn * H + c] + msB[gn * H + c]) / (float)dg;
    insb[n][c] = f2bf(hv);
    insb[n][H + c] = f2bf(ms);
  }
  __syncthreads();
  int w = tid >> 6, lane = tid & 63, fr = lane & 15, kg = lane >> 4;
  f32x4 acc[2];
  acc[0] = (f32x4){0.f, 0.f, 0.f, 0.f};
  acc[1] = (f32x4){0.f, 0.f, 0.f, 0.f};
#pragma unroll
  for (int ks = 0; ks < 8; ++ks) {
    int k = ks * 32 + kg * 8;
    short8 a = *(const short8*)&insb[fr][k];
#pragma unroll
    for (int nt = 0; nt < 2; ++nt) {
      int col = w * 32 + nt * 16 + fr;
      short8 b = *(const short8*)&w1T[col * 256 + k];
      acc[nt] = __builtin_amdgcn_mfma_f32_16x16x32_bf16(a, b, acc[nt], 0, 0, 0);
    }
  }
#pragma unroll
  for (int nt = 0; nt < 2; ++nt) {
    int col = w * 32 + nt * 16 + fr;
    float b1 = nb1[col];
#pragma unroll
    for (int r = 0; r < 4; ++r) {
      int row = kg * 4 + r;
      hnsb[row][col] = f2bf(silu(acc[nt][r] + b1));
    }
  }
  __syncthreads();
  f32x4 acc2[2];
  acc2[0] = (f32x4){0.f, 0.f, 0.f, 0.f};
  acc2[1] = (f32x4){0.f, 0.f, 0.f, 0.f};
#pragma unroll
  for (int ks = 0; ks < 4; ++ks) {
    int k = ks * 32 + kg * 8;
    short8 a = *(const short8*)&hnsb[fr][k];
#pragma unroll
    for (int nt = 0; nt < 2; ++nt) {
      int col = w * 32 + nt * 16 + fr;
      short8 b = *(const short8*)&w2T[col * H + k];
      acc2[nt] = __builtin_amdgcn_mfma_f32_16x16x32_bf16(a, b, acc2[nt], 0, 0, 0);
    }
  }
  // h_new: global fp32 + bf16 into reused insb region (free after GEMM1 barrier)
  unsigned short (*hb)[136] = (unsigned short(*)[136])insb;
#pragma unroll
  for (int nt = 0; nt < 2; ++nt) {
    int col = w * 32 + nt * 16 + fr;
    float b2 = nb2[col];
#pragma unroll
    for (int r = 0; r < 4; ++r) {
      int row = kg * 4 + r;
      float hv = acc2[nt][r] + b2;
      h_out[(n0 + row) * H + col] = hv;
      hb[row][col] = f2bf(hv);
    }
  }
  if (tid < 48) {
    int nl = tid / 3, comp = tid - nl * 3;
    int gn = n0 + nl;
    int dg = degi[gn];
    float add = 0.0f;
    if (dg > 0)
      add = (cuA[gn * 3 + comp] + cuB[gn * 3 + comp]) / (float)dg;
    p_out[gn * 3 + comp] = p_in[gn * 3 + comp] + add;
  }
  if (doab) {
    __syncthreads();
    f32x4 acc3[4];
#pragma unroll
    for (int nt = 0; nt < 4; ++nt) acc3[nt] = (f32x4){0.f, 0.f, 0.f, 0.f};
#pragma unroll
    for (int ks = 0; ks < 4; ++ks) {
      int k = ks * 32 + kg * 8;
      short8 a = *(const short8*)&hb[fr][k];
#pragma unroll
      for (int nt = 0; nt < 4; ++nt) {
        int col = w * 64 + nt * 16 + fr;
        short8 b = *(const short8*)&ew1Tn[col * H + k];
        acc3[nt] = __builtin_amdgcn_mfma_f32_16x16x32_bf16(a, b, acc3[nt], 0, 0, 0);
      }
    }
#pragma unroll
    for (int nt = 0; nt < 4; ++nt) {
      int col = w * 64 + nt * 16 + fr;
      float bias = (col < H) ? eb1n[col] : 0.0f;
#pragma unroll
      for (int r = 0; r < 4; ++r) {
        int row = kg * 4 + r;
        float val = acc3[nt][r] + bias;
        if (col < H) Abf[(n0 + row) * H + col] = f2bf(val);
        else Bbf[(n0 + row) * H + (col - H)] = f2bf(val);
      }
    }
  }
}

// ---------------------------------------------------------------------------
// Output head
// ---------------------------------------------------------------------------
__global__ __launch_bounds__(256) void out_kernel(
    const float* __restrict__ h, const float* __restrict__ p,
    const float* __restrict__ ecw, const float* __restrict__ ecb,
    const float* __restrict__ efw, const float* __restrict__ efb,
    float* __restrict__ out) {
  __shared__ float hs[32][H];
  int tid = threadIdx.x, n0 = blockIdx.x * 32;
  for (int idx = tid; idx < 32 * H; idx += 256) {
    int n = idx >> 7, c = idx & 127;
    int gn = n0 + n;
    hs[n][c] = (gn < N_NODES) ? h[gn * H + c] : 0.0f;
  }
  __syncthreads();
  for (int f = tid; f < 32 * 70; f += 256) {
    int nl = f / 70, j = f % 70;
    int gn = n0 + nl;
    if (gn >= N_NODES) continue;
    float v;
    if (j < 3) {
      v = ecb[j];
      for (int c = 0; c < H; ++c) v = fmaf(hs[nl][c], ecw[c * 3 + j], v);
    } else if (j < 67) {
      int jj = j - 3;
      v = efb[jj];
      for (int c = 0; c < H; ++c) v = fmaf(hs[nl][c], efw[c * ND + jj], v);
    } else {
      v = p[gn * 3 + (j - 67)];
    }
    out[gn * 70 + j] = v;
  }
}

// ---------------------------------------------------------------------------
extern "C" void kernel_launch(void* const* d_in, const int* in_sizes, int n_in,
                              void* d_out, int out_size, void* d_ws, size_t ws_size,
                              hipStream_t stream) {
  const float* x = (const float*)d_in[0];
  const float* pos = (const float*)d_in[1];
  const float* t = (const float*)d_in[2];
  const float* s = (const float*)d_in[3];
  const float* pw = (const float*)d_in[4];
  const float* pb = (const float*)d_in[5];
  const float* ew1 = (const float*)d_in[6];
  const float* eb1 = (const float*)d_in[7];
  const float* ew2 = (const float*)d_in[8];
  const float* eb2 = (const float*)d_in[9];
  const float* nw1 = (const float*)d_in[10];
  const float* nb1 = (const float*)d_in[11];
  const float* nw2 = (const float*)d_in[12];
  const float* nb2 = (const float*)d_in[13];
  const float* cw = (const float*)d_in[14];
  const float* cb = (const float*)d_in[15];
  const float* ecw = (const float*)d_in[16];
  const float* ecb = (const float*)d_in[17];
  const float* efw = (const float*)d_in[18];
  const float* efb = (const float*)d_in[19];

  char* wp = (char*)d_ws;
  auto alloc = [&](size_t bytes) {
    char* r = wp;
    wp += (bytes + 255) & ~(size_t)255;
    return r;
  };
  float* h0 = (float*)alloc((size_t)N_NODES * H * 4);
  float* h1 = (float*)alloc((size_t)N_NODES * H * 4);
  unsigned short* Abf = (unsigned short*)alloc((size_t)N_NODES * H * 2);
  unsigned short* Bbf = (unsigned short*)alloc((size_t)N_NODES * H * 2);
  float* msAb = (float*)alloc((size_t)N_NODES * H * 4);
  float* msBb = (float*)alloc((size_t)N_NODES * H * 4);
  float* cuAb = (float*)alloc((size_t)N_NODES * 3 * 4);
  float* cuBb = (float*)alloc((size_t)N_NODES * 3 * 4);
  float* p0 = (float*)alloc((size_t)N_NODES * 3 * 4);
  float* p1 = (float*)alloc((size_t)N_NODES * 3 * 4);
  int* degi = (int*)alloc((size_t)N_NODES * 4);
  int* nbr = (int*)alloc((size_t)E_EDGES * 4);
  int* off = (int*)alloc((size_t)(N_NODES + 1) * 4);
  int* cursor = (int*)alloc((size_t)N_NODES * 4);
  int* eid = (int*)alloc((size_t)E_EDGES * 4);
  int* dstof = (int*)alloc((size_t)E_EDGES * 4);
  unsigned short* w2Tb = (unsigned short*)alloc((size_t)LAYERS * H * H * 2);
  unsigned short* nw1Tb = (unsigned short*)alloc((size_t)LAYERS * 2 * H * H * 2);
  unsigned short* nw2Tb = (unsigned short*)alloc((size_t)LAYERS * H * H * 2);
  unsigned short* ew1Tb = (unsigned short*)alloc((size_t)LAYERS * 2 * H * H * 2);

  // pos4 aliases msAb (first written by edge_mfma, after KNN is done)
  float4* pos4 = (float4*)msAb;

  hipMemsetAsync(degi, 0, (size_t)N_NODES * 4, stream);
  wcvt_kernel<<<1536, 256, 0, stream>>>(ew2, nw1, nw2, ew1, w2Tb, nw1Tb, nw2Tb, ew1Tb);
  pos4_kernel<<<(N_NODES + 255) / 256, 256, 0, stream>>>(pos, pos4);
  knn_kernel<<<N_NODES, 256, 0, stream>>>(pos4, nbr);
  deg_count_kernel<<<(E_EDGES + 255) / 256, 256, 0, stream>>>(nbr, degi);
  scan_kernel<<<1, 1024, 0, stream>>>(degi, off, cursor);
  scatter_kernel<<<(E_EDGES + 255) / 256, 256, 0, stream>>>(nbr, cursor, eid, dstof);
  sort_kernel<<<(N_NODES + 255) / 256, 256, 0, stream>>>(off, eid);
  hipMemcpyAsync(p0, pos, (size_t)N_NODES * 3 * 4, hipMemcpyDeviceToDevice, stream);
  proj_kernel<<<N_NODES / 2, 256, 0, stream>>>(x, s, t, pw, pb, h0);
  ab_mfma_kernel<<<N_NODES / 16, 256, 0, stream>>>(h0, ew1Tb, eb1, Abf, Bbf);

  float* hc = h0;
  float* hn = h1;
  float* pc = p0;
  float* pn = p1;
  for (int l = 0; l < LAYERS; ++l) {
    const float* ew1l = ew1 + (size_t)l * 257 * H;
    int doab = (l < LAYERS - 1) ? 1 : 0;
    edge_mfma_kernel<<<E_EDGES / TILE_E, 256, 0, stream>>>(
        Abf, Bbf, pc, s, off, eid, dstof, ew1l + 256 * H,
        w2Tb + (size_t)l * H * H, eb2 + l * H, cw + l * H, cb + l,
        msAb, msBb, cuAb, cuBb);
    node_mfma_kernel<<<N_NODES / 16, 256, 0, stream>>>(
        hc, msAb, msBb, degi, cuAb, cuBb, pc, nw1Tb + (size_t)l * 2 * H * H,
        nb1 + l * H, nw2Tb + (size_t)l * H * H, nb2 + l * H,
        ew1Tb + (size_t)(l + doab) * 2 * H * H, eb1 + (size_t)(l + doab) * H,
        doab, hn, pn, Abf, Bbf);
    float* tmp = hc; hc = hn; hn = tmp;
    tmp = pc; pc = pn; pn = tmp;
  }
  out_kernel<<<(N_NODES + 31) / 32, 256, 0, stream>>>(hc, pc, ecw, ecb, efw, efb,
                                                      (float*)d_out);
}

// Round 7
// 552.217 us; speedup vs baseline: 1.1903x; 1.1903x over previous
//
#include <hip/hip_runtime.h>
#include <math.h>

#define N_NODES 10000
#define ND 64
#define H 128
#define LAYERS 4
#define KNN 16
#define TD 16
#define E_EDGES (N_NODES * KNN)
#define KC 1250    // knn candidates per LDS chunk (20 KB)
#define TILE_E 128 // edges per block in edge_mfma_kernel

typedef __attribute__((ext_vector_type(8))) short short8;
typedef __attribute__((ext_vector_type(4))) float f32x4;

__device__ __forceinline__ float silu(float x) { return x / (1.0f + __expf(-x)); }

__device__ __forceinline__ unsigned short f2bf(float f) {
  unsigned int u = __float_as_uint(f);
  u += 0x7fffu + ((u >> 16) & 1u);  // RNE
  return (unsigned short)(u >> 16);
}
__device__ __forceinline__ float bf2f(unsigned short h) {
  return __uint_as_float(((unsigned int)h) << 16);
}

// ---------------------------------------------------------------------------
// pos4 precompute: [x,y,z,|p|^2]; also copies pos->p0 and zeroes degi
// (folds the old memcpy + memset dispatches into this kernel).
// ---------------------------------------------------------------------------
__global__ __launch_bounds__(256) void pos4_kernel(const float* __restrict__ pos,
                                                   float4* __restrict__ pos4,
                                                   float* __restrict__ p0,
                                                   int* __restrict__ degi) {
  int i = blockIdx.x * 256 + threadIdx.x;
  if (i >= N_NODES) return;
  float x = pos[i * 3 + 0], y = pos[i * 3 + 1], z = pos[i * 3 + 2];
  pos4[i] = make_float4(x, y, z, x * x + y * y + z * z);
  p0[i * 3 + 0] = x;
  p0[i * 3 + 1] = y;
  p0[i * 3 + 2] = z;
  degi[i] = 0;
}

// ---------------------------------------------------------------------------
// Weight precast: bf16 transposed copies of ew2, nw1, nw2, ew1 ([l][out][in]).
// ---------------------------------------------------------------------------
__global__ __launch_bounds__(256) void wcvt_kernel(
    const float* __restrict__ ew2, const float* __restrict__ nw1,
    const float* __restrict__ nw2, const float* __restrict__ ew1,
    unsigned short* __restrict__ w2T, unsigned short* __restrict__ nw1T,
    unsigned short* __restrict__ nw2T, unsigned short* __restrict__ ew1T) {
  int i = blockIdx.x * 256 + threadIdx.x;  // 393216 total
  if (i < 65536) {  // w2T: [l][o][c] <- ew2[l][c][o]
    int l = i >> 14, rem = i & 16383, o = rem >> 7, c = rem & 127;
    w2T[i] = f2bf(ew2[l * 16384 + c * 128 + o]);
  } else if (i < 196608) {  // nw1T: [l][o][c2] <- nw1[l][c2][o]
    int j = i - 65536;
    int l = j >> 15, rem = j & 32767, o = rem >> 8, c2 = rem & 255;
    nw1T[j] = f2bf(nw1[l * 32768 + c2 * 128 + o]);
  } else if (i < 262144) {  // nw2T: [l][o][c] <- nw2[l][c][o]
    int j = i - 196608;
    int l = j >> 14, rem = j & 16383, o = rem >> 7, c = rem & 127;
    nw2T[j] = f2bf(nw2[l * 16384 + c * 128 + o]);
  } else {  // ew1T: [l][o(256)][c(128)] <- ew1[l][c + 128*(o>=128)][o&127]
    int j = i - 262144;
    int l = j >> 15, rem = j & 32767, o = rem >> 7, c = rem & 127;
    ew1T[j] = f2bf(ew1[l * 257 * 128 + (c + ((o >> 7) << 7)) * 128 + (o & 127)]);
  }
}

// ---------------------------------------------------------------------------
// KNN, wave-cooperative (round-5 proven form): one query per wave (4/block).
// Top-16 distributed in lanes 0..15 (sorted). LDS-staged 1250-candidate
// chunks. Strict-<-threshold + stay-on-equal + ascending scan order preserves
// lowest-index-wins ties. Also accumulates in-degree (fused deg_count).
// ---------------------------------------------------------------------------
__global__ __launch_bounds__(256) void knn_kernel(const float4* __restrict__ pos4,
                                                  int* __restrict__ nbr,
                                                  int* __restrict__ degi) {
  __shared__ float4 C[KC];
  int tid = threadIdx.x;
  int lane = tid & 63;
  int wid = tid >> 6;
  int i = blockIdx.x * 4 + wid;
  float4 q = pos4[i];
  float v = __builtin_inff();
  int vid = 0;
  float thresh = __builtin_inff();
  for (int base = 0; base < N_NODES; base += KC) {
    int cnt = min(KC, N_NODES - base);
    __syncthreads();
    for (int jj = tid; jj < cnt; jj += 256) C[jj] = pos4[base + jj];
    __syncthreads();
    for (int j0 = 0; j0 < cnt; j0 += 64) {
      int jl = j0 + lane;
      float d2 = __builtin_inff();
      if (jl < cnt) {
        float4 p = C[jl];
        d2 = q.w + p.w - 2.0f * (q.x * p.x + q.y * p.y + q.z * p.z);
        if (base + jl == i) d2 = __builtin_inff();
      }
      unsigned long long mask = __ballot(d2 < thresh);
      while (mask) {
        int sl = __ffsll((long long)mask) - 1;
        mask &= mask - 1;
        float d2b = __shfl(d2, sl, 64);
        if (d2b >= thresh) continue;  // wave-uniform (thresh tightened)
        int gjb = base + j0 + sl;
        float prevv = __shfl_up(v, 1, 64);
        int previd = __shfl_up(vid, 1, 64);
        bool stay = (v <= d2b);
        bool takenew = (lane == 0) || (prevv <= d2b);
        v = stay ? v : (takenew ? d2b : prevv);
        vid = stay ? vid : (takenew ? gjb : previd);
        thresh = __shfl(v, 15, 64);
      }
    }
  }
  if (lane < KNN) {
    nbr[i * KNN + lane] = vid;
    atomicAdd(&degi[vid], 1);
  }
}

// ---------------------------------------------------------------------------
// CSR build (deterministic): scan -> scatter(+dstof) -> per-node sort
// ---------------------------------------------------------------------------
__global__ __launch_bounds__(1024) void scan_kernel(const int* __restrict__ degi,
                                                    int* __restrict__ off,
                                                    int* __restrict__ cursor) {
  __shared__ int part[1024];
  int t = threadIdx.x;
  int base = t * 10;
  int sum = 0;
  if (t < 1000)
    for (int i = 0; i < 10; ++i) sum += degi[base + i];
  part[t] = sum;
  __syncthreads();
  for (int stp = 1; stp < 1024; stp <<= 1) {
    int v = (t >= stp) ? part[t - stp] : 0;
    __syncthreads();
    part[t] += v;
    __syncthreads();
  }
  if (t < 1000) {
    int run = (t == 0) ? 0 : part[t - 1];
    for (int i = 0; i < 10; ++i) {
      off[base + i] = run;
      cursor[base + i] = run;
      run += degi[base + i];
    }
  }
  if (t == 0) off[N_NODES] = E_EDGES;
}

__global__ void scatter_kernel(const int* __restrict__ nbr, int* __restrict__ cursor,
                               int* __restrict__ eid, int* __restrict__ dstof) {
  int e = blockIdx.x * 256 + threadIdx.x;
  if (e < E_EDGES) {
    int d = nbr[e];
    int p = atomicAdd(&cursor[d], 1);
    eid[p] = e;
    dstof[p] = d;
  }
}

__global__ void sort_kernel(const int* __restrict__ off, int* __restrict__ eid) {
  int n = blockIdx.x * 256 + threadIdx.x;
  if (n >= N_NODES) return;
  int a = off[n], b = off[n + 1];
  for (int i = a + 1; i < b; ++i) {
    int v = eid[i];
    int j = i - 1;
    while (j >= a && eid[j] > v) { eid[j + 1] = eid[j]; --j; }
    eid[j + 1] = v;
  }
}

// ---------------------------------------------------------------------------
// Input projection
// ---------------------------------------------------------------------------
__global__ __launch_bounds__(256) void proj_kernel(const float* __restrict__ x,
                                                   const float* __restrict__ s,
                                                   const float* __restrict__ tptr,
                                                   const float* __restrict__ pw,
                                                   const float* __restrict__ pb,
                                                   float* __restrict__ h) {
  __shared__ float inp[2][81];
  int tid = threadIdx.x;
  int g = tid >> 7;
  int o = tid & 127;
  int node = blockIdx.x * 2 + g;
  float t = tptr[0];
  if (o < 64) inp[g][o] = x[node * ND + o];
  else if (o == 64) inp[g][64] = s[node];
  else if (o < 81) {
    int j = o - 65;
    int jj = (j < 8) ? j : (j - 8);
    float f = __expf(-4.0f * (float)jj / 7.0f);
    float a = t * f;
    inp[g][o] = (j < 8) ? sinf(a) : cosf(a);
  }
  __syncthreads();
  float acc = pb[o];
#pragma unroll
  for (int c = 0; c < 81; ++c) acc = fmaf(inp[g][c], pw[c * H + o], acc);
  h[node * H + o] = acc;
}

// ---------------------------------------------------------------------------
// Layer-0 A/B via MFMA: 16 nodes/block; A=h@ew1[0:128]+eb1, B=h@ew1[128:256].
// ---------------------------------------------------------------------------
__global__ __launch_bounds__(256) void ab_mfma_kernel(
    const float* __restrict__ h, const unsigned short* __restrict__ ew1T,
    const float* __restrict__ eb1, unsigned short* __restrict__ Abf,
    unsigned short* __restrict__ Bbf) {
  __shared__ unsigned short hb[16][136];
  int tid = threadIdx.x;
  int n0 = blockIdx.x * 16;
  for (int idx = tid; idx < 16 * H; idx += 256) {
    int n = idx >> 7, c = idx & 127;
    hb[n][c] = f2bf(h[(n0 + n) * H + c]);
  }
  __syncthreads();
  int w = tid >> 6, lane = tid & 63, fr = lane & 15, kg = lane >> 4;
  f32x4 acc[4];
#pragma unroll
  for (int nt = 0; nt < 4; ++nt) acc[nt] = (f32x4){0.f, 0.f, 0.f, 0.f};
#pragma unroll
  for (int ks = 0; ks < 4; ++ks) {
    int k = ks * 32 + kg * 8;
    short8 a = *(const short8*)&hb[fr][k];
#pragma unroll
    for (int nt = 0; nt < 4; ++nt) {
      int col = w * 64 + nt * 16 + fr;
      short8 b = *(const short8*)&ew1T[col * H + k];
      acc[nt] = __builtin_amdgcn_mfma_f32_16x16x32_bf16(a, b, acc[nt], 0, 0, 0);
    }
  }
#pragma unroll
  for (int nt = 0; nt < 4; ++nt) {
    int col = w * 64 + nt * 16 + fr;
    float bias = (col < H) ? eb1[col] : 0.0f;
#pragma unroll
    for (int r = 0; r < 4; ++r) {
      int row = kg * 4 + r;
      float val = acc[nt][r] + bias;
      if (col < H) Abf[(n0 + row) * H + col] = f2bf(val);
      else Bbf[(n0 + row) * H + (col - H)] = f2bf(val);
    }
  }
}

// ---------------------------------------------------------------------------
// Edge phase, MFMA: 128 CSR positions per block. A/B gathered as bf16.
// ---------------------------------------------------------------------------
__global__ __launch_bounds__(256) void edge_mfma_kernel(
    const unsigned short* __restrict__ Abf, const unsigned short* __restrict__ Bbf,
    const float* __restrict__ p, const float* __restrict__ s,
    const int* __restrict__ csr_off, const int* __restrict__ eid,
    const int* __restrict__ dstof, const float* __restrict__ wr,
    const unsigned short* __restrict__ w2T, const float* __restrict__ eb2,
    const float* __restrict__ cw, const float* __restrict__ cbp,
    float* __restrict__ msA, float* __restrict__ msB,
    float* __restrict__ cuA, float* __restrict__ cuB) {
  __shared__ unsigned short t1s[TILE_E][136];  // t1 (bf16), later reused for m
  __shared__ float r2A[TILE_E], sA[TILE_E], dirA[TILE_E][3], gA[TILE_E];
  __shared__ int srcA[TILE_E], dstA[TILE_E];
  __shared__ float wrs[H], b2s[H], cws[H];

  int tid = threadIdx.x;
  int P0 = blockIdx.x * TILE_E;
  int P1 = P0 + TILE_E;

  if (tid < H) { wrs[tid] = wr[tid]; b2s[tid] = eb2[tid]; cws[tid] = cw[tid]; }
  if (tid < TILE_E) {
    int e = tid;
    int edge = eid[P0 + e];
    int src = edge >> 4;  // edge / KNN
    int d = dstof[P0 + e];
    srcA[e] = src;
    dstA[e] = d;
    float dx = p[d * 3 + 0] - p[src * 3 + 0];
    float dy = p[d * 3 + 1] - p[src * 3 + 1];
    float dz = p[d * 3 + 2] - p[src * 3 + 2];
    float r2 = dx * dx + dy * dy + dz * dz;
    r2A[e] = r2;
    float rinv = 1.0f / sqrtf(r2 + 1e-8f);
    dirA[e][0] = dx * rinv;
    dirA[e][1] = dy * rinv;
    dirA[e][2] = dz * rinv;
    sA[e] = s[src];
  }
  __syncthreads();

  int nA = dstA[0], nB = dstA[TILE_E - 1];
  int nn = nB - nA + 1;

  // stage 1: t1 tile (bf16); 4 cols per thread, coalesced uint2 gathers
  for (int idx = tid; idx < TILE_E * 32; idx += 256) {
    int e = idx >> 5, cp = (idx & 31) * 4;
    uint2 au = *(const uint2*)&Abf[dstA[e] * H + cp];
    uint2 bu = *(const uint2*)&Bbf[srcA[e] * H + cp];
    float r2v = r2A[e];
    float pr0 = silu(bf2f((unsigned short)(au.x & 0xffffu)) +
                     bf2f((unsigned short)(bu.x & 0xffffu)) + r2v * wrs[cp]);
    float pr1 = silu(bf2f((unsigned short)(au.x >> 16)) +
                     bf2f((unsigned short)(bu.x >> 16)) + r2v * wrs[cp + 1]);
    float pr2 = silu(bf2f((unsigned short)(au.y & 0xffffu)) +
                     bf2f((unsigned short)(bu.y & 0xffffu)) + r2v * wrs[cp + 2]);
    float pr3 = silu(bf2f((unsigned short)(au.y >> 16)) +
                     bf2f((unsigned short)(bu.y >> 16)) + r2v * wrs[cp + 3]);
    uint2 o;
    o.x = ((unsigned int)f2bf(pr1) << 16) | (unsigned int)f2bf(pr0);
    o.y = ((unsigned int)f2bf(pr3) << 16) | (unsigned int)f2bf(pr2);
    *(uint2*)&t1s[e][cp] = o;
  }
  __syncthreads();

  // stage 2: GEMM m_pre = t1 @ w2. Wave w -> out cols [w*32, w*32+32).
  int w = tid >> 6, lane = tid & 63;
  int fr = lane & 15, kg = lane >> 4;
  f32x4 acc[8][2];
#pragma unroll
  for (int mt = 0; mt < 8; ++mt)
#pragma unroll
    for (int nt = 0; nt < 2; ++nt) acc[mt][nt] = (f32x4){0.f, 0.f, 0.f, 0.f};
#pragma unroll
  for (int ks = 0; ks < 4; ++ks) {
    int k = ks * 32 + kg * 8;
    short8 bf0 = *(const short8*)&w2T[(w * 32 + fr) * H + k];
    short8 bf1 = *(const short8*)&w2T[(w * 32 + 16 + fr) * H + k];
#pragma unroll
    for (int mt = 0; mt < 8; ++mt) {
      short8 a = *(const short8*)&t1s[mt * 16 + fr][k];
      acc[mt][0] = __builtin_amdgcn_mfma_f32_16x16x32_bf16(a, bf0, acc[mt][0], 0, 0, 0);
      acc[mt][1] = __builtin_amdgcn_mfma_f32_16x16x32_bf16(a, bf1, acc[mt][1], 0, 0, 0);
    }
  }
  __syncthreads();  // all t1s reads done

  // epilogue: m = silu(acc + b2) * s[src] -> back into t1s (bf16)
#pragma unroll
  for (int mt = 0; mt < 8; ++mt) {
#pragma unroll
    for (int nt = 0; nt < 2; ++nt) {
      int col = w * 32 + nt * 16 + fr;
      float b2v = b2s[col];
#pragma unroll
      for (int r = 0; r < 4; ++r) {
        int row = mt * 16 + kg * 4 + r;
        float mv = silu(acc[mt][nt][r] + b2v) * sA[row];
        t1s[row][col] = f2bf(mv);
      }
    }
  }
  __syncthreads();

  // gamma per edge (ascending col order)
  if (tid < TILE_E) {
    float g = 0.f;
    for (int c = 0; c < H; c += 4) {
      uint2 u = *(const uint2*)&t1s[tid][c];
      g = fmaf(bf2f((unsigned short)(u.x & 0xffffu)), cws[c], g);
      g = fmaf(bf2f((unsigned short)(u.x >> 16)), cws[c + 1], g);
      g = fmaf(bf2f((unsigned short)(u.y & 0xffffu)), cws[c + 2], g);
      g = fmaf(bf2f((unsigned short)(u.y >> 16)), cws[c + 3], g);
    }
    gA[tid] = g + cbp[0];
  }
  __syncthreads();

  // per-node partial msum -> slots
  for (int idx = tid; idx < nn * H; idx += 256) {
    int ni = idx >> 7, c = idx & 127;
    int n = nA + ni;
    int o0 = csr_off[n], o1 = csr_off[n + 1];
    int lo = max(o0, P0), hi = min(o1, P1);
    float sum = 0.f;
    for (int pos = lo; pos < hi; ++pos) sum += bf2f(t1s[pos - P0][c]);
    if (o0 >= P0) {
      msA[n * H + c] = sum;
      if (o1 <= P1) msB[n * H + c] = 0.0f;
    } else {
      msB[n * H + c] = sum;
    }
  }
  // per-node partial cu -> slots
  for (int idx = tid; idx < nn * 3; idx += 256) {
    int ni = idx / 3, comp = idx - ni * 3;
    int n = nA + ni;
    int o0 = csr_off[n], o1 = csr_off[n + 1];
    int lo = max(o0, P0), hi = min(o1, P1);
    float sum = 0.f;
    for (int pos = lo; pos < hi; ++pos)
      sum += gA[pos - P0] * dirA[pos - P0][comp];
    if (o0 >= P0) {
      cuA[n * 3 + comp] = sum;
      if (o1 <= P1) cuB[n * 3 + comp] = 0.0f;
    } else {
      cuB[n * 3 + comp] = sum;
    }
  }
}

// ---------------------------------------------------------------------------
// Node update via MFMA: 16 nodes/block, 4 waves.
// GEMM1 (K=256) -> silu -> GEMM2 (K=128) -> h_out; optionally fused A/B GEMM
// (K=128 -> N=256, ew1T of the NEXT layer) writing bf16 Abf/Bbf.
// ---------------------------------------------------------------------------
__global__ __launch_bounds__(256) void node_mfma_kernel(
    const float* __restrict__ h, const float* __restrict__ msA,
    const float* __restrict__ msB, const int* __restrict__ degi,
    const float* __restrict__ cuA, const float* __restrict__ cuB,
    const float* __restrict__ p_in, const unsigned short* __restrict__ w1T,
    const float* __restrict__ nb1, const unsigned short* __restrict__ w2T,
    const float* __restrict__ nb2, const unsigned short* __restrict__ ew1Tn,
    const float* __restrict__ eb1n, int doab, float* __restrict__ h_out,
    float* __restrict__ p_out, unsigned short* __restrict__ Abf,
    unsigned short* __restrict__ Bbf) {
  __shared__ unsigned short insb[16][264];
  __shared__ unsigned short hnsb[16][136];
  int tid = threadIdx.x;
  int n0 = blockIdx.x * 16;
  for (int idx = tid; idx < 16 * H; idx += 256) {
    int n = idx >> 7, c = idx & 127;
    int gn = n0 + n;
    float hv = h[gn * H + c];
    int dg = degi[gn];
    float ms = 0.f;
    if (dg > 0) ms = (msA[gn * H + c] + msB[gn * H + c]) / (float)dg;
    insb[n][c] = f2bf(hv);
    insb[n][H + c] = f2bf(ms);
  }
  __syncthreads();
  int w = tid >> 6, lane = tid & 63, fr = lane & 15, kg = lane >> 4;
  f32x4 acc[2];
  acc[0] = (f32x4){0.f, 0.f, 0.f, 0.f};
  acc[1] = (f32x4){0.f, 0.f, 0.f, 0.f};
#pragma unroll
  for (int ks = 0; ks < 8; ++ks) {
    int k = ks * 32 + kg * 8;
    short8 a = *(const short8*)&insb[fr][k];
#pragma unroll
    for (int nt = 0; nt < 2; ++nt) {
      int col = w * 32 + nt * 16 + fr;
      short8 b = *(const short8*)&w1T[col * 256 + k];
      acc[nt] = __builtin_amdgcn_mfma_f32_16x16x32_bf16(a, b, acc[nt], 0, 0, 0);
    }
  }
#pragma unroll
  for (int nt = 0; nt < 2; ++nt) {
    int col = w * 32 + nt * 16 + fr;
    float b1 = nb1[col];
#pragma unroll
    for (int r = 0; r < 4; ++r) {
      int row = kg * 4 + r;
      hnsb[row][col] = f2bf(silu(acc[nt][r] + b1));
    }
  }
  __syncthreads();
  f32x4 acc2[2];
  acc2[0] = (f32x4){0.f, 0.f, 0.f, 0.f};
  acc2[1] = (f32x4){0.f, 0.f, 0.f, 0.f};
#pragma unroll
  for (int ks = 0; ks < 4; ++ks) {
    int k = ks * 32 + kg * 8;
    short8 a = *(const short8*)&hnsb[fr][k];
#pragma unroll
    for (int nt = 0; nt < 2; ++nt) {
      int col = w * 32 + nt * 16 + fr;
      short8 b = *(const short8*)&w2T[col * H + k];
      acc2[nt] = __builtin_amdgcn_mfma_f32_16x16x32_bf16(a, b, acc2[nt], 0, 0, 0);
    }
  }
  // h_new: global fp32 + bf16 into reused insb region (free after GEMM1 barrier)
  unsigned short (*hb)[136] = (unsigned short(*)[136])insb;
#pragma unroll
  for (int nt = 0; nt < 2; ++nt) {
    int col = w * 32 + nt * 16 + fr;
    float b2 = nb2[col];
#pragma unroll
    for (int r = 0; r < 4; ++r) {
      int row = kg * 4 + r;
      float hv = acc2[nt][r] + b2;
      h_out[(n0 + row) * H + col] = hv;
      hb[row][col] = f2bf(hv);
    }
  }
  if (tid < 48) {
    int nl = tid / 3, comp = tid - nl * 3;
    int gn = n0 + nl;
    int dg = degi[gn];
    float add = 0.0f;
    if (dg > 0)
      add = (cuA[gn * 3 + comp] + cuB[gn * 3 + comp]) / (float)dg;
    p_out[gn * 3 + comp] = p_in[gn * 3 + comp] + add;
  }
  if (doab) {
    __syncthreads();
    f32x4 acc3[4];
#pragma unroll
    for (int nt = 0; nt < 4; ++nt) acc3[nt] = (f32x4){0.f, 0.f, 0.f, 0.f};
#pragma unroll
    for (int ks = 0; ks < 4; ++ks) {
      int k = ks * 32 + kg * 8;
      short8 a = *(const short8*)&hb[fr][k];
#pragma unroll
      for (int nt = 0; nt < 4; ++nt) {
        int col = w * 64 + nt * 16 + fr;
        short8 b = *(const short8*)&ew1Tn[col * H + k];
        acc3[nt] = __builtin_amdgcn_mfma_f32_16x16x32_bf16(a, b, acc3[nt], 0, 0, 0);
      }
    }
#pragma unroll
    for (int nt = 0; nt < 4; ++nt) {
      int col = w * 64 + nt * 16 + fr;
      float bias = (col < H) ? eb1n[col] : 0.0f;
#pragma unroll
      for (int r = 0; r < 4; ++r) {
        int row = kg * 4 + r;
        float val = acc3[nt][r] + bias;
        if (col < H) Abf[(n0 + row) * H + col] = f2bf(val);
        else Bbf[(n0 + row) * H + (col - H)] = f2bf(val);
      }
    }
  }
}

// ---------------------------------------------------------------------------
// Output head
// ---------------------------------------------------------------------------
__global__ __launch_bounds__(256) void out_kernel(
    const float* __restrict__ h, const float* __restrict__ p,
    const float* __restrict__ ecw, const float* __restrict__ ecb,
    const float* __restrict__ efw, const float* __restrict__ efb,
    float* __restrict__ out) {
  __shared__ float hs[32][H];
  int tid = threadIdx.x, n0 = blockIdx.x * 32;
  for (int idx = tid; idx < 32 * H; idx += 256) {
    int n = idx >> 7, c = idx & 127;
    int gn = n0 + n;
    hs[n][c] = (gn < N_NODES) ? h[gn * H + c] : 0.0f;
  }
  __syncthreads();
  for (int f = tid; f < 32 * 70; f += 256) {
    int nl = f / 70, j = f % 70;
    int gn = n0 + nl;
    if (gn >= N_NODES) continue;
    float v;
    if (j < 3) {
      v = ecb[j];
      for (int c = 0; c < H; ++c) v = fmaf(hs[nl][c], ecw[c * 3 + j], v);
    } else if (j < 67) {
      int jj = j - 3;
      v = efb[jj];
      for (int c = 0; c < H; ++c) v = fmaf(hs[nl][c], efw[c * ND + jj], v);
    } else {
      v = p[gn * 3 + (j - 67)];
    }
    out[gn * 70 + j] = v;
  }
}

// ---------------------------------------------------------------------------
extern "C" void kernel_launch(void* const* d_in, const int* in_sizes, int n_in,
                              void* d_out, int out_size, void* d_ws, size_t ws_size,
                              hipStream_t stream) {
  const float* x = (const float*)d_in[0];
  const float* pos = (const float*)d_in[1];
  const float* t = (const float*)d_in[2];
  const float* s = (const float*)d_in[3];
  const float* pw = (const float*)d_in[4];
  const float* pb = (const float*)d_in[5];
  const float* ew1 = (const float*)d_in[6];
  const float* eb1 = (const float*)d_in[7];
  const float* ew2 = (const float*)d_in[8];
  const float* eb2 = (const float*)d_in[9];
  const float* nw1 = (const float*)d_in[10];
  const float* nb1 = (const float*)d_in[11];
  const float* nw2 = (const float*)d_in[12];
  const float* nb2 = (const float*)d_in[13];
  const float* cw = (const float*)d_in[14];
  const float* cb = (const float*)d_in[15];
  const float* ecw = (const float*)d_in[16];
  const float* ecb = (const float*)d_in[17];
  const float* efw = (const float*)d_in[18];
  const float* efb = (const float*)d_in[19];

  char* wp = (char*)d_ws;
  auto alloc = [&](size_t bytes) {
    char* r = wp;
    wp += (bytes + 255) & ~(size_t)255;
    return r;
  };
  float* h0 = (float*)alloc((size_t)N_NODES * H * 4);
  float* h1 = (float*)alloc((size_t)N_NODES * H * 4);
  unsigned short* Abf = (unsigned short*)alloc((size_t)N_NODES * H * 2);
  unsigned short* Bbf = (unsigned short*)alloc((size_t)N_NODES * H * 2);
  float* msAb = (float*)alloc((size_t)N_NODES * H * 4);
  float* msBb = (float*)alloc((size_t)N_NODES * H * 4);
  float* cuAb = (float*)alloc((size_t)N_NODES * 3 * 4);
  float* cuBb = (float*)alloc((size_t)N_NODES * 3 * 4);
  float* p0 = (float*)alloc((size_t)N_NODES * 3 * 4);
  float* p1 = (float*)alloc((size_t)N_NODES * 3 * 4);
  int* degi = (int*)alloc((size_t)N_NODES * 4);
  int* nbr = (int*)alloc((size_t)E_EDGES * 4);
  int* off = (int*)alloc((size_t)(N_NODES + 1) * 4);
  int* cursor = (int*)alloc((size_t)N_NODES * 4);
  int* eid = (int*)alloc((size_t)E_EDGES * 4);
  int* dstof = (int*)alloc((size_t)E_EDGES * 4);
  unsigned short* w2Tb = (unsigned short*)alloc((size_t)LAYERS * H * H * 2);
  unsigned short* nw1Tb = (unsigned short*)alloc((size_t)LAYERS * 2 * H * H * 2);
  unsigned short* nw2Tb = (unsigned short*)alloc((size_t)LAYERS * H * H * 2);
  unsigned short* ew1Tb = (unsigned short*)alloc((size_t)LAYERS * 2 * H * H * 2);

  // pos4 aliases msAb (first written by edge_mfma, after KNN is done)
  float4* pos4 = (float4*)msAb;

  wcvt_kernel<<<1536, 256, 0, stream>>>(ew2, nw1, nw2, ew1, w2Tb, nw1Tb, nw2Tb, ew1Tb);
  pos4_kernel<<<(N_NODES + 255) / 256, 256, 0, stream>>>(pos, pos4, p0, degi);
  knn_kernel<<<N_NODES / 4, 256, 0, stream>>>(pos4, nbr, degi);
  scan_kernel<<<1, 1024, 0, stream>>>(degi, off, cursor);
  scatter_kernel<<<(E_EDGES + 255) / 256, 256, 0, stream>>>(nbr, cursor, eid, dstof);
  sort_kernel<<<(N_NODES + 255) / 256, 256, 0, stream>>>(off, eid);
  proj_kernel<<<N_NODES / 2, 256, 0, stream>>>(x, s, t, pw, pb, h0);
  ab_mfma_kernel<<<N_NODES / 16, 256, 0, stream>>>(h0, ew1Tb, eb1, Abf, Bbf);

  float* hc = h0;
  float* hn = h1;
  float* pc = p0;
  float* pn = p1;
  for (int l = 0; l < LAYERS; ++l) {
    const float* ew1l = ew1 + (size_t)l * 257 * H;
    int doab = (l < LAYERS - 1) ? 1 : 0;
    edge_mfma_kernel<<<E_EDGES / TILE_E, 256, 0, stream>>>(
        Abf, Bbf, pc, s, off, eid, dstof, ew1l + 256 * H,
        w2Tb + (size_t)l * H * H, eb2 + l * H, cw + l * H, cb + l,
        msAb, msBb, cuAb, cuBb);
    node_mfma_kernel<<<N_NODES / 16, 256, 0, stream>>>(
        hc, msAb, msBb, degi, cuAb, cuBb, pc, nw1Tb + (size_t)l * 2 * H * H,
        nb1 + l * H, nw2Tb + (size_t)l * H * H, nb2 + l * H,
        ew1Tb + (size_t)(l + doab) * 2 * H * H, eb1 + (size_t)(l + doab) * H,
        doab, hn, pn, Abf, Bbf);
    float* tmp = hc; hc = hn; hn = tmp;
    tmp = pc; pc = pn; pn = tmp;
  }
  out_kernel<<<(N_NODES + 31) / 32, 256, 0, stream>>>(hc, pc, ecw, ecb, efw, efb,
                                                      (float*)d_out);
}

// Round 8
// 450.675 us; speedup vs baseline: 1.4585x; 1.2253x over previous
//
#include <hip/hip_runtime.h>
#include <math.h>

#define N_NODES 10000
#define ND 64
#define H 128
#define LAYERS 4
#define KNN 16
#define TD 16
#define E_EDGES (N_NODES * KNN)
#define KC 1250    // knn candidates per LDS chunk (20 KB)
#define TILE_E 128 // edges per block in edge_mfma_kernel

typedef __attribute__((ext_vector_type(8))) short short8;
typedef __attribute__((ext_vector_type(4))) float f32x4;

__device__ __forceinline__ float silu(float x) {
  return x * __builtin_amdgcn_rcpf(1.0f + __expf(-x));
}

__device__ __forceinline__ unsigned short f2bf(float f) {
  unsigned int u = __float_as_uint(f);
  u += 0x7fffu + ((u >> 16) & 1u);  // RNE
  return (unsigned short)(u >> 16);
}
__device__ __forceinline__ float bf2f(unsigned short h) {
  return __uint_as_float(((unsigned int)h) << 16);
}

// ---------------------------------------------------------------------------
// pos4 precompute: [x,y,z,|p|^2]; also copies pos->p0 and zeroes degi.
// ---------------------------------------------------------------------------
__global__ __launch_bounds__(256) void pos4_kernel(const float* __restrict__ pos,
                                                   float4* __restrict__ pos4,
                                                   float* __restrict__ p0,
                                                   int* __restrict__ degi) {
  int i = blockIdx.x * 256 + threadIdx.x;
  if (i >= N_NODES) return;
  float x = pos[i * 3 + 0], y = pos[i * 3 + 1], z = pos[i * 3 + 2];
  pos4[i] = make_float4(x, y, z, x * x + y * y + z * z);
  p0[i * 3 + 0] = x;
  p0[i * 3 + 1] = y;
  p0[i * 3 + 2] = z;
  degi[i] = 0;
}

// ---------------------------------------------------------------------------
// Weight precast (bf16, transposed [out][in]):
//   w2T 4*128*128 | nw1T 4*128*256 | nw2T 4*128*128 | ew1T 4*256*128
//   pwT 128*96 (pw zero-padded 81->96) | owT 80*128 ([ecw|efw] padded 67->80)
// ---------------------------------------------------------------------------
__global__ __launch_bounds__(256) void wcvt_kernel(
    const float* __restrict__ ew2, const float* __restrict__ nw1,
    const float* __restrict__ nw2, const float* __restrict__ ew1,
    const float* __restrict__ pw, const float* __restrict__ ecw,
    const float* __restrict__ efw, unsigned short* __restrict__ w2T,
    unsigned short* __restrict__ nw1T, unsigned short* __restrict__ nw2T,
    unsigned short* __restrict__ ew1T, unsigned short* __restrict__ pwT,
    unsigned short* __restrict__ owT) {
  int i = blockIdx.x * 256 + threadIdx.x;  // 415744 total
  if (i < 65536) {  // w2T: [l][o][c] <- ew2[l][c][o]
    int l = i >> 14, rem = i & 16383, o = rem >> 7, c = rem & 127;
    w2T[i] = f2bf(ew2[l * 16384 + c * 128 + o]);
  } else if (i < 196608) {  // nw1T: [l][o][c2] <- nw1[l][c2][o]
    int j = i - 65536;
    int l = j >> 15, rem = j & 32767, o = rem >> 8, c2 = rem & 255;
    nw1T[j] = f2bf(nw1[l * 32768 + c2 * 128 + o]);
  } else if (i < 262144) {  // nw2T: [l][o][c] <- nw2[l][c][o]
    int j = i - 196608;
    int l = j >> 14, rem = j & 16383, o = rem >> 7, c = rem & 127;
    nw2T[j] = f2bf(nw2[l * 16384 + c * 128 + o]);
  } else if (i < 393216) {  // ew1T: [l][o(256)][c(128)]
    int j = i - 262144;
    int l = j >> 15, rem = j & 32767, o = rem >> 7, c = rem & 127;
    ew1T[j] = f2bf(ew1[l * 257 * 128 + (c + ((o >> 7) << 7)) * 128 + (o & 127)]);
  } else if (i < 405504) {  // pwT: [o(128)][c(96)] <- pw[c(81)][o], pad 0
    int j = i - 393216;
    int o = j / 96, c = j - o * 96;
    pwT[j] = (c < 81) ? f2bf(pw[c * 128 + o]) : 0;
  } else {  // owT: [o(80)][c(128)]: o<3 ecw, 3..66 efw, else 0
    int j = i - 405504;
    int o = j >> 7, c = j & 127;
    float v = 0.0f;
    if (o < 3) v = ecw[c * 3 + o];
    else if (o < 67) v = efw[c * 64 + (o - 3)];
    owT[j] = f2bf(v);
  }
}

// ---------------------------------------------------------------------------
// KNN, wave-cooperative: one query per wave (4/block); top-16 distributed in
// lanes 0..15 (sorted). 128 candidates per round with a single combined
// ballot gate. Distances in shifted units d2' = p.w - 2*dot (order-equal).
// Ascending-index processing + strict < + stay-on-equal = lowest-index ties.
// Fused in-degree count.
// ---------------------------------------------------------------------------
__global__ __launch_bounds__(256) void knn_kernel(const float4* __restrict__ pos4,
                                                  int* __restrict__ nbr,
                                                  int* __restrict__ degi) {
  __shared__ float4 C[KC];
  int tid = threadIdx.x;
  int lane = tid & 63;
  int wid = tid >> 6;
  int i = blockIdx.x * 4 + wid;
  float4 q = pos4[i];
  float v = __builtin_inff();
  int vid = 0;
  float thresh = __builtin_inff();
  for (int base = 0; base < N_NODES; base += KC) {
    int cnt = min(KC, N_NODES - base);
    __syncthreads();
    for (int jj = tid; jj < cnt; jj += 256) C[jj] = pos4[base + jj];
    __syncthreads();
    for (int j0 = 0; j0 < cnt; j0 += 128) {
      int ja = j0 + lane, jb = j0 + 64 + lane;
      float da = __builtin_inff(), db = __builtin_inff();
      if (ja < cnt) {
        float4 p = C[ja];
        float dot = fmaf(q.x, p.x, fmaf(q.y, p.y, q.z * p.z));
        da = fmaf(-2.0f, dot, p.w);
        if (base + ja == i) da = __builtin_inff();
      }
      if (jb < cnt) {
        float4 p = C[jb];
        float dot = fmaf(q.x, p.x, fmaf(q.y, p.y, q.z * p.z));
        db = fmaf(-2.0f, dot, p.w);
        if (base + jb == i) db = __builtin_inff();
      }
      if (__ballot(fminf(da, db) < thresh)) {
        unsigned long long mask = __ballot(da < thresh);
        while (mask) {
          int sl = __ffsll((long long)mask) - 1;
          mask &= mask - 1;
          float d2b = __shfl(da, sl, 64);
          if (d2b >= thresh) continue;
          int gjb = base + j0 + sl;
          float prevv = __shfl_up(v, 1, 64);
          int previd = __shfl_up(vid, 1, 64);
          bool stay = (v <= d2b);
          bool takenew = (lane == 0) || (prevv <= d2b);
          v = stay ? v : (takenew ? d2b : prevv);
          vid = stay ? vid : (takenew ? gjb : previd);
          thresh = __shfl(v, 15, 64);
        }
        mask = __ballot(db < thresh);
        while (mask) {
          int sl = __ffsll((long long)mask) - 1;
          mask &= mask - 1;
          float d2b = __shfl(db, sl, 64);
          if (d2b >= thresh) continue;
          int gjb = base + j0 + 64 + sl;
          float prevv = __shfl_up(v, 1, 64);
          int previd = __shfl_up(vid, 1, 64);
          bool stay = (v <= d2b);
          bool takenew = (lane == 0) || (prevv <= d2b);
          v = stay ? v : (takenew ? d2b : prevv);
          vid = stay ? vid : (takenew ? gjb : previd);
          thresh = __shfl(v, 15, 64);
        }
      }
    }
  }
  if (lane < KNN) {
    nbr[i * KNN + lane] = vid;
    atomicAdd(&degi[vid], 1);
  }
}

// ---------------------------------------------------------------------------
// CSR build (deterministic): scan -> scatter(+dstof) -> per-node sort
// ---------------------------------------------------------------------------
__global__ __launch_bounds__(1024) void scan_kernel(const int* __restrict__ degi,
                                                    int* __restrict__ off,
                                                    int* __restrict__ cursor) {
  __shared__ int part[1024];
  int t = threadIdx.x;
  int base = t * 10;
  int sum = 0;
  if (t < 1000)
    for (int i = 0; i < 10; ++i) sum += degi[base + i];
  part[t] = sum;
  __syncthreads();
  for (int stp = 1; stp < 1024; stp <<= 1) {
    int v = (t >= stp) ? part[t - stp] : 0;
    __syncthreads();
    part[t] += v;
    __syncthreads();
  }
  if (t < 1000) {
    int run = (t == 0) ? 0 : part[t - 1];
    for (int i = 0; i < 10; ++i) {
      off[base + i] = run;
      cursor[base + i] = run;
      run += degi[base + i];
    }
  }
  if (t == 0) off[N_NODES] = E_EDGES;
}

__global__ void scatter_kernel(const int* __restrict__ nbr, int* __restrict__ cursor,
                               int* __restrict__ eid, int* __restrict__ dstof) {
  int e = blockIdx.x * 256 + threadIdx.x;
  if (e < E_EDGES) {
    int d = nbr[e];
    int p = atomicAdd(&cursor[d], 1);
    eid[p] = e;
    dstof[p] = d;
  }
}

__global__ void sort_kernel(const int* __restrict__ off, int* __restrict__ eid) {
  int n = blockIdx.x * 256 + threadIdx.x;
  if (n >= N_NODES) return;
  int a = off[n], b = off[n + 1];
  for (int i = a + 1; i < b; ++i) {
    int v = eid[i];
    int j = i - 1;
    while (j >= a && eid[j] > v) { eid[j + 1] = eid[j]; --j; }
    eid[j + 1] = v;
  }
}

// ---------------------------------------------------------------------------
// Fused proj + layer-0 A/B, MFMA. 16 nodes/block, 4 waves.
// h0 = [x,s,temb,(pad)] @ pwT (K=96) + pb ; then A/B = h0 @ ew1T (K=128).
// ---------------------------------------------------------------------------
__global__ __launch_bounds__(256) void proj_ab_kernel(
    const float* __restrict__ x, const float* __restrict__ s,
    const float* __restrict__ tptr, const unsigned short* __restrict__ pwT,
    const float* __restrict__ pb, const unsigned short* __restrict__ ew1T,
    const float* __restrict__ eb1, float* __restrict__ h_out,
    unsigned short* __restrict__ Abf, unsigned short* __restrict__ Bbf) {
  __shared__ unsigned short inpb[16][104];
  __shared__ unsigned short hb[16][136];
  int tid = threadIdx.x;
  int n0 = blockIdx.x * 16;
  float t = tptr[0];
  for (int idx = tid; idx < 16 * 104; idx += 256) {
    int n = idx / 104, c = idx - n * 104;
    int gn = n0 + n;
    float val;
    if (c < 64) val = x[gn * ND + c];
    else if (c == 64) val = s[gn];
    else if (c < 81) {
      int j = c - 65;
      int jj = (j < 8) ? j : (j - 8);
      float f = __expf(-4.0f * (float)jj / 7.0f);
      float a = t * f;
      val = (j < 8) ? sinf(a) : cosf(a);
    } else val = 0.0f;
    inpb[n][c] = f2bf(val);
  }
  __syncthreads();
  int w = tid >> 6, lane = tid & 63, fr = lane & 15, kg = lane >> 4;
  // GEMM1: h0 (128 cols, 2 tiles/wave, K=96)
  f32x4 acc[2];
  acc[0] = (f32x4){0.f, 0.f, 0.f, 0.f};
  acc[1] = (f32x4){0.f, 0.f, 0.f, 0.f};
#pragma unroll
  for (int ks = 0; ks < 3; ++ks) {
    int k = ks * 32 + kg * 8;
    short8 a = *(const short8*)&inpb[fr][k];
#pragma unroll
    for (int nt = 0; nt < 2; ++nt) {
      int col = w * 32 + nt * 16 + fr;
      short8 b = *(const short8*)&pwT[col * 96 + k];
      acc[nt] = __builtin_amdgcn_mfma_f32_16x16x32_bf16(a, b, acc[nt], 0, 0, 0);
    }
  }
#pragma unroll
  for (int nt = 0; nt < 2; ++nt) {
    int col = w * 32 + nt * 16 + fr;
    float bias = pb[col];
#pragma unroll
    for (int r = 0; r < 4; ++r) {
      int row = kg * 4 + r;
      float hv = acc[nt][r] + bias;
      h_out[(n0 + row) * H + col] = hv;
      hb[row][col] = f2bf(hv);
    }
  }
  __syncthreads();
  // GEMM2: A/B (256 cols, 4 tiles/wave, K=128)
  f32x4 acc2[4];
#pragma unroll
  for (int nt = 0; nt < 4; ++nt) acc2[nt] = (f32x4){0.f, 0.f, 0.f, 0.f};
#pragma unroll
  for (int ks = 0; ks < 4; ++ks) {
    int k = ks * 32 + kg * 8;
    short8 a = *(const short8*)&hb[fr][k];
#pragma unroll
    for (int nt = 0; nt < 4; ++nt) {
      int col = w * 64 + nt * 16 + fr;
      short8 b = *(const short8*)&ew1T[col * H + k];
      acc2[nt] = __builtin_amdgcn_mfma_f32_16x16x32_bf16(a, b, acc2[nt], 0, 0, 0);
    }
  }
#pragma unroll
  for (int nt = 0; nt < 4; ++nt) {
    int col = w * 64 + nt * 16 + fr;
    float bias = (col < H) ? eb1[col] : 0.0f;
#pragma unroll
    for (int r = 0; r < 4; ++r) {
      int row = kg * 4 + r;
      float val = acc2[nt][r] + bias;
      if (col < H) Abf[(n0 + row) * H + col] = f2bf(val);
      else Bbf[(n0 + row) * H + (col - H)] = f2bf(val);
    }
  }
}

// ---------------------------------------------------------------------------
// Edge phase, MFMA: 128 CSR positions per block. A/B gathered as bf16.
// ---------------------------------------------------------------------------
__global__ __launch_bounds__(256) void edge_mfma_kernel(
    const unsigned short* __restrict__ Abf, const unsigned short* __restrict__ Bbf,
    const float* __restrict__ p, const float* __restrict__ s,
    const int* __restrict__ csr_off, const int* __restrict__ eid,
    const int* __restrict__ dstof, const float* __restrict__ wr,
    const unsigned short* __restrict__ w2T, const float* __restrict__ eb2,
    const float* __restrict__ cw, const float* __restrict__ cbp,
    float* __restrict__ msA, float* __restrict__ msB,
    float* __restrict__ cuA, float* __restrict__ cuB) {
  __shared__ unsigned short t1s[TILE_E][136];  // t1 (bf16), later reused for m
  __shared__ float r2A[TILE_E], sA[TILE_E], dirA[TILE_E][3], gA[TILE_E];
  __shared__ int srcA[TILE_E], dstA[TILE_E];
  __shared__ float wrs[H], b2s[H], cws[H];

  int tid = threadIdx.x;
  int P0 = blockIdx.x * TILE_E;
  int P1 = P0 + TILE_E;

  if (tid < H) { wrs[tid] = wr[tid]; b2s[tid] = eb2[tid]; cws[tid] = cw[tid]; }
  if (tid < TILE_E) {
    int e = tid;
    int edge = eid[P0 + e];
    int src = edge >> 4;  // edge / KNN
    int d = dstof[P0 + e];
    srcA[e] = src;
    dstA[e] = d;
    float dx = p[d * 3 + 0] - p[src * 3 + 0];
    float dy = p[d * 3 + 1] - p[src * 3 + 1];
    float dz = p[d * 3 + 2] - p[src * 3 + 2];
    float r2 = dx * dx + dy * dy + dz * dz;
    r2A[e] = r2;
    float rinv = 1.0f / sqrtf(r2 + 1e-8f);
    dirA[e][0] = dx * rinv;
    dirA[e][1] = dy * rinv;
    dirA[e][2] = dz * rinv;
    sA[e] = s[src];
  }
  __syncthreads();

  int nA = dstA[0], nB = dstA[TILE_E - 1];
  int nn = nB - nA + 1;

  // stage 1: t1 tile (bf16); 4 cols per thread, coalesced uint2 gathers
  for (int idx = tid; idx < TILE_E * 32; idx += 256) {
    int e = idx >> 5, cp = (idx & 31) * 4;
    uint2 au = *(const uint2*)&Abf[dstA[e] * H + cp];
    uint2 bu = *(const uint2*)&Bbf[srcA[e] * H + cp];
    float r2v = r2A[e];
    float pr0 = silu(bf2f((unsigned short)(au.x & 0xffffu)) +
                     bf2f((unsigned short)(bu.x & 0xffffu)) + r2v * wrs[cp]);
    float pr1 = silu(bf2f((unsigned short)(au.x >> 16)) +
                     bf2f((unsigned short)(bu.x >> 16)) + r2v * wrs[cp + 1]);
    float pr2 = silu(bf2f((unsigned short)(au.y & 0xffffu)) +
                     bf2f((unsigned short)(bu.y & 0xffffu)) + r2v * wrs[cp + 2]);
    float pr3 = silu(bf2f((unsigned short)(au.y >> 16)) +
                     bf2f((unsigned short)(bu.y >> 16)) + r2v * wrs[cp + 3]);
    uint2 o;
    o.x = ((unsigned int)f2bf(pr1) << 16) | (unsigned int)f2bf(pr0);
    o.y = ((unsigned int)f2bf(pr3) << 16) | (unsigned int)f2bf(pr2);
    *(uint2*)&t1s[e][cp] = o;
  }
  __syncthreads();

  // stage 2: GEMM m_pre = t1 @ w2. Wave w -> out cols [w*32, w*32+32).
  int w = tid >> 6, lane = tid & 63;
  int fr = lane & 15, kg = lane >> 4;
  f32x4 acc[8][2];
#pragma unroll
  for (int mt = 0; mt < 8; ++mt)
#pragma unroll
    for (int nt = 0; nt < 2; ++nt) acc[mt][nt] = (f32x4){0.f, 0.f, 0.f, 0.f};
#pragma unroll
  for (int ks = 0; ks < 4; ++ks) {
    int k = ks * 32 + kg * 8;
    short8 bf0 = *(const short8*)&w2T[(w * 32 + fr) * H + k];
    short8 bf1 = *(const short8*)&w2T[(w * 32 + 16 + fr) * H + k];
#pragma unroll
    for (int mt = 0; mt < 8; ++mt) {
      short8 a = *(const short8*)&t1s[mt * 16 + fr][k];
      acc[mt][0] = __builtin_amdgcn_mfma_f32_16x16x32_bf16(a, bf0, acc[mt][0], 0, 0, 0);
      acc[mt][1] = __builtin_amdgcn_mfma_f32_16x16x32_bf16(a, bf1, acc[mt][1], 0, 0, 0);
    }
  }
  __syncthreads();  // all t1s reads done

  // epilogue: m = silu(acc + b2) * s[src] -> back into t1s (bf16)
#pragma unroll
  for (int mt = 0; mt < 8; ++mt) {
#pragma unroll
    for (int nt = 0; nt < 2; ++nt) {
      int col = w * 32 + nt * 16 + fr;
      float b2v = b2s[col];
#pragma unroll
      for (int r = 0; r < 4; ++r) {
        int row = mt * 16 + kg * 4 + r;
        float mv = silu(acc[mt][nt][r] + b2v) * sA[row];
        t1s[row][col] = f2bf(mv);
      }
    }
  }
  __syncthreads();

  // gamma per edge (ascending col order)
  if (tid < TILE_E) {
    float g = 0.f;
    for (int c = 0; c < H; c += 4) {
      uint2 u = *(const uint2*)&t1s[tid][c];
      g = fmaf(bf2f((unsigned short)(u.x & 0xffffu)), cws[c], g);
      g = fmaf(bf2f((unsigned short)(u.x >> 16)), cws[c + 1], g);
      g = fmaf(bf2f((unsigned short)(u.y & 0xffffu)), cws[c + 2], g);
      g = fmaf(bf2f((unsigned short)(u.y >> 16)), cws[c + 3], g);
    }
    gA[tid] = g + cbp[0];
  }
  __syncthreads();

  // per-node partial msum -> slots
  for (int idx = tid; idx < nn * H; idx += 256) {
    int ni = idx >> 7, c = idx & 127;
    int n = nA + ni;
    int o0 = csr_off[n], o1 = csr_off[n + 1];
    int lo = max(o0, P0), hi = min(o1, P1);
    float sum = 0.f;
    for (int pos = lo; pos < hi; ++pos) sum += bf2f(t1s[pos - P0][c]);
    if (o0 >= P0) {
      msA[n * H + c] = sum;
      if (o1 <= P1) msB[n * H + c] = 0.0f;
    } else {
      msB[n * H + c] = sum;
    }
  }
  // per-node partial cu -> slots
  for (int idx = tid; idx < nn * 3; idx += 256) {
    int ni = idx / 3, comp = idx - ni * 3;
    int n = nA + ni;
    int o0 = csr_off[n], o1 = csr_off[n + 1];
    int lo = max(o0, P0), hi = min(o1, P1);
    float sum = 0.f;
    for (int pos = lo; pos < hi; ++pos)
      sum += gA[pos - P0] * dirA[pos - P0][comp];
    if (o0 >= P0) {
      cuA[n * 3 + comp] = sum;
      if (o1 <= P1) cuB[n * 3 + comp] = 0.0f;
    } else {
      cuB[n * 3 + comp] = sum;
    }
  }
}

// ---------------------------------------------------------------------------
// Node update via MFMA: 16 nodes/block, 4 waves. GEMM1 (K=256) -> silu ->
// GEMM2 (K=128) -> h_out; optional fused next-layer A/B GEMM.
// ---------------------------------------------------------------------------
__global__ __launch_bounds__(256) void node_mfma_kernel(
    const float* __restrict__ h, const float* __restrict__ msA,
    const float* __restrict__ msB, const int* __restrict__ degi,
    const float* __restrict__ cuA, const float* __restrict__ cuB,
    const float* __restrict__ p_in, const unsigned short* __restrict__ w1T,
    const float* __restrict__ nb1, const unsigned short* __restrict__ w2T,
    const float* __restrict__ nb2, const unsigned short* __restrict__ ew1Tn,
    const float* __restrict__ eb1n, int doab, float* __restrict__ h_out,
    float* __restrict__ p_out, unsigned short* __restrict__ Abf,
    unsigned short* __restrict__ Bbf) {
  __shared__ unsigned short insb[16][264];
  __shared__ unsigned short hnsb[16][136];
  int tid = threadIdx.x;
  int n0 = blockIdx.x * 16;
  for (int idx = tid; idx < 16 * H; idx += 256) {
    int n = idx >> 7, c = idx & 127;
    int gn = n0 + n;
    float hv = h[gn * H + c];
    int dg = degi[gn];
    float ms = 0.f;
    if (dg > 0) ms = (msA[gn * H + c] + msB[gn * H + c]) / (float)dg;
    insb[n][c] = f2bf(hv);
    insb[n][H + c] = f2bf(ms);
  }
  __syncthreads();
  int w = tid >> 6, lane = tid & 63, fr = lane & 15, kg = lane >> 4;
  f32x4 acc[2];
  acc[0] = (f32x4){0.f, 0.f, 0.f, 0.f};
  acc[1] = (f32x4){0.f, 0.f, 0.f, 0.f};
#pragma unroll
  for (int ks = 0; ks < 8; ++ks) {
    int k = ks * 32 + kg * 8;
    short8 a = *(const short8*)&insb[fr][k];
#pragma unroll
    for (int nt = 0; nt < 2; ++nt) {
      int col = w * 32 + nt * 16 + fr;
      short8 b = *(const short8*)&w1T[col * 256 + k];
      acc[nt] = __builtin_amdgcn_mfma_f32_16x16x32_bf16(a, b, acc[nt], 0, 0, 0);
    }
  }
#pragma unroll
  for (int nt = 0; nt < 2; ++nt) {
    int col = w * 32 + nt * 16 + fr;
    float b1 = nb1[col];
#pragma unroll
    for (int r = 0; r < 4; ++r) {
      int row = kg * 4 + r;
      hnsb[row][col] = f2bf(silu(acc[nt][r] + b1));
    }
  }
  __syncthreads();
  f32x4 acc2[2];
  acc2[0] = (f32x4){0.f, 0.f, 0.f, 0.f};
  acc2[1] = (f32x4){0.f, 0.f, 0.f, 0.f};
#pragma unroll
  for (int ks = 0; ks < 4; ++ks) {
    int k = ks * 32 + kg * 8;
    short8 a = *(const short8*)&hnsb[fr][k];
#pragma unroll
    for (int nt = 0; nt < 2; ++nt) {
      int col = w * 32 + nt * 16 + fr;
      short8 b = *(const short8*)&w2T[col * H + k];
      acc2[nt] = __builtin_amdgcn_mfma_f32_16x16x32_bf16(a, b, acc2[nt], 0, 0, 0);
    }
  }
  unsigned short (*hb)[136] = (unsigned short(*)[136])insb;
#pragma unroll
  for (int nt = 0; nt < 2; ++nt) {
    int col = w * 32 + nt * 16 + fr;
    float b2 = nb2[col];
#pragma unroll
    for (int r = 0; r < 4; ++r) {
      int row = kg * 4 + r;
      float hv = acc2[nt][r] + b2;
      h_out[(n0 + row) * H + col] = hv;
      hb[row][col] = f2bf(hv);
    }
  }
  if (tid < 48) {
    int nl = tid / 3, comp = tid - nl * 3;
    int gn = n0 + nl;
    int dg = degi[gn];
    float add = 0.0f;
    if (dg > 0)
      add = (cuA[gn * 3 + comp] + cuB[gn * 3 + comp]) / (float)dg;
    p_out[gn * 3 + comp] = p_in[gn * 3 + comp] + add;
  }
  if (doab) {
    __syncthreads();
    f32x4 acc3[4];
#pragma unroll
    for (int nt = 0; nt < 4; ++nt) acc3[nt] = (f32x4){0.f, 0.f, 0.f, 0.f};
#pragma unroll
    for (int ks = 0; ks < 4; ++ks) {
      int k = ks * 32 + kg * 8;
      short8 a = *(const short8*)&hb[fr][k];
#pragma unroll
      for (int nt = 0; nt < 4; ++nt) {
        int col = w * 64 + nt * 16 + fr;
        short8 b = *(const short8*)&ew1Tn[col * H + k];
        acc3[nt] = __builtin_amdgcn_mfma_f32_16x16x32_bf16(a, b, acc3[nt], 0, 0, 0);
      }
    }
#pragma unroll
    for (int nt = 0; nt < 4; ++nt) {
      int col = w * 64 + nt * 16 + fr;
      float bias = (col < H) ? eb1n[col] : 0.0f;
#pragma unroll
      for (int r = 0; r < 4; ++r) {
        int row = kg * 4 + r;
        float val = acc3[nt][r] + bias;
        if (col < H) Abf[(n0 + row) * H + col] = f2bf(val);
        else Bbf[(n0 + row) * H + (col - H)] = f2bf(val);
      }
    }
  }
}

// ---------------------------------------------------------------------------
// Output head via MFMA: 16 nodes/block; out[:, :67] = h @ [ecw|efw] + bias,
// out[:, 67:70] = p. owT is [80][128] (padded); 5 col tiles, wave0 takes #4.
// ---------------------------------------------------------------------------
__global__ __launch_bounds__(256) void out_mfma_kernel(
    const float* __restrict__ h, const float* __restrict__ p,
    const unsigned short* __restrict__ owT, const float* __restrict__ ecb,
    const float* __restrict__ efb, float* __restrict__ out) {
  __shared__ unsigned short hb[16][136];
  int tid = threadIdx.x;
  int n0 = blockIdx.x * 16;
  for (int idx = tid; idx < 16 * H; idx += 256) {
    int n = idx >> 7, c = idx & 127;
    hb[n][c] = f2bf(h[(n0 + n) * H + c]);
  }
  __syncthreads();
  int w = tid >> 6, lane = tid & 63, fr = lane & 15, kg = lane >> 4;
  int ntiles = (w == 0) ? 2 : 1;
  for (int tt = 0; tt < ntiles; ++tt) {
    int tile = (tt == 0) ? w : 4;
    f32x4 acc = (f32x4){0.f, 0.f, 0.f, 0.f};
    int col = tile * 16 + fr;
#pragma unroll
    for (int ks = 0; ks < 4; ++ks) {
      int k = ks * 32 + kg * 8;
      short8 a = *(const short8*)&hb[fr][k];
      short8 b = *(const short8*)&owT[col * H + k];
      acc = __builtin_amdgcn_mfma_f32_16x16x32_bf16(a, b, acc, 0, 0, 0);
    }
    if (col < 67) {
      float bias = (col < 3) ? ecb[col] : efb[col - 3];
#pragma unroll
      for (int r = 0; r < 4; ++r) {
        int row = kg * 4 + r;
        out[(n0 + row) * 70 + col] = acc[r] + bias;
      }
    }
  }
  if (tid < 48) {
    int nl = tid / 3, comp = tid - nl * 3;
    int gn = n0 + nl;
    out[gn * 70 + 67 + comp] = p[gn * 3 + comp];
  }
}

// ---------------------------------------------------------------------------
extern "C" void kernel_launch(void* const* d_in, const int* in_sizes, int n_in,
                              void* d_out, int out_size, void* d_ws, size_t ws_size,
                              hipStream_t stream) {
  const float* x = (const float*)d_in[0];
  const float* pos = (const float*)d_in[1];
  const float* t = (const float*)d_in[2];
  const float* s = (const float*)d_in[3];
  const float* pw = (const float*)d_in[4];
  const float* pb = (const float*)d_in[5];
  const float* ew1 = (const float*)d_in[6];
  const float* eb1 = (const float*)d_in[7];
  const float* ew2 = (const float*)d_in[8];
  const float* eb2 = (const float*)d_in[9];
  const float* nw1 = (const float*)d_in[10];
  const float* nb1 = (const float*)d_in[11];
  const float* nw2 = (const float*)d_in[12];
  const float* nb2 = (const float*)d_in[13];
  const float* cw = (const float*)d_in[14];
  const float* cb = (const float*)d_in[15];
  const float* ecw = (const float*)d_in[16];
  const float* ecb = (const float*)d_in[17];
  const float* efw = (const float*)d_in[18];
  const float* efb = (const float*)d_in[19];

  char* wp = (char*)d_ws;
  auto alloc = [&](size_t bytes) {
    char* r = wp;
    wp += (bytes + 255) & ~(size_t)255;
    return r;
  };
  float* h0 = (float*)alloc((size_t)N_NODES * H * 4);
  float* h1 = (float*)alloc((size_t)N_NODES * H * 4);
  unsigned short* Abf = (unsigned short*)alloc((size_t)N_NODES * H * 2);
  unsigned short* Bbf = (unsigned short*)alloc((size_t)N_NODES * H * 2);
  float* msAb = (float*)alloc((size_t)N_NODES * H * 4);
  float* msBb = (float*)alloc((size_t)N_NODES * H * 4);
  float* cuAb = (float*)alloc((size_t)N_NODES * 3 * 4);
  float* cuBb = (float*)alloc((size_t)N_NODES * 3 * 4);
  float* p0 = (float*)alloc((size_t)N_NODES * 3 * 4);
  float* p1 = (float*)alloc((size_t)N_NODES * 3 * 4);
  int* degi = (int*)alloc((size_t)N_NODES * 4);
  int* nbr = (int*)alloc((size_t)E_EDGES * 4);
  int* off = (int*)alloc((size_t)(N_NODES + 1) * 4);
  int* cursor = (int*)alloc((size_t)N_NODES * 4);
  int* eid = (int*)alloc((size_t)E_EDGES * 4);
  int* dstof = (int*)alloc((size_t)E_EDGES * 4);
  unsigned short* w2Tb = (unsigned short*)alloc((size_t)LAYERS * H * H * 2);
  unsigned short* nw1Tb = (unsigned short*)alloc((size_t)LAYERS * 2 * H * H * 2);
  unsigned short* nw2Tb = (unsigned short*)alloc((size_t)LAYERS * H * H * 2);
  unsigned short* ew1Tb = (unsigned short*)alloc((size_t)LAYERS * 2 * H * H * 2);
  unsigned short* pwTb = (unsigned short*)alloc((size_t)H * 96 * 2);
  unsigned short* owTb = (unsigned short*)alloc((size_t)80 * H * 2);

  // pos4 aliases msAb (first written by edge_mfma, after KNN is done)
  float4* pos4 = (float4*)msAb;

  wcvt_kernel<<<1624, 256, 0, stream>>>(ew2, nw1, nw2, ew1, pw, ecw, efw,
                                        w2Tb, nw1Tb, nw2Tb, ew1Tb, pwTb, owTb);
  pos4_kernel<<<(N_NODES + 255) / 256, 256, 0, stream>>>(pos, pos4, p0, degi);
  knn_kernel<<<N_NODES / 4, 256, 0, stream>>>(pos4, nbr, degi);
  scan_kernel<<<1, 1024, 0, stream>>>(degi, off, cursor);
  scatter_kernel<<<(E_EDGES + 255) / 256, 256, 0, stream>>>(nbr, cursor, eid, dstof);
  sort_kernel<<<(N_NODES + 255) / 256, 256, 0, stream>>>(off, eid);
  proj_ab_kernel<<<N_NODES / 16, 256, 0, stream>>>(x, s, t, pwTb, pb, ew1Tb, eb1,
                                                   h0, Abf, Bbf);

  float* hc = h0;
  float* hn = h1;
  float* pc = p0;
  float* pn = p1;
  for (int l = 0; l < LAYERS; ++l) {
    const float* ew1l = ew1 + (size_t)l * 257 * H;
    int doab = (l < LAYERS - 1) ? 1 : 0;
    edge_mfma_kernel<<<E_EDGES / TILE_E, 256, 0, stream>>>(
        Abf, Bbf, pc, s, off, eid, dstof, ew1l + 256 * H,
        w2Tb + (size_t)l * H * H, eb2 + l * H, cw + l * H, cb + l,
        msAb, msBb, cuAb, cuBb);
    node_mfma_kernel<<<N_NODES / 16, 256, 0, stream>>>(
        hc, msAb, msBb, degi, cuAb, cuBb, pc, nw1Tb + (size_t)l * 2 * H * H,
        nb1 + l * H, nw2Tb + (size_t)l * H * H, nb2 + l * H,
        ew1Tb + (size_t)(l + doab) * 2 * H * H, eb1 + (size_t)(l + doab) * H,
        doab, hn, pn, Abf, Bbf);
    float* tmp = hc; hc = hn; hn = tmp;
    tmp = pc; pc = pn; pn = tmp;
  }
  out_mfma_kernel<<<N_NODES / 16, 256, 0, stream>>>(hc, pc, owTb, ecb, efb,
                                                    (float*)d_out);
}

// Round 9
// 428.931 us; speedup vs baseline: 1.5325x; 1.0507x over previous
//
#include <hip/hip_runtime.h>
#include <math.h>

#define N_NODES 10000
#define ND 64
#define H 128
#define LAYERS 4
#define KNN 16
#define TD 16
#define E_EDGES (N_NODES * KNN)
#define KC 1250    // knn candidates per LDS chunk (20 KB)
#define TILE_E 128 // edges per block in edge_mfma_kernel

typedef __attribute__((ext_vector_type(8))) short short8;
typedef __attribute__((ext_vector_type(4))) float f32x4;

__device__ __forceinline__ float silu(float x) {
  return x * __builtin_amdgcn_rcpf(1.0f + __expf(-x));
}

__device__ __forceinline__ unsigned short f2bf(float f) {
  unsigned int u = __float_as_uint(f);
  u += 0x7fffu + ((u >> 16) & 1u);  // RNE
  return (unsigned short)(u >> 16);
}
__device__ __forceinline__ float bf2f(unsigned short h) {
  return __uint_as_float(((unsigned int)h) << 16);
}

// ---------------------------------------------------------------------------
// pos4 precompute: [x,y,z,|p|^2]; also copies pos->p0 and zeroes degi.
// ---------------------------------------------------------------------------
__global__ __launch_bounds__(256) void pos4_kernel(const float* __restrict__ pos,
                                                   float4* __restrict__ pos4,
                                                   float* __restrict__ p0,
                                                   int* __restrict__ degi) {
  int i = blockIdx.x * 256 + threadIdx.x;
  if (i >= N_NODES) return;
  float x = pos[i * 3 + 0], y = pos[i * 3 + 1], z = pos[i * 3 + 2];
  pos4[i] = make_float4(x, y, z, x * x + y * y + z * z);
  p0[i * 3 + 0] = x;
  p0[i * 3 + 1] = y;
  p0[i * 3 + 2] = z;
  degi[i] = 0;
}

// ---------------------------------------------------------------------------
// Weight precast (bf16, transposed [out][in]). Big segments are src-linear
// (coalesced reads, scattered writes — stores don't stall).
// ---------------------------------------------------------------------------
__global__ __launch_bounds__(256) void wcvt_kernel(
    const float* __restrict__ ew2, const float* __restrict__ nw1,
    const float* __restrict__ nw2, const float* __restrict__ ew1,
    const float* __restrict__ pw, const float* __restrict__ ecw,
    const float* __restrict__ efw, unsigned short* __restrict__ w2T,
    unsigned short* __restrict__ nw1T, unsigned short* __restrict__ nw2T,
    unsigned short* __restrict__ ew1T, unsigned short* __restrict__ pwT,
    unsigned short* __restrict__ owT) {
  int i = blockIdx.x * 256 + threadIdx.x;  // 415744 total
  if (i < 65536) {  // w2T[l][o][c] <- ew2[l][c][o]; src-linear
    int l = i >> 14, rem = i & 16383, c = rem >> 7, o = rem & 127;
    w2T[l * 16384 + o * 128 + c] = f2bf(ew2[i]);
  } else if (i < 196608) {  // nw1T[l][o][c2] <- nw1[l][c2][o]; src-linear
    int j = i - 65536;
    int l = j >> 15, rem = j & 32767, c2 = rem >> 7, o = rem & 127;
    nw1T[l * 32768 + o * 256 + c2] = f2bf(nw1[j]);
  } else if (i < 262144) {  // nw2T; src-linear
    int j = i - 196608;
    int l = j >> 14, rem = j & 16383, c = rem >> 7, o = rem & 127;
    nw2T[l * 16384 + o * 128 + c] = f2bf(nw2[j]);
  } else if (i < 393216) {  // ew1T: src rows 0..255 of each 257-row ew1[l]
    int j = i - 262144;
    int l = j >> 15, rem = j & 32767, r = rem >> 7, o = rem & 127;
    int o2 = o + ((r >> 7) << 7);  // +128 if r >= 128 (B half)
    int c = r & 127;
    ew1T[l * 32768 + o2 * 128 + c] = f2bf(ew1[l * 257 * 128 + r * 128 + o]);
  } else if (i < 405504) {  // pwT: [o(128)][c(96)] <- pw[c(81)][o], pad 0
    int j = i - 393216;
    int o = j / 96, c = j - o * 96;
    pwT[j] = (c < 81) ? f2bf(pw[c * 128 + o]) : 0;
  } else {  // owT: [o(80)][c(128)]: o<3 ecw, 3..66 efw, else 0
    int j = i - 405504;
    int o = j >> 7, c = j & 127;
    float v = 0.0f;
    if (o < 3) v = ecw[c * 3 + o];
    else if (o < 67) v = efw[c * 64 + (o - 3)];
    owT[j] = f2bf(v);
  }
}

// ---------------------------------------------------------------------------
// KNN: 2 queries per wave (8/block, 1250 blocks). Top-17 distributed in
// lanes 0..16 (sorted asc) INCLUDING self: d' = |pj|^2 - 2 pi.pj makes self
// the strict global min (lands lane 0), so no per-candidate self check;
// neighbors are lanes 1..16. 256 candidates per round (4 b128 reads in
// flight), one gate ballot per query. Ascending-index processing + strict <
// + stay-on-equal preserves lowest-index-wins ties. Fused in-degree count.
// ---------------------------------------------------------------------------
#define INS(dval, gbase, V, ID, TH)                                   \
  {                                                                   \
    unsigned long long mask = __ballot((dval) < (TH));                \
    while (mask) {                                                    \
      int sl = __ffsll((long long)mask) - 1;                          \
      mask &= mask - 1;                                               \
      float db = __shfl((dval), sl, 64);                              \
      if (db >= (TH)) continue;                                       \
      int gj = (gbase) + sl;                                          \
      float pv = __shfl_up((V), 1, 64);                               \
      int pid = __shfl_up((ID), 1, 64);                               \
      bool stay = ((V) <= db);                                        \
      bool tk = (lane == 0) || (pv <= db);                            \
      (V) = stay ? (V) : (tk ? db : pv);                              \
      (ID) = stay ? (ID) : (tk ? gj : pid);                           \
      (TH) = __shfl((V), 16, 64);                                     \
    }                                                                 \
  }

__global__ __launch_bounds__(256) void knn_kernel(const float4* __restrict__ pos4,
                                                  int* __restrict__ nbr,
                                                  int* __restrict__ degi) {
  __shared__ float4 C[KC];
  int tid = threadIdx.x;
  int lane = tid & 63;
  int wid = tid >> 6;
  int qb = blockIdx.x * 8 + wid * 2;
  float4 q0 = pos4[qb];
  float4 q1 = pos4[qb + 1];
  float v0 = __builtin_inff(), v1 = __builtin_inff();
  int id0 = 0, id1 = 0;
  float th0 = __builtin_inff(), th1 = __builtin_inff();
  for (int base = 0; base < N_NODES; base += KC) {
    int cnt = min(KC, N_NODES - base);
    __syncthreads();
    for (int jj = tid; jj < cnt; jj += 256) C[jj] = pos4[base + jj];
    __syncthreads();
    for (int j0 = 0; j0 < cnt; j0 += 256) {
      float dA0 = __builtin_inff(), dA1 = __builtin_inff();
      float dB0 = __builtin_inff(), dB1 = __builtin_inff();
      float dC0 = __builtin_inff(), dC1 = __builtin_inff();
      float dD0 = __builtin_inff(), dD1 = __builtin_inff();
      int ja = j0 + lane, jbx = j0 + 64 + lane;
      int jc = j0 + 128 + lane, jd = j0 + 192 + lane;
      if (ja < cnt) {
        float4 p = C[ja];
        dA0 = fmaf(-2.0f, fmaf(q0.x, p.x, fmaf(q0.y, p.y, q0.z * p.z)), p.w);
        dA1 = fmaf(-2.0f, fmaf(q1.x, p.x, fmaf(q1.y, p.y, q1.z * p.z)), p.w);
      }
      if (jbx < cnt) {
        float4 p = C[jbx];
        dB0 = fmaf(-2.0f, fmaf(q0.x, p.x, fmaf(q0.y, p.y, q0.z * p.z)), p.w);
        dB1 = fmaf(-2.0f, fmaf(q1.x, p.x, fmaf(q1.y, p.y, q1.z * p.z)), p.w);
      }
      if (jc < cnt) {
        float4 p = C[jc];
        dC0 = fmaf(-2.0f, fmaf(q0.x, p.x, fmaf(q0.y, p.y, q0.z * p.z)), p.w);
        dC1 = fmaf(-2.0f, fmaf(q1.x, p.x, fmaf(q1.y, p.y, q1.z * p.z)), p.w);
      }
      if (jd < cnt) {
        float4 p = C[jd];
        dD0 = fmaf(-2.0f, fmaf(q0.x, p.x, fmaf(q0.y, p.y, q0.z * p.z)), p.w);
        dD1 = fmaf(-2.0f, fmaf(q1.x, p.x, fmaf(q1.y, p.y, q1.z * p.z)), p.w);
      }
      int gb = base + j0;
      float m0 = fminf(fminf(dA0, dB0), fminf(dC0, dD0));
      if (__ballot(m0 < th0)) {
        INS(dA0, gb, v0, id0, th0);
        INS(dB0, gb + 64, v0, id0, th0);
        INS(dC0, gb + 128, v0, id0, th0);
        INS(dD0, gb + 192, v0, id0, th0);
      }
      float m1 = fminf(fminf(dA1, dB1), fminf(dC1, dD1));
      if (__ballot(m1 < th1)) {
        INS(dA1, gb, v1, id1, th1);
        INS(dB1, gb + 64, v1, id1, th1);
        INS(dC1, gb + 128, v1, id1, th1);
        INS(dD1, gb + 192, v1, id1, th1);
      }
    }
  }
  if (lane >= 1 && lane < 17) {
    nbr[qb * KNN + lane - 1] = id0;
    atomicAdd(&degi[id0], 1);
    nbr[(qb + 1) * KNN + lane - 1] = id1;
    atomicAdd(&degi[id1], 1);
  }
}

// ---------------------------------------------------------------------------
// CSR build (deterministic): scan -> scatter(+dstof) -> per-node sort
// ---------------------------------------------------------------------------
__global__ __launch_bounds__(1024) void scan_kernel(const int* __restrict__ degi,
                                                    int* __restrict__ off,
                                                    int* __restrict__ cursor) {
  __shared__ int part[1024];
  int t = threadIdx.x;
  int base = t * 10;
  int sum = 0;
  if (t < 1000)
    for (int i = 0; i < 10; ++i) sum += degi[base + i];
  part[t] = sum;
  __syncthreads();
  for (int stp = 1; stp < 1024; stp <<= 1) {
    int v = (t >= stp) ? part[t - stp] : 0;
    __syncthreads();
    part[t] += v;
    __syncthreads();
  }
  if (t < 1000) {
    int run = (t == 0) ? 0 : part[t - 1];
    for (int i = 0; i < 10; ++i) {
      off[base + i] = run;
      cursor[base + i] = run;
      run += degi[base + i];
    }
  }
  if (t == 0) off[N_NODES] = E_EDGES;
}

__global__ void scatter_kernel(const int* __restrict__ nbr, int* __restrict__ cursor,
                               int* __restrict__ eid, int* __restrict__ dstof) {
  int e = blockIdx.x * 256 + threadIdx.x;
  if (e < E_EDGES) {
    int d = nbr[e];
    int p = atomicAdd(&cursor[d], 1);
    eid[p] = e;
    dstof[p] = d;
  }
}

__global__ void sort_kernel(const int* __restrict__ off, int* __restrict__ eid) {
  int n = blockIdx.x * 256 + threadIdx.x;
  if (n >= N_NODES) return;
  int a = off[n], b = off[n + 1];
  for (int i = a + 1; i < b; ++i) {
    int v = eid[i];
    int j = i - 1;
    while (j >= a && eid[j] > v) { eid[j + 1] = eid[j]; --j; }
    eid[j + 1] = v;
  }
}

// ---------------------------------------------------------------------------
// Fused proj + layer-0 A/B, MFMA. 16 nodes/block, 4 waves.
// ---------------------------------------------------------------------------
__global__ __launch_bounds__(256) void proj_ab_kernel(
    const float* __restrict__ x, const float* __restrict__ s,
    const float* __restrict__ tptr, const unsigned short* __restrict__ pwT,
    const float* __restrict__ pb, const unsigned short* __restrict__ ew1T,
    const float* __restrict__ eb1, float* __restrict__ h_out,
    unsigned short* __restrict__ Abf, unsigned short* __restrict__ Bbf) {
  __shared__ unsigned short inpb[16][104];
  __shared__ unsigned short hb[16][136];
  int tid = threadIdx.x;
  int n0 = blockIdx.x * 16;
  float t = tptr[0];
  for (int idx = tid; idx < 16 * 104; idx += 256) {
    int n = idx / 104, c = idx - n * 104;
    int gn = n0 + n;
    float val;
    if (c < 64) val = x[gn * ND + c];
    else if (c == 64) val = s[gn];
    else if (c < 81) {
      int j = c - 65;
      int jj = (j < 8) ? j : (j - 8);
      float f = __expf(-4.0f * (float)jj / 7.0f);
      float a = t * f;
      val = (j < 8) ? sinf(a) : cosf(a);
    } else val = 0.0f;
    inpb[n][c] = f2bf(val);
  }
  __syncthreads();
  int w = tid >> 6, lane = tid & 63, fr = lane & 15, kg = lane >> 4;
  f32x4 acc[2];
  acc[0] = (f32x4){0.f, 0.f, 0.f, 0.f};
  acc[1] = (f32x4){0.f, 0.f, 0.f, 0.f};
#pragma unroll
  for (int ks = 0; ks < 3; ++ks) {
    int k = ks * 32 + kg * 8;
    short8 a = *(const short8*)&inpb[fr][k];
#pragma unroll
    for (int nt = 0; nt < 2; ++nt) {
      int col = w * 32 + nt * 16 + fr;
      short8 b = *(const short8*)&pwT[col * 96 + k];
      acc[nt] = __builtin_amdgcn_mfma_f32_16x16x32_bf16(a, b, acc[nt], 0, 0, 0);
    }
  }
#pragma unroll
  for (int nt = 0; nt < 2; ++nt) {
    int col = w * 32 + nt * 16 + fr;
    float bias = pb[col];
#pragma unroll
    for (int r = 0; r < 4; ++r) {
      int row = kg * 4 + r;
      float hv = acc[nt][r] + bias;
      h_out[(n0 + row) * H + col] = hv;
      hb[row][col] = f2bf(hv);
    }
  }
  __syncthreads();
  f32x4 acc2[4];
#pragma unroll
  for (int nt = 0; nt < 4; ++nt) acc2[nt] = (f32x4){0.f, 0.f, 0.f, 0.f};
#pragma unroll
  for (int ks = 0; ks < 4; ++ks) {
    int k = ks * 32 + kg * 8;
    short8 a = *(const short8*)&hb[fr][k];
#pragma unroll
    for (int nt = 0; nt < 4; ++nt) {
      int col = w * 64 + nt * 16 + fr;
      short8 b = *(const short8*)&ew1T[col * H + k];
      acc2[nt] = __builtin_amdgcn_mfma_f32_16x16x32_bf16(a, b, acc2[nt], 0, 0, 0);
    }
  }
#pragma unroll
  for (int nt = 0; nt < 4; ++nt) {
    int col = w * 64 + nt * 16 + fr;
    float bias = (col < H) ? eb1[col] : 0.0f;
#pragma unroll
    for (int r = 0; r < 4; ++r) {
      int row = kg * 4 + r;
      float val = acc2[nt][r] + bias;
      if (col < H) Abf[(n0 + row) * H + col] = f2bf(val);
      else Bbf[(n0 + row) * H + (col - H)] = f2bf(val);
    }
  }
}

// ---------------------------------------------------------------------------
// Edge phase, MFMA: 128 CSR positions per block. A/B gathered as bf16.
// ---------------------------------------------------------------------------
__global__ __launch_bounds__(256) void edge_mfma_kernel(
    const unsigned short* __restrict__ Abf, const unsigned short* __restrict__ Bbf,
    const float* __restrict__ p, const float* __restrict__ s,
    const int* __restrict__ csr_off, const int* __restrict__ eid,
    const int* __restrict__ dstof, const float* __restrict__ wr,
    const unsigned short* __restrict__ w2T, const float* __restrict__ eb2,
    const float* __restrict__ cw, const float* __restrict__ cbp,
    float* __restrict__ msA, float* __restrict__ msB,
    float* __restrict__ cuA, float* __restrict__ cuB) {
  __shared__ unsigned short t1s[TILE_E][136];  // t1 (bf16), later reused for m
  __shared__ float r2A[TILE_E], sA[TILE_E], dirA[TILE_E][3], gA[TILE_E];
  __shared__ float gpart[2][TILE_E];
  __shared__ int srcA[TILE_E], dstA[TILE_E];
  __shared__ float wrs[H], b2s[H], cws[H];

  int tid = threadIdx.x;
  int P0 = blockIdx.x * TILE_E;
  int P1 = P0 + TILE_E;

  if (tid < H) { wrs[tid] = wr[tid]; b2s[tid] = eb2[tid]; cws[tid] = cw[tid]; }
  if (tid < TILE_E) {
    int e = tid;
    int edge = eid[P0 + e];
    int src = edge >> 4;  // edge / KNN
    int d = dstof[P0 + e];
    srcA[e] = src;
    dstA[e] = d;
    float dx = p[d * 3 + 0] - p[src * 3 + 0];
    float dy = p[d * 3 + 1] - p[src * 3 + 1];
    float dz = p[d * 3 + 2] - p[src * 3 + 2];
    float r2 = dx * dx + dy * dy + dz * dz;
    r2A[e] = r2;
    float rinv = 1.0f / sqrtf(r2 + 1e-8f);
    dirA[e][0] = dx * rinv;
    dirA[e][1] = dy * rinv;
    dirA[e][2] = dz * rinv;
    sA[e] = s[src];
  }
  __syncthreads();

  int nA = dstA[0], nB = dstA[TILE_E - 1];
  int nn = nB - nA + 1;

  // stage 1: t1 tile (bf16); 4 cols per thread, coalesced uint2 gathers
  for (int idx = tid; idx < TILE_E * 32; idx += 256) {
    int e = idx >> 5, cp = (idx & 31) * 4;
    uint2 au = *(const uint2*)&Abf[dstA[e] * H + cp];
    uint2 bu = *(const uint2*)&Bbf[srcA[e] * H + cp];
    float r2v = r2A[e];
    float pr0 = silu(bf2f((unsigned short)(au.x & 0xffffu)) +
                     bf2f((unsigned short)(bu.x & 0xffffu)) + r2v * wrs[cp]);
    float pr1 = silu(bf2f((unsigned short)(au.x >> 16)) +
                     bf2f((unsigned short)(bu.x >> 16)) + r2v * wrs[cp + 1]);
    float pr2 = silu(bf2f((unsigned short)(au.y & 0xffffu)) +
                     bf2f((unsigned short)(bu.y & 0xffffu)) + r2v * wrs[cp + 2]);
    float pr3 = silu(bf2f((unsigned short)(au.y >> 16)) +
                     bf2f((unsigned short)(bu.y >> 16)) + r2v * wrs[cp + 3]);
    uint2 o;
    o.x = ((unsigned int)f2bf(pr1) << 16) | (unsigned int)f2bf(pr0);
    o.y = ((unsigned int)f2bf(pr3) << 16) | (unsigned int)f2bf(pr2);
    *(uint2*)&t1s[e][cp] = o;
  }
  __syncthreads();

  // stage 2: GEMM m_pre = t1 @ w2. Wave w -> out cols [w*32, w*32+32).
  int w = tid >> 6, lane = tid & 63;
  int fr = lane & 15, kg = lane >> 4;
  f32x4 acc[8][2];
#pragma unroll
  for (int mt = 0; mt < 8; ++mt)
#pragma unroll
    for (int nt = 0; nt < 2; ++nt) acc[mt][nt] = (f32x4){0.f, 0.f, 0.f, 0.f};
#pragma unroll
  for (int ks = 0; ks < 4; ++ks) {
    int k = ks * 32 + kg * 8;
    short8 bf0 = *(const short8*)&w2T[(w * 32 + fr) * H + k];
    short8 bf1 = *(const short8*)&w2T[(w * 32 + 16 + fr) * H + k];
#pragma unroll
    for (int mt = 0; mt < 8; ++mt) {
      short8 a = *(const short8*)&t1s[mt * 16 + fr][k];
      acc[mt][0] = __builtin_amdgcn_mfma_f32_16x16x32_bf16(a, bf0, acc[mt][0], 0, 0, 0);
      acc[mt][1] = __builtin_amdgcn_mfma_f32_16x16x32_bf16(a, bf1, acc[mt][1], 0, 0, 0);
    }
  }
  __syncthreads();  // all t1s reads done

  // epilogue: m = silu(acc + b2) * s[src] -> back into t1s (bf16)
#pragma unroll
  for (int mt = 0; mt < 8; ++mt) {
#pragma unroll
    for (int nt = 0; nt < 2; ++nt) {
      int col = w * 32 + nt * 16 + fr;
      float b2v = b2s[col];
#pragma unroll
      for (int r = 0; r < 4; ++r) {
        int row = mt * 16 + kg * 4 + r;
        float mv = silu(acc[mt][nt][r] + b2v) * sA[row];
        t1s[row][col] = f2bf(mv);
      }
    }
  }
  __syncthreads();

  // gamma per edge: 2 threads/row (64 cols each), LDS combine
  {
    int e = tid & 127, half = tid >> 7;
    int c0 = half * 64;
    float g = 0.f;
    for (int c = c0; c < c0 + 64; c += 4) {
      uint2 u = *(const uint2*)&t1s[e][c];
      g = fmaf(bf2f((unsigned short)(u.x & 0xffffu)), cws[c], g);
      g = fmaf(bf2f((unsigned short)(u.x >> 16)), cws[c + 1], g);
      g = fmaf(bf2f((unsigned short)(u.y & 0xffffu)), cws[c + 2], g);
      g = fmaf(bf2f((unsigned short)(u.y >> 16)), cws[c + 3], g);
    }
    gpart[half][e] = g;
  }
  __syncthreads();
  if (tid < TILE_E) gA[tid] = gpart[0][tid] + gpart[1][tid] + cbp[0];
  __syncthreads();

  // per-node partial msum -> slots (4 cols per item, float4 writes)
  for (int idx = tid; idx < nn * 32; idx += 256) {
    int ni = idx >> 5, cq = (idx & 31) * 4;
    int n = nA + ni;
    int o0 = csr_off[n], o1 = csr_off[n + 1];
    int lo = max(o0, P0), hi = min(o1, P1);
    float s0 = 0.f, s1 = 0.f, s2 = 0.f, s3 = 0.f;
    for (int pos = lo; pos < hi; ++pos) {
      uint2 u = *(const uint2*)&t1s[pos - P0][cq];
      s0 += bf2f((unsigned short)(u.x & 0xffffu));
      s1 += bf2f((unsigned short)(u.x >> 16));
      s2 += bf2f((unsigned short)(u.y & 0xffffu));
      s3 += bf2f((unsigned short)(u.y >> 16));
    }
    float4 sv = make_float4(s0, s1, s2, s3);
    if (o0 >= P0) {
      *(float4*)&msA[n * H + cq] = sv;
      if (o1 <= P1) *(float4*)&msB[n * H + cq] = make_float4(0.f, 0.f, 0.f, 0.f);
    } else {
      *(float4*)&msB[n * H + cq] = sv;
    }
  }
  // per-node partial cu -> slots
  for (int idx = tid; idx < nn * 3; idx += 256) {
    int ni = idx / 3, comp = idx - ni * 3;
    int n = nA + ni;
    int o0 = csr_off[n], o1 = csr_off[n + 1];
    int lo = max(o0, P0), hi = min(o1, P1);
    float sum = 0.f;
    for (int pos = lo; pos < hi; ++pos)
      sum += gA[pos - P0] * dirA[pos - P0][comp];
    if (o0 >= P0) {
      cuA[n * 3 + comp] = sum;
      if (o1 <= P1) cuB[n * 3 + comp] = 0.0f;
    } else {
      cuB[n * 3 + comp] = sum;
    }
  }
}

// ---------------------------------------------------------------------------
// Node update via MFMA: 16 nodes/block, 4 waves. GEMM1 (K=256) -> silu ->
// GEMM2 (K=128) -> h_out; optional fused next-layer A/B GEMM.
// ---------------------------------------------------------------------------
__global__ __launch_bounds__(256) void node_mfma_kernel(
    const float* __restrict__ h, const float* __restrict__ msA,
    const float* __restrict__ msB, const int* __restrict__ degi,
    const float* __restrict__ cuA, const float* __restrict__ cuB,
    const float* __restrict__ p_in, const unsigned short* __restrict__ w1T,
    const float* __restrict__ nb1, const unsigned short* __restrict__ w2T,
    const float* __restrict__ nb2, const unsigned short* __restrict__ ew1Tn,
    const float* __restrict__ eb1n, int doab, float* __restrict__ h_out,
    float* __restrict__ p_out, unsigned short* __restrict__ Abf,
    unsigned short* __restrict__ Bbf) {
  __shared__ unsigned short insb[16][264];
  __shared__ unsigned short hnsb[16][136];
  int tid = threadIdx.x;
  int n0 = blockIdx.x * 16;
  for (int idx = tid; idx < 16 * H; idx += 256) {
    int n = idx >> 7, c = idx & 127;
    int gn = n0 + n;
    float hv = h[gn * H + c];
    int dg = degi[gn];
    float ms = 0.f;
    if (dg > 0) ms = (msA[gn * H + c] + msB[gn * H + c]) / (float)dg;
    insb[n][c] = f2bf(hv);
    insb[n][H + c] = f2bf(ms);
  }
  __syncthreads();
  int w = tid >> 6, lane = tid & 63, fr = lane & 15, kg = lane >> 4;
  f32x4 acc[2];
  acc[0] = (f32x4){0.f, 0.f, 0.f, 0.f};
  acc[1] = (f32x4){0.f, 0.f, 0.f, 0.f};
#pragma unroll
  for (int ks = 0; ks < 8; ++ks) {
    int k = ks * 32 + kg * 8;
    short8 a = *(const short8*)&insb[fr][k];
#pragma unroll
    for (int nt = 0; nt < 2; ++nt) {
      int col = w * 32 + nt * 16 + fr;
      short8 b = *(const short8*)&w1T[col * 256 + k];
      acc[nt] = __builtin_amdgcn_mfma_f32_16x16x32_bf16(a, b, acc[nt], 0, 0, 0);
    }
  }
#pragma unroll
  for (int nt = 0; nt < 2; ++nt) {
    int col = w * 32 + nt * 16 + fr;
    float b1 = nb1[col];
#pragma unroll
    for (int r = 0; r < 4; ++r) {
      int row = kg * 4 + r;
      hnsb[row][col] = f2bf(silu(acc[nt][r] + b1));
    }
  }
  __syncthreads();
  f32x4 acc2[2];
  acc2[0] = (f32x4){0.f, 0.f, 0.f, 0.f};
  acc2[1] = (f32x4){0.f, 0.f, 0.f, 0.f};
#pragma unroll
  for (int ks = 0; ks < 4; ++ks) {
    int k = ks * 32 + kg * 8;
    short8 a = *(const short8*)&hnsb[fr][k];
#pragma unroll
    for (int nt = 0; nt < 2; ++nt) {
      int col = w * 32 + nt * 16 + fr;
      short8 b = *(const short8*)&w2T[col * H + k];
      acc2[nt] = __builtin_amdgcn_mfma_f32_16x16x32_bf16(a, b, acc2[nt], 0, 0, 0);
    }
  }
  unsigned short (*hb)[136] = (unsigned short(*)[136])insb;
#pragma unroll
  for (int nt = 0; nt < 2; ++nt) {
    int col = w * 32 + nt * 16 + fr;
    float b2 = nb2[col];
#pragma unroll
    for (int r = 0; r < 4; ++r) {
      int row = kg * 4 + r;
      float hv = acc2[nt][r] + b2;
      h_out[(n0 + row) * H + col] = hv;
      hb[row][col] = f2bf(hv);
    }
  }
  if (tid < 48) {
    int nl = tid / 3, comp = tid - nl * 3;
    int gn = n0 + nl;
    int dg = degi[gn];
    float add = 0.0f;
    if (dg > 0)
      add = (cuA[gn * 3 + comp] + cuB[gn * 3 + comp]) / (float)dg;
    p_out[gn * 3 + comp] = p_in[gn * 3 + comp] + add;
  }
  if (doab) {
    __syncthreads();
    f32x4 acc3[4];
#pragma unroll
    for (int nt = 0; nt < 4; ++nt) acc3[nt] = (f32x4){0.f, 0.f, 0.f, 0.f};
#pragma unroll
    for (int ks = 0; ks < 4; ++ks) {
      int k = ks * 32 + kg * 8;
      short8 a = *(const short8*)&hb[fr][k];
#pragma unroll
      for (int nt = 0; nt < 4; ++nt) {
        int col = w * 64 + nt * 16 + fr;
        short8 b = *(const short8*)&ew1Tn[col * H + k];
        acc3[nt] = __builtin_amdgcn_mfma_f32_16x16x32_bf16(a, b, acc3[nt], 0, 0, 0);
      }
    }
#pragma unroll
    for (int nt = 0; nt < 4; ++nt) {
      int col = w * 64 + nt * 16 + fr;
      float bias = (col < H) ? eb1n[col] : 0.0f;
#pragma unroll
      for (int r = 0; r < 4; ++r) {
        int row = kg * 4 + r;
        float val = acc3[nt][r] + bias;
        if (col < H) Abf[(n0 + row) * H + col] = f2bf(val);
        else Bbf[(n0 + row) * H + (col - H)] = f2bf(val);
      }
    }
  }
}

// ---------------------------------------------------------------------------
// Output head via MFMA: 16 nodes/block.
// ---------------------------------------------------------------------------
__global__ __launch_bounds__(256) void out_mfma_kernel(
    const float* __restrict__ h, const float* __restrict__ p,
    const unsigned short* __restrict__ owT, const float* __restrict__ ecb,
    const float* __restrict__ efb, float* __restrict__ out) {
  __shared__ unsigned short hb[16][136];
  int tid = threadIdx.x;
  int n0 = blockIdx.x * 16;
  for (int idx = tid; idx < 16 * H; idx += 256) {
    int n = idx >> 7, c = idx & 127;
    hb[n][c] = f2bf(h[(n0 + n) * H + c]);
  }
  __syncthreads();
  int w = tid >> 6, lane = tid & 63, fr = lane & 15, kg = lane >> 4;
  int ntiles = (w == 0) ? 2 : 1;
  for (int tt = 0; tt < ntiles; ++tt) {
    int tile = (tt == 0) ? w : 4;
    f32x4 acc = (f32x4){0.f, 0.f, 0.f, 0.f};
    int col = tile * 16 + fr;
#pragma unroll
    for (int ks = 0; ks < 4; ++ks) {
      int k = ks * 32 + kg * 8;
      short8 a = *(const short8*)&hb[fr][k];
      short8 b = *(const short8*)&owT[col * H + k];
      acc = __builtin_amdgcn_mfma_f32_16x16x32_bf16(a, b, acc, 0, 0, 0);
    }
    if (col < 67) {
      float bias = (col < 3) ? ecb[col] : efb[col - 3];
#pragma unroll
      for (int r = 0; r < 4; ++r) {
        int row = kg * 4 + r;
        out[(n0 + row) * 70 + col] = acc[r] + bias;
      }
    }
  }
  if (tid < 48) {
    int nl = tid / 3, comp = tid - nl * 3;
    int gn = n0 + nl;
    out[gn * 70 + 67 + comp] = p[gn * 3 + comp];
  }
}

// ---------------------------------------------------------------------------
extern "C" void kernel_launch(void* const* d_in, const int* in_sizes, int n_in,
                              void* d_out, int out_size, void* d_ws, size_t ws_size,
                              hipStream_t stream) {
  const float* x = (const float*)d_in[0];
  const float* pos = (const float*)d_in[1];
  const float* t = (const float*)d_in[2];
  const float* s = (const float*)d_in[3];
  const float* pw = (const float*)d_in[4];
  const float* pb = (const float*)d_in[5];
  const float* ew1 = (const float*)d_in[6];
  const float* eb1 = (const float*)d_in[7];
  const float* ew2 = (const float*)d_in[8];
  const float* eb2 = (const float*)d_in[9];
  const float* nw1 = (const float*)d_in[10];
  const float* nb1 = (const float*)d_in[11];
  const float* nw2 = (const float*)d_in[12];
  const float* nb2 = (const float*)d_in[13];
  const float* cw = (const float*)d_in[14];
  const float* cb = (const float*)d_in[15];
  const float* ecw = (const float*)d_in[16];
  const float* ecb = (const float*)d_in[17];
  const float* efw = (const float*)d_in[18];
  const float* efb = (const float*)d_in[19];

  char* wp = (char*)d_ws;
  auto alloc = [&](size_t bytes) {
    char* r = wp;
    wp += (bytes + 255) & ~(size_t)255;
    return r;
  };
  float* h0 = (float*)alloc((size_t)N_NODES * H * 4);
  float* h1 = (float*)alloc((size_t)N_NODES * H * 4);
  unsigned short* Abf = (unsigned short*)alloc((size_t)N_NODES * H * 2);
  unsigned short* Bbf = (unsigned short*)alloc((size_t)N_NODES * H * 2);
  float* msAb = (float*)alloc((size_t)N_NODES * H * 4);
  float* msBb = (float*)alloc((size_t)N_NODES * H * 4);
  float* cuAb = (float*)alloc((size_t)N_NODES * 3 * 4);
  float* cuBb = (float*)alloc((size_t)N_NODES * 3 * 4);
  float* p0 = (float*)alloc((size_t)N_NODES * 3 * 4);
  float* p1 = (float*)alloc((size_t)N_NODES * 3 * 4);
  int* degi = (int*)alloc((size_t)N_NODES * 4);
  int* nbr = (int*)alloc((size_t)E_EDGES * 4);
  int* off = (int*)alloc((size_t)(N_NODES + 1) * 4);
  int* cursor = (int*)alloc((size_t)N_NODES * 4);
  int* eid = (int*)alloc((size_t)E_EDGES * 4);
  int* dstof = (int*)alloc((size_t)E_EDGES * 4);
  unsigned short* w2Tb = (unsigned short*)alloc((size_t)LAYERS * H * H * 2);
  unsigned short* nw1Tb = (unsigned short*)alloc((size_t)LAYERS * 2 * H * H * 2);
  unsigned short* nw2Tb = (unsigned short*)alloc((size_t)LAYERS * H * H * 2);
  unsigned short* ew1Tb = (unsigned short*)alloc((size_t)LAYERS * 2 * H * H * 2);
  unsigned short* pwTb = (unsigned short*)alloc((size_t)H * 96 * 2);
  unsigned short* owTb = (unsigned short*)alloc((size_t)80 * H * 2);

  // pos4 aliases msAb (first written by edge_mfma, after KNN is done)
  float4* pos4 = (float4*)msAb;

  wcvt_kernel<<<1624, 256, 0, stream>>>(ew2, nw1, nw2, ew1, pw, ecw, efw,
                                        w2Tb, nw1Tb, nw2Tb, ew1Tb, pwTb, owTb);
  pos4_kernel<<<(N_NODES + 255) / 256, 256, 0, stream>>>(pos, pos4, p0, degi);
  knn_kernel<<<N_NODES / 8, 256, 0, stream>>>(pos4, nbr, degi);
  scan_kernel<<<1, 1024, 0, stream>>>(degi, off, cursor);
  scatter_kernel<<<(E_EDGES + 255) / 256, 256, 0, stream>>>(nbr, cursor, eid, dstof);
  sort_kernel<<<(N_NODES + 255) / 256, 256, 0, stream>>>(off, eid);
  proj_ab_kernel<<<N_NODES / 16, 256, 0, stream>>>(x, s, t, pwTb, pb, ew1Tb, eb1,
                                                   h0, Abf, Bbf);

  float* hc = h0;
  float* hn = h1;
  float* pc = p0;
  float* pn = p1;
  for (int l = 0; l < LAYERS; ++l) {
    const float* ew1l = ew1 + (size_t)l * 257 * H;
    int doab = (l < LAYERS - 1) ? 1 : 0;
    edge_mfma_kernel<<<E_EDGES / TILE_E, 256, 0, stream>>>(
        Abf, Bbf, pc, s, off, eid, dstof, ew1l + 256 * H,
        w2Tb + (size_t)l * H * H, eb2 + l * H, cw + l * H, cb + l,
        msAb, msBb, cuAb, cuBb);
    node_mfma_kernel<<<N_NODES / 16, 256, 0, stream>>>(
        hc, msAb, msBb, degi, cuAb, cuBb, pc, nw1Tb + (size_t)l * 2 * H * H,
        nb1 + l * H, nw2Tb + (size_t)l * H * H, nb2 + l * H,
        ew1Tb + (size_t)(l + doab) * 2 * H * H, eb1 + (size_t)(l + doab) * H,
        doab, hn, pn, Abf, Bbf);
    float* tmp = hc; hc = hn; hn = tmp;
    tmp = pc; pc = pn; pn = tmp;
  }
  out_mfma_kernel<<<N_NODES / 16, 256, 0, stream>>>(hc, pc, owTb, ecb, efb,
                                                    (float*)d_out);
}

// Round 10
// 401.225 us; speedup vs baseline: 1.6383x; 1.0691x over previous
//
#include <hip/hip_runtime.h>
#include <math.h>

#define N_NODES 10000
#define ND 64
#define H 128
#define LAYERS 4
#define KNN 16
#define TD 16
#define E_EDGES (N_NODES * KNN)
#define KC 1250    // knn candidates per LDS chunk (20 KB)
#define TILE_E 128 // edges per block in edge_mfma_kernel

typedef __attribute__((ext_vector_type(8))) short short8;
typedef __attribute__((ext_vector_type(4))) float f32x4;

__device__ __forceinline__ float silu(float x) {
  return x * __builtin_amdgcn_rcpf(1.0f + __expf(-x));
}

__device__ __forceinline__ unsigned short f2bf(float f) {
  unsigned int u = __float_as_uint(f);
  u += 0x7fffu + ((u >> 16) & 1u);  // RNE
  return (unsigned short)(u >> 16);
}
__device__ __forceinline__ float bf2f(unsigned short h) {
  return __uint_as_float(((unsigned int)h) << 16);
}

// ---------------------------------------------------------------------------
// pos4 precompute: [x,y,z,|p|^2]; also copies pos->p0 and zeroes degi.
// ---------------------------------------------------------------------------
__global__ __launch_bounds__(256) void pos4_kernel(const float* __restrict__ pos,
                                                   float4* __restrict__ pos4,
                                                   float* __restrict__ p0,
                                                   int* __restrict__ degi) {
  int i = blockIdx.x * 256 + threadIdx.x;
  if (i >= N_NODES) return;
  float x = pos[i * 3 + 0], y = pos[i * 3 + 1], z = pos[i * 3 + 2];
  pos4[i] = make_float4(x, y, z, x * x + y * y + z * z);
  p0[i * 3 + 0] = x;
  p0[i * 3 + 1] = y;
  p0[i * 3 + 2] = z;
  degi[i] = 0;
}

// ---------------------------------------------------------------------------
// Weight precast (bf16, transposed [out][in]). Big segments are src-linear.
// ---------------------------------------------------------------------------
__global__ __launch_bounds__(256) void wcvt_kernel(
    const float* __restrict__ ew2, const float* __restrict__ nw1,
    const float* __restrict__ nw2, const float* __restrict__ ew1,
    const float* __restrict__ pw, const float* __restrict__ ecw,
    const float* __restrict__ efw, unsigned short* __restrict__ w2T,
    unsigned short* __restrict__ nw1T, unsigned short* __restrict__ nw2T,
    unsigned short* __restrict__ ew1T, unsigned short* __restrict__ pwT,
    unsigned short* __restrict__ owT) {
  int i = blockIdx.x * 256 + threadIdx.x;  // 415744 total
  if (i < 65536) {
    int l = i >> 14, rem = i & 16383, c = rem >> 7, o = rem & 127;
    w2T[l * 16384 + o * 128 + c] = f2bf(ew2[i]);
  } else if (i < 196608) {
    int j = i - 65536;
    int l = j >> 15, rem = j & 32767, c2 = rem >> 7, o = rem & 127;
    nw1T[l * 32768 + o * 256 + c2] = f2bf(nw1[j]);
  } else if (i < 262144) {
    int j = i - 196608;
    int l = j >> 14, rem = j & 16383, c = rem >> 7, o = rem & 127;
    nw2T[l * 16384 + o * 128 + c] = f2bf(nw2[j]);
  } else if (i < 393216) {
    int j = i - 262144;
    int l = j >> 15, rem = j & 32767, r = rem >> 7, o = rem & 127;
    int o2 = o + ((r >> 7) << 7);
    int c = r & 127;
    ew1T[l * 32768 + o2 * 128 + c] = f2bf(ew1[l * 257 * 128 + r * 128 + o]);
  } else if (i < 405504) {
    int j = i - 393216;
    int o = j / 96, c = j - o * 96;
    pwT[j] = (c < 81) ? f2bf(pw[c * 128 + o]) : 0;
  } else {
    int j = i - 405504;
    int o = j >> 7, c = j & 127;
    float v = 0.0f;
    if (o < 3) v = ecw[c * 3 + o];
    else if (o < 67) v = efw[c * 64 + (o - 3)];
    owT[j] = f2bf(v);
  }
}

// ---------------------------------------------------------------------------
// KNN: 2 queries per wave (8/block, 1250 blocks). Top-17 distributed in
// lanes 0..16 (sorted asc) INCLUDING self (d' = |pj|^2 - 2 pi.pj makes self
// the strict global min -> lane 0; neighbors lanes 1..16). 256 cands/round,
// 4 guard-free rounds + guarded tail (KC=1250=4*256+226). Fused dual-query
// insert loop (independent shuffle chains overlap). Ascending chunk/group/
// lane processing + strict < + stay-on-equal = lowest-index-wins ties.
// Fused in-degree count.
// ---------------------------------------------------------------------------
#define DIST2(pp, d0, d1)                                                    \
  d0 = fmaf(ax0, (pp).x, fmaf(ay0, (pp).y, fmaf(az0, (pp).z, (pp).w)));      \
  d1 = fmaf(ax1, (pp).x, fmaf(ay1, (pp).y, fmaf(az1, (pp).z, (pp).w)));

#define PAIR(dv0, dv1, gbase)                                                \
  {                                                                          \
    unsigned long long m0 = __ballot((dv0) < th0);                           \
    unsigned long long m1 = __ballot((dv1) < th1);                           \
    while (m0 | m1) {                                                        \
      if (m0) {                                                              \
        int sl = __ffsll((long long)m0) - 1;                                 \
        m0 &= m0 - 1;                                                        \
        float db = __shfl((dv0), sl, 64);                                    \
        if (db < th0) {                                                      \
          int gj = (gbase) + sl;                                             \
          float pv = __shfl_up(v0, 1, 64);                                   \
          int pid = __shfl_up(id0, 1, 64);                                   \
          bool stay = (v0 <= db);                                            \
          bool tk = (lane == 0) || (pv <= db);                               \
          v0 = stay ? v0 : (tk ? db : pv);                                   \
          id0 = stay ? id0 : (tk ? gj : pid);                                \
          th0 = __shfl(v0, 16, 64);                                          \
        }                                                                    \
      }                                                                      \
      if (m1) {                                                              \
        int sl = __ffsll((long long)m1) - 1;                                 \
        m1 &= m1 - 1;                                                        \
        float db = __shfl((dv1), sl, 64);                                    \
        if (db < th1) {                                                      \
          int gj = (gbase) + sl;                                             \
          float pv = __shfl_up(v1, 1, 64);                                   \
          int pid = __shfl_up(id1, 1, 64);                                   \
          bool stay = (v1 <= db);                                            \
          bool tk = (lane == 0) || (pv <= db);                               \
          v1 = stay ? v1 : (tk ? db : pv);                                   \
          id1 = stay ? id1 : (tk ? gj : pid);                                \
          th1 = __shfl(v1, 16, 64);                                          \
        }                                                                    \
      }                                                                      \
    }                                                                        \
  }

__global__ __launch_bounds__(256) void knn_kernel(const float4* __restrict__ pos4,
                                                  int* __restrict__ nbr,
                                                  int* __restrict__ degi) {
  __shared__ float4 C[KC];
  int tid = threadIdx.x;
  int lane = tid & 63;
  int wid = tid >> 6;
  int qb = blockIdx.x * 8 + wid * 2;
  float4 q0 = pos4[qb];
  float4 q1 = pos4[qb + 1];
  float ax0 = -2.0f * q0.x, ay0 = -2.0f * q0.y, az0 = -2.0f * q0.z;
  float ax1 = -2.0f * q1.x, ay1 = -2.0f * q1.y, az1 = -2.0f * q1.z;
  float v0 = __builtin_inff(), v1 = __builtin_inff();
  int id0 = 0, id1 = 0;
  float th0 = __builtin_inff(), th1 = __builtin_inff();
  for (int base = 0; base < N_NODES; base += KC) {
    __syncthreads();
    for (int jj = tid; jj < KC; jj += 256) C[jj] = pos4[base + jj];
    __syncthreads();
    // 4 guard-free full rounds (j0 = 0,256,512,768)
    for (int j0 = 0; j0 < 1024; j0 += 256) {
      float4 pA = C[j0 + lane], pB = C[j0 + 64 + lane];
      float4 pC = C[j0 + 128 + lane], pD = C[j0 + 192 + lane];
      float dA0, dA1, dB0, dB1, dC0, dC1, dD0, dD1;
      DIST2(pA, dA0, dA1);
      DIST2(pB, dB0, dB1);
      DIST2(pC, dC0, dC1);
      DIST2(pD, dD0, dD1);
      float mn0 = fminf(fminf(dA0, dB0), fminf(dC0, dD0));
      float mn1 = fminf(fminf(dA1, dB1), fminf(dC1, dD1));
      if (__ballot((mn0 < th0) | (mn1 < th1))) {
        int gb = base + j0;
        PAIR(dA0, dA1, gb);
        PAIR(dB0, dB1, gb + 64);
        PAIR(dC0, dC1, gb + 128);
        PAIR(dD0, dD1, gb + 192);
      }
    }
    // tail round j0=1024: A,B,C full; D partial (34 lanes)
    {
      float4 pA = C[1024 + lane], pB = C[1088 + lane], pC = C[1152 + lane];
      float dA0, dA1, dB0, dB1, dC0, dC1;
      float dD0 = __builtin_inff(), dD1 = __builtin_inff();
      DIST2(pA, dA0, dA1);
      DIST2(pB, dB0, dB1);
      DIST2(pC, dC0, dC1);
      if (lane < 34) {
        float4 pD = C[1216 + lane];
        DIST2(pD, dD0, dD1);
      }
      float mn0 = fminf(fminf(dA0, dB0), fminf(dC0, dD0));
      float mn1 = fminf(fminf(dA1, dB1), fminf(dC1, dD1));
      if (__ballot((mn0 < th0) | (mn1 < th1))) {
        int gb = base + 1024;
        PAIR(dA0, dA1, gb);
        PAIR(dB0, dB1, gb + 64);
        PAIR(dC0, dC1, gb + 128);
        PAIR(dD0, dD1, gb + 192);
      }
    }
  }
  if (lane >= 1 && lane < 17) {
    nbr[qb * KNN + lane - 1] = id0;
    atomicAdd(&degi[id0], 1);
    nbr[(qb + 1) * KNN + lane - 1] = id1;
    atomicAdd(&degi[id1], 1);
  }
}

// ---------------------------------------------------------------------------
// CSR build (deterministic): scan -> scatter(+dstof) -> per-node sort
// ---------------------------------------------------------------------------
__global__ __launch_bounds__(1024) void scan_kernel(const int* __restrict__ degi,
                                                    int* __restrict__ off,
                                                    int* __restrict__ cursor) {
  __shared__ int part[1024];
  int t = threadIdx.x;
  int base = t * 10;
  int sum = 0;
  if (t < 1000)
    for (int i = 0; i < 10; ++i) sum += degi[base + i];
  part[t] = sum;
  __syncthreads();
  for (int stp = 1; stp < 1024; stp <<= 1) {
    int v = (t >= stp) ? part[t - stp] : 0;
    __syncthreads();
    part[t] += v;
    __syncthreads();
  }
  if (t < 1000) {
    int run = (t == 0) ? 0 : part[t - 1];
    for (int i = 0; i < 10; ++i) {
      off[base + i] = run;
      cursor[base + i] = run;
      run += degi[base + i];
    }
  }
  if (t == 0) off[N_NODES] = E_EDGES;
}

__global__ void scatter_kernel(const int* __restrict__ nbr, int* __restrict__ cursor,
                               int* __restrict__ eid, int* __restrict__ dstof) {
  int e = blockIdx.x * 256 + threadIdx.x;
  if (e < E_EDGES) {
    int d = nbr[e];
    int p = atomicAdd(&cursor[d], 1);
    eid[p] = e;
    dstof[p] = d;
  }
}

__global__ void sort_kernel(const int* __restrict__ off, int* __restrict__ eid) {
  int n = blockIdx.x * 256 + threadIdx.x;
  if (n >= N_NODES) return;
  int a = off[n], b = off[n + 1];
  for (int i = a + 1; i < b; ++i) {
    int v = eid[i];
    int j = i - 1;
    while (j >= a && eid[j] > v) { eid[j + 1] = eid[j]; --j; }
    eid[j + 1] = v;
  }
}

// ---------------------------------------------------------------------------
// Fused proj + layer-0 A/B, MFMA. 16 nodes/block, 4 waves.
// ---------------------------------------------------------------------------
__global__ __launch_bounds__(256) void proj_ab_kernel(
    const float* __restrict__ x, const float* __restrict__ s,
    const float* __restrict__ tptr, const unsigned short* __restrict__ pwT,
    const float* __restrict__ pb, const unsigned short* __restrict__ ew1T,
    const float* __restrict__ eb1, float* __restrict__ h_out,
    unsigned short* __restrict__ Abf, unsigned short* __restrict__ Bbf) {
  __shared__ unsigned short inpb[16][104];
  __shared__ unsigned short hb[16][136];
  int tid = threadIdx.x;
  int n0 = blockIdx.x * 16;
  float t = tptr[0];
  for (int idx = tid; idx < 16 * 104; idx += 256) {
    int n = idx / 104, c = idx - n * 104;
    int gn = n0 + n;
    float val;
    if (c < 64) val = x[gn * ND + c];
    else if (c == 64) val = s[gn];
    else if (c < 81) {
      int j = c - 65;
      int jj = (j < 8) ? j : (j - 8);
      float f = __expf(-4.0f * (float)jj / 7.0f);
      float a = t * f;
      val = (j < 8) ? sinf(a) : cosf(a);
    } else val = 0.0f;
    inpb[n][c] = f2bf(val);
  }
  __syncthreads();
  int w = tid >> 6, lane = tid & 63, fr = lane & 15, kg = lane >> 4;
  f32x4 acc[2];
  acc[0] = (f32x4){0.f, 0.f, 0.f, 0.f};
  acc[1] = (f32x4){0.f, 0.f, 0.f, 0.f};
#pragma unroll
  for (int ks = 0; ks < 3; ++ks) {
    int k = ks * 32 + kg * 8;
    short8 a = *(const short8*)&inpb[fr][k];
#pragma unroll
    for (int nt = 0; nt < 2; ++nt) {
      int col = w * 32 + nt * 16 + fr;
      short8 b = *(const short8*)&pwT[col * 96 + k];
      acc[nt] = __builtin_amdgcn_mfma_f32_16x16x32_bf16(a, b, acc[nt], 0, 0, 0);
    }
  }
#pragma unroll
  for (int nt = 0; nt < 2; ++nt) {
    int col = w * 32 + nt * 16 + fr;
    float bias = pb[col];
#pragma unroll
    for (int r = 0; r < 4; ++r) {
      int row = kg * 4 + r;
      float hv = acc[nt][r] + bias;
      h_out[(n0 + row) * H + col] = hv;
      hb[row][col] = f2bf(hv);
    }
  }
  __syncthreads();
  f32x4 acc2[4];
#pragma unroll
  for (int nt = 0; nt < 4; ++nt) acc2[nt] = (f32x4){0.f, 0.f, 0.f, 0.f};
#pragma unroll
  for (int ks = 0; ks < 4; ++ks) {
    int k = ks * 32 + kg * 8;
    short8 a = *(const short8*)&hb[fr][k];
#pragma unroll
    for (int nt = 0; nt < 4; ++nt) {
      int col = w * 64 + nt * 16 + fr;
      short8 b = *(const short8*)&ew1T[col * H + k];
      acc2[nt] = __builtin_amdgcn_mfma_f32_16x16x32_bf16(a, b, acc2[nt], 0, 0, 0);
    }
  }
#pragma unroll
  for (int nt = 0; nt < 4; ++nt) {
    int col = w * 64 + nt * 16 + fr;
    float bias = (col < H) ? eb1[col] : 0.0f;
#pragma unroll
    for (int r = 0; r < 4; ++r) {
      int row = kg * 4 + r;
      float val = acc2[nt][r] + bias;
      if (col < H) Abf[(n0 + row) * H + col] = f2bf(val);
      else Bbf[(n0 + row) * H + (col - H)] = f2bf(val);
    }
  }
}

// ---------------------------------------------------------------------------
// Edge phase, MFMA: 128 CSR positions per block. A/B gathered as bf16 uint4.
// ---------------------------------------------------------------------------
__global__ __launch_bounds__(256) void edge_mfma_kernel(
    const unsigned short* __restrict__ Abf, const unsigned short* __restrict__ Bbf,
    const float* __restrict__ p, const float* __restrict__ s,
    const int* __restrict__ csr_off, const int* __restrict__ eid,
    const int* __restrict__ dstof, const float* __restrict__ wr,
    const unsigned short* __restrict__ w2T, const float* __restrict__ eb2,
    const float* __restrict__ cw, const float* __restrict__ cbp,
    float* __restrict__ msA, float* __restrict__ msB,
    float* __restrict__ cuA, float* __restrict__ cuB) {
  __shared__ unsigned short t1s[TILE_E][136];  // t1 (bf16), later reused for m
  __shared__ float r2A[TILE_E], sA[TILE_E], dirA[TILE_E][3], gA[TILE_E];
  __shared__ float gpart[2][TILE_E];
  __shared__ int srcA[TILE_E], dstA[TILE_E];
  __shared__ float wrs[H], b2s[H], cws[H];

  int tid = threadIdx.x;
  int P0 = blockIdx.x * TILE_E;
  int P1 = P0 + TILE_E;

  if (tid < H) { wrs[tid] = wr[tid]; b2s[tid] = eb2[tid]; cws[tid] = cw[tid]; }
  if (tid < TILE_E) {
    int e = tid;
    int edge = eid[P0 + e];
    int src = edge >> 4;  // edge / KNN
    int d = dstof[P0 + e];
    srcA[e] = src;
    dstA[e] = d;
    float dx = p[d * 3 + 0] - p[src * 3 + 0];
    float dy = p[d * 3 + 1] - p[src * 3 + 1];
    float dz = p[d * 3 + 2] - p[src * 3 + 2];
    float r2 = dx * dx + dy * dy + dz * dz;
    r2A[e] = r2;
    float rinv = 1.0f / sqrtf(r2 + 1e-8f);
    dirA[e][0] = dx * rinv;
    dirA[e][1] = dy * rinv;
    dirA[e][2] = dz * rinv;
    sA[e] = s[src];
  }
  __syncthreads();

  int nA = dstA[0], nB = dstA[TILE_E - 1];
  int nn = nB - nA + 1;

  // stage 1: t1 tile (bf16); 8 cols per thread per iter, uint4 gathers
  for (int idx = tid; idx < TILE_E * 16; idx += 256) {
    int e = idx >> 4, cp = (idx & 15) * 8;
    uint4 au = *(const uint4*)&Abf[dstA[e] * H + cp];
    uint4 bu = *(const uint4*)&Bbf[srcA[e] * H + cp];
    float r2v = r2A[e];
    unsigned int as[4] = {au.x, au.y, au.z, au.w};
    unsigned int bs[4] = {bu.x, bu.y, bu.z, bu.w};
    unsigned int res[4];
#pragma unroll
    for (int q = 0; q < 4; ++q) {
      float pr0 = silu(bf2f((unsigned short)(as[q] & 0xffffu)) +
                       bf2f((unsigned short)(bs[q] & 0xffffu)) +
                       r2v * wrs[cp + 2 * q]);
      float pr1 = silu(bf2f((unsigned short)(as[q] >> 16)) +
                       bf2f((unsigned short)(bs[q] >> 16)) +
                       r2v * wrs[cp + 2 * q + 1]);
      res[q] = ((unsigned int)f2bf(pr1) << 16) | (unsigned int)f2bf(pr0);
    }
    *(uint4*)&t1s[e][cp] = make_uint4(res[0], res[1], res[2], res[3]);
  }
  __syncthreads();

  // stage 2: GEMM m_pre = t1 @ w2. Wave w -> out cols [w*32, w*32+32).
  int w = tid >> 6, lane = tid & 63;
  int fr = lane & 15, kg = lane >> 4;
  f32x4 acc[8][2];
#pragma unroll
  for (int mt = 0; mt < 8; ++mt)
#pragma unroll
    for (int nt = 0; nt < 2; ++nt) acc[mt][nt] = (f32x4){0.f, 0.f, 0.f, 0.f};
#pragma unroll
  for (int ks = 0; ks < 4; ++ks) {
    int k = ks * 32 + kg * 8;
    short8 bf0 = *(const short8*)&w2T[(w * 32 + fr) * H + k];
    short8 bf1 = *(const short8*)&w2T[(w * 32 + 16 + fr) * H + k];
#pragma unroll
    for (int mt = 0; mt < 8; ++mt) {
      short8 a = *(const short8*)&t1s[mt * 16 + fr][k];
      acc[mt][0] = __builtin_amdgcn_mfma_f32_16x16x32_bf16(a, bf0, acc[mt][0], 0, 0, 0);
      acc[mt][1] = __builtin_amdgcn_mfma_f32_16x16x32_bf16(a, bf1, acc[mt][1], 0, 0, 0);
    }
  }
  __syncthreads();  // all t1s reads done

  // epilogue: m = silu(acc + b2) * s[src] -> back into t1s (bf16)
#pragma unroll
  for (int mt = 0; mt < 8; ++mt) {
#pragma unroll
    for (int nt = 0; nt < 2; ++nt) {
      int col = w * 32 + nt * 16 + fr;
      float b2v = b2s[col];
#pragma unroll
      for (int r = 0; r < 4; ++r) {
        int row = mt * 16 + kg * 4 + r;
        float mv = silu(acc[mt][nt][r] + b2v) * sA[row];
        t1s[row][col] = f2bf(mv);
      }
    }
  }
  __syncthreads();

  // gamma per edge: 2 threads/row (64 cols each), LDS combine
  {
    int e = tid & 127, half = tid >> 7;
    int c0 = half * 64;
    float g = 0.f;
    for (int c = c0; c < c0 + 64; c += 4) {
      uint2 u = *(const uint2*)&t1s[e][c];
      g = fmaf(bf2f((unsigned short)(u.x & 0xffffu)), cws[c], g);
      g = fmaf(bf2f((unsigned short)(u.x >> 16)), cws[c + 1], g);
      g = fmaf(bf2f((unsigned short)(u.y & 0xffffu)), cws[c + 2], g);
      g = fmaf(bf2f((unsigned short)(u.y >> 16)), cws[c + 3], g);
    }
    gpart[half][e] = g;
  }
  __syncthreads();
  if (tid < TILE_E) gA[tid] = gpart[0][tid] + gpart[1][tid] + cbp[0];
  __syncthreads();

  // per-node partial msum -> slots (4 cols per item, float4 writes)
  for (int idx = tid; idx < nn * 32; idx += 256) {
    int ni = idx >> 5, cq = (idx & 31) * 4;
    int n = nA + ni;
    int o0 = csr_off[n], o1 = csr_off[n + 1];
    int lo = max(o0, P0), hi = min(o1, P1);
    float s0 = 0.f, s1 = 0.f, s2 = 0.f, s3 = 0.f;
    for (int pos = lo; pos < hi; ++pos) {
      uint2 u = *(const uint2*)&t1s[pos - P0][cq];
      s0 += bf2f((unsigned short)(u.x & 0xffffu));
      s1 += bf2f((unsigned short)(u.x >> 16));
      s2 += bf2f((unsigned short)(u.y & 0xffffu));
      s3 += bf2f((unsigned short)(u.y >> 16));
    }
    float4 sv = make_float4(s0, s1, s2, s3);
    if (o0 >= P0) {
      *(float4*)&msA[n * H + cq] = sv;
      if (o1 <= P1) *(float4*)&msB[n * H + cq] = make_float4(0.f, 0.f, 0.f, 0.f);
    } else {
      *(float4*)&msB[n * H + cq] = sv;
    }
  }
  // per-node partial cu -> slots
  for (int idx = tid; idx < nn * 3; idx += 256) {
    int ni = idx / 3, comp = idx - ni * 3;
    int n = nA + ni;
    int o0 = csr_off[n], o1 = csr_off[n + 1];
    int lo = max(o0, P0), hi = min(o1, P1);
    float sum = 0.f;
    for (int pos = lo; pos < hi; ++pos)
      sum += gA[pos - P0] * dirA[pos - P0][comp];
    if (o0 >= P0) {
      cuA[n * 3 + comp] = sum;
      if (o1 <= P1) cuB[n * 3 + comp] = 0.0f;
    } else {
      cuB[n * 3 + comp] = sum;
    }
  }
}

// ---------------------------------------------------------------------------
// Node update via MFMA: 16 nodes/block, 4 waves. GEMM1 (K=256) -> silu ->
// GEMM2 (K=128) -> h_out; optional fused next-layer A/B GEMM.
// ---------------------------------------------------------------------------
__global__ __launch_bounds__(256) void node_mfma_kernel(
    const float* __restrict__ h, const float* __restrict__ msA,
    const float* __restrict__ msB, const int* __restrict__ degi,
    const float* __restrict__ cuA, const float* __restrict__ cuB,
    const float* __restrict__ p_in, const unsigned short* __restrict__ w1T,
    const float* __restrict__ nb1, const unsigned short* __restrict__ w2T,
    const float* __restrict__ nb2, const unsigned short* __restrict__ ew1Tn,
    const float* __restrict__ eb1n, int doab, float* __restrict__ h_out,
    float* __restrict__ p_out, unsigned short* __restrict__ Abf,
    unsigned short* __restrict__ Bbf) {
  __shared__ unsigned short insb[16][264];
  __shared__ unsigned short hnsb[16][136];
  int tid = threadIdx.x;
  int n0 = blockIdx.x * 16;
  // staging: float4 loads, uint2 bf16 LDS writes (2 iters/thread)
  for (int idx = tid; idx < 16 * 32; idx += 256) {
    int n = idx >> 5, cq = (idx & 31) * 4;
    int gn = n0 + n;
    float4 hv = *(const float4*)&h[gn * H + cq];
    int dg = degi[gn];
    float m0 = 0.f, m1 = 0.f, m2 = 0.f, m3 = 0.f;
    if (dg > 0) {
      float4 a = *(const float4*)&msA[gn * H + cq];
      float4 b = *(const float4*)&msB[gn * H + cq];
      float fdg = (float)dg;
      m0 = (a.x + b.x) / fdg;
      m1 = (a.y + b.y) / fdg;
      m2 = (a.z + b.z) / fdg;
      m3 = (a.w + b.w) / fdg;
    }
    uint2 uh, um;
    uh.x = ((unsigned int)f2bf(hv.y) << 16) | (unsigned int)f2bf(hv.x);
    uh.y = ((unsigned int)f2bf(hv.w) << 16) | (unsigned int)f2bf(hv.z);
    um.x = ((unsigned int)f2bf(m1) << 16) | (unsigned int)f2bf(m0);
    um.y = ((unsigned int)f2bf(m3) << 16) | (unsigned int)f2bf(m2);
    *(uint2*)&insb[n][cq] = uh;
    *(uint2*)&insb[n][H + cq] = um;
  }
  __syncthreads();
  int w = tid >> 6, lane = tid & 63, fr = lane & 15, kg = lane >> 4;
  f32x4 acc[2];
  acc[0] = (f32x4){0.f, 0.f, 0.f, 0.f};
  acc[1] = (f32x4){0.f, 0.f, 0.f, 0.f};
#pragma unroll
  for (int ks = 0; ks < 8; ++ks) {
    int k = ks * 32 + kg * 8;
    short8 a = *(const short8*)&insb[fr][k];
#pragma unroll
    for (int nt = 0; nt < 2; ++nt) {
      int col = w * 32 + nt * 16 + fr;
      short8 b = *(const short8*)&w1T[col * 256 + k];
      acc[nt] = __builtin_amdgcn_mfma_f32_16x16x32_bf16(a, b, acc[nt], 0, 0, 0);
    }
  }
#pragma unroll
  for (int nt = 0; nt < 2; ++nt) {
    int col = w * 32 + nt * 16 + fr;
    float b1 = nb1[col];
#pragma unroll
    for (int r = 0; r < 4; ++r) {
      int row = kg * 4 + r;
      hnsb[row][col] = f2bf(silu(acc[nt][r] + b1));
    }
  }
  __syncthreads();
  f32x4 acc2[2];
  acc2[0] = (f32x4){0.f, 0.f, 0.f, 0.f};
  acc2[1] = (f32x4){0.f, 0.f, 0.f, 0.f};
#pragma unroll
  for (int ks = 0; ks < 4; ++ks) {
    int k = ks * 32 + kg * 8;
    short8 a = *(const short8*)&hnsb[fr][k];
#pragma unroll
    for (int nt = 0; nt < 2; ++nt) {
      int col = w * 32 + nt * 16 + fr;
      short8 b = *(const short8*)&w2T[col * H + k];
      acc2[nt] = __builtin_amdgcn_mfma_f32_16x16x32_bf16(a, b, acc2[nt], 0, 0, 0);
    }
  }
  unsigned short (*hb)[136] = (unsigned short(*)[136])insb;
#pragma unroll
  for (int nt = 0; nt < 2; ++nt) {
    int col = w * 32 + nt * 16 + fr;
    float b2 = nb2[col];
#pragma unroll
    for (int r = 0; r < 4; ++r) {
      int row = kg * 4 + r;
      float hv = acc2[nt][r] + b2;
      h_out[(n0 + row) * H + col] = hv;
      hb[row][col] = f2bf(hv);
    }
  }
  if (tid < 48) {
    int nl = tid / 3, comp = tid - nl * 3;
    int gn = n0 + nl;
    int dg = degi[gn];
    float add = 0.0f;
    if (dg > 0)
      add = (cuA[gn * 3 + comp] + cuB[gn * 3 + comp]) / (float)dg;
    p_out[gn * 3 + comp] = p_in[gn * 3 + comp] + add;
  }
  if (doab) {
    __syncthreads();
    f32x4 acc3[4];
#pragma unroll
    for (int nt = 0; nt < 4; ++nt) acc3[nt] = (f32x4){0.f, 0.f, 0.f, 0.f};
#pragma unroll
    for (int ks = 0; ks < 4; ++ks) {
      int k = ks * 32 + kg * 8;
      short8 a = *(const short8*)&hb[fr][k];
#pragma unroll
      for (int nt = 0; nt < 4; ++nt) {
        int col = w * 64 + nt * 16 + fr;
        short8 b = *(const short8*)&ew1Tn[col * H + k];
        acc3[nt] = __builtin_amdgcn_mfma_f32_16x16x32_bf16(a, b, acc3[nt], 0, 0, 0);
      }
    }
#pragma unroll
    for (int nt = 0; nt < 4; ++nt) {
      int col = w * 64 + nt * 16 + fr;
      float bias = (col < H) ? eb1n[col] : 0.0f;
#pragma unroll
      for (int r = 0; r < 4; ++r) {
        int row = kg * 4 + r;
        float val = acc3[nt][r] + bias;
        if (col < H) Abf[(n0 + row) * H + col] = f2bf(val);
        else Bbf[(n0 + row) * H + (col - H)] = f2bf(val);
      }
    }
  }
}

// ---------------------------------------------------------------------------
// Output head via MFMA: 16 nodes/block.
// ---------------------------------------------------------------------------
__global__ __launch_bounds__(256) void out_mfma_kernel(
    const float* __restrict__ h, const float* __restrict__ p,
    const unsigned short* __restrict__ owT, const float* __restrict__ ecb,
    const float* __restrict__ efb, float* __restrict__ out) {
  __shared__ unsigned short hb[16][136];
  int tid = threadIdx.x;
  int n0 = blockIdx.x * 16;
  for (int idx = tid; idx < 16 * H; idx += 256) {
    int n = idx >> 7, c = idx & 127;
    hb[n][c] = f2bf(h[(n0 + n) * H + c]);
  }
  __syncthreads();
  int w = tid >> 6, lane = tid & 63, fr = lane & 15, kg = lane >> 4;
  int ntiles = (w == 0) ? 2 : 1;
  for (int tt = 0; tt < ntiles; ++tt) {
    int tile = (tt == 0) ? w : 4;
    f32x4 acc = (f32x4){0.f, 0.f, 0.f, 0.f};
    int col = tile * 16 + fr;
#pragma unroll
    for (int ks = 0; ks < 4; ++ks) {
      int k = ks * 32 + kg * 8;
      short8 a = *(const short8*)&hb[fr][k];
      short8 b = *(const short8*)&owT[col * H + k];
      acc = __builtin_amdgcn_mfma_f32_16x16x32_bf16(a, b, acc, 0, 0, 0);
    }
    if (col < 67) {
      float bias = (col < 3) ? ecb[col] : efb[col - 3];
#pragma unroll
      for (int r = 0; r < 4; ++r) {
        int row = kg * 4 + r;
        out[(n0 + row) * 70 + col] = acc[r] + bias;
      }
    }
  }
  if (tid < 48) {
    int nl = tid / 3, comp = tid - nl * 3;
    int gn = n0 + nl;
    out[gn * 70 + 67 + comp] = p[gn * 3 + comp];
  }
}

// ---------------------------------------------------------------------------
extern "C" void kernel_launch(void* const* d_in, const int* in_sizes, int n_in,
                              void* d_out, int out_size, void* d_ws, size_t ws_size,
                              hipStream_t stream) {
  const float* x = (const float*)d_in[0];
  const float* pos = (const float*)d_in[1];
  const float* t = (const float*)d_in[2];
  const float* s = (const float*)d_in[3];
  const float* pw = (const float*)d_in[4];
  const float* pb = (const float*)d_in[5];
  const float* ew1 = (const float*)d_in[6];
  const float* eb1 = (const float*)d_in[7];
  const float* ew2 = (const float*)d_in[8];
  const float* eb2 = (const float*)d_in[9];
  const float* nw1 = (const float*)d_in[10];
  const float* nb1 = (const float*)d_in[11];
  const float* nw2 = (const float*)d_in[12];
  const float* nb2 = (const float*)d_in[13];
  const float* cw = (const float*)d_in[14];
  const float* cb = (const float*)d_in[15];
  const float* ecw = (const float*)d_in[16];
  const float* ecb = (const float*)d_in[17];
  const float* efw = (const float*)d_in[18];
  const float* efb = (const float*)d_in[19];

  char* wp = (char*)d_ws;
  auto alloc = [&](size_t bytes) {
    char* r = wp;
    wp += (bytes + 255) & ~(size_t)255;
    return r;
  };
  float* h0 = (float*)alloc((size_t)N_NODES * H * 4);
  float* h1 = (float*)alloc((size_t)N_NODES * H * 4);
  unsigned short* Abf = (unsigned short*)alloc((size_t)N_NODES * H * 2);
  unsigned short* Bbf = (unsigned short*)alloc((size_t)N_NODES * H * 2);
  float* msAb = (float*)alloc((size_t)N_NODES * H * 4);
  float* msBb = (float*)alloc((size_t)N_NODES * H * 4);
  float* cuAb = (float*)alloc((size_t)N_NODES * 3 * 4);
  float* cuBb = (float*)alloc((size_t)N_NODES * 3 * 4);
  float* p0 = (float*)alloc((size_t)N_NODES * 3 * 4);
  float* p1 = (float*)alloc((size_t)N_NODES * 3 * 4);
  int* degi = (int*)alloc((size_t)N_NODES * 4);
  int* nbr = (int*)alloc((size_t)E_EDGES * 4);
  int* off = (int*)alloc((size_t)(N_NODES + 1) * 4);
  int* cursor = (int*)alloc((size_t)N_NODES * 4);
  int* eid = (int*)alloc((size_t)E_EDGES * 4);
  int* dstof = (int*)alloc((size_t)E_EDGES * 4);
  unsigned short* w2Tb = (unsigned short*)alloc((size_t)LAYERS * H * H * 2);
  unsigned short* nw1Tb = (unsigned short*)alloc((size_t)LAYERS * 2 * H * H * 2);
  unsigned short* nw2Tb = (unsigned short*)alloc((size_t)LAYERS * H * H * 2);
  unsigned short* ew1Tb = (unsigned short*)alloc((size_t)LAYERS * 2 * H * H * 2);
  unsigned short* pwTb = (unsigned short*)alloc((size_t)H * 96 * 2);
  unsigned short* owTb = (unsigned short*)alloc((size_t)80 * H * 2);

  // pos4 aliases msAb (first written by edge_mfma, after KNN is done)
  float4* pos4 = (float4*)msAb;

  wcvt_kernel<<<1624, 256, 0, stream>>>(ew2, nw1, nw2, ew1, pw, ecw, efw,
                                        w2Tb, nw1Tb, nw2Tb, ew1Tb, pwTb, owTb);
  pos4_kernel<<<(N_NODES + 255) / 256, 256, 0, stream>>>(pos, pos4, p0, degi);
  knn_kernel<<<N_NODES / 8, 256, 0, stream>>>(pos4, nbr, degi);
  scan_kernel<<<1, 1024, 0, stream>>>(degi, off, cursor);
  scatter_kernel<<<(E_EDGES + 255) / 256, 256, 0, stream>>>(nbr, cursor, eid, dstof);
  sort_kernel<<<(N_NODES + 255) / 256, 256, 0, stream>>>(off, eid);
  proj_ab_kernel<<<N_NODES / 16, 256, 0, stream>>>(x, s, t, pwTb, pb, ew1Tb, eb1,
                                                   h0, Abf, Bbf);

  float* hc = h0;
  float* hn = h1;
  float* pc = p0;
  float* pn = p1;
  for (int l = 0; l < LAYERS; ++l) {
    const float* ew1l = ew1 + (size_t)l * 257 * H;
    int doab = (l < LAYERS - 1) ? 1 : 0;
    edge_mfma_kernel<<<E_EDGES / TILE_E, 256, 0, stream>>>(
        Abf, Bbf, pc, s, off, eid, dstof, ew1l + 256 * H,
        w2Tb + (size_t)l * H * H, eb2 + l * H, cw + l * H, cb + l,
        msAb, msBb, cuAb, cuBb);
    node_mfma_kernel<<<N_NODES / 16, 256, 0, stream>>>(
        hc, msAb, msBb, degi, cuAb, cuBb, pc, nw1Tb + (size_t)l * 2 * H * H,
        nb1 + l * H, nw2Tb + (size_t)l * H * H, nb2 + l * H,
        ew1Tb + (size_t)(l + doab) * 2 * H * H, eb1 + (size_t)(l + doab) * H,
        doab, hn, pn, Abf, Bbf);
    float* tmp = hc; hc = hn; hn = tmp;
    tmp = pc; pc = pn; pn = tmp;
  }
  out_mfma_kernel<<<N_NODES / 16, 256, 0, stream>>>(hc, pc, owTb, ecb, efb,
                                                    (float*)d_out);
}

// Round 11
// 400.991 us; speedup vs baseline: 1.6393x; 1.0006x over previous
//
#include <hip/hip_runtime.h>
#include <math.h>

#define N_NODES 10000
#define ND 64
#define H 128
#define LAYERS 4
#define KNN 16
#define TD 16
#define E_EDGES (N_NODES * KNN)
#define KC 1250    // knn candidates per LDS chunk (20 KB)
#define TILE_E 128 // edges per block in edge_mfma_kernel

typedef __attribute__((ext_vector_type(8))) short short8;
typedef __attribute__((ext_vector_type(4))) float f32x4;

__device__ __forceinline__ float silu(float x) {
  return x * __builtin_amdgcn_rcpf(1.0f + __expf(-x));
}

__device__ __forceinline__ unsigned short f2bf(float f) {
  unsigned int u = __float_as_uint(f);
  u += 0x7fffu + ((u >> 16) & 1u);  // RNE
  return (unsigned short)(u >> 16);
}
__device__ __forceinline__ float bf2f(unsigned short h) {
  return __uint_as_float(((unsigned int)h) << 16);
}

// ---------------------------------------------------------------------------
// pos4 precompute: [x,y,z,|p|^2]; also copies pos->p0 and zeroes degi.
// ---------------------------------------------------------------------------
__global__ __launch_bounds__(256) void pos4_kernel(const float* __restrict__ pos,
                                                   float4* __restrict__ pos4,
                                                   float* __restrict__ p0,
                                                   int* __restrict__ degi) {
  int i = blockIdx.x * 256 + threadIdx.x;
  if (i >= N_NODES) return;
  float x = pos[i * 3 + 0], y = pos[i * 3 + 1], z = pos[i * 3 + 2];
  pos4[i] = make_float4(x, y, z, x * x + y * y + z * z);
  p0[i * 3 + 0] = x;
  p0[i * 3 + 1] = y;
  p0[i * 3 + 2] = z;
  degi[i] = 0;
}

// ---------------------------------------------------------------------------
// Weight precast (bf16, transposed [out][in]). Big segments are src-linear.
// ---------------------------------------------------------------------------
__global__ __launch_bounds__(256) void wcvt_kernel(
    const float* __restrict__ ew2, const float* __restrict__ nw1,
    const float* __restrict__ nw2, const float* __restrict__ ew1,
    const float* __restrict__ pw, const float* __restrict__ ecw,
    const float* __restrict__ efw, unsigned short* __restrict__ w2T,
    unsigned short* __restrict__ nw1T, unsigned short* __restrict__ nw2T,
    unsigned short* __restrict__ ew1T, unsigned short* __restrict__ pwT,
    unsigned short* __restrict__ owT) {
  int i = blockIdx.x * 256 + threadIdx.x;  // 415744 total
  if (i < 65536) {
    int l = i >> 14, rem = i & 16383, c = rem >> 7, o = rem & 127;
    w2T[l * 16384 + o * 128 + c] = f2bf(ew2[i]);
  } else if (i < 196608) {
    int j = i - 65536;
    int l = j >> 15, rem = j & 32767, c2 = rem >> 7, o = rem & 127;
    nw1T[l * 32768 + o * 256 + c2] = f2bf(nw1[j]);
  } else if (i < 262144) {
    int j = i - 196608;
    int l = j >> 14, rem = j & 16383, c = rem >> 7, o = rem & 127;
    nw2T[l * 16384 + o * 128 + c] = f2bf(nw2[j]);
  } else if (i < 393216) {
    int j = i - 262144;
    int l = j >> 15, rem = j & 32767, r = rem >> 7, o = rem & 127;
    int o2 = o + ((r >> 7) << 7);
    int c = r & 127;
    ew1T[l * 32768 + o2 * 128 + c] = f2bf(ew1[l * 257 * 128 + r * 128 + o]);
  } else if (i < 405504) {
    int j = i - 393216;
    int o = j / 96, c = j - o * 96;
    pwT[j] = (c < 81) ? f2bf(pw[c * 128 + o]) : 0;
  } else {
    int j = i - 405504;
    int o = j >> 7, c = j & 127;
    float v = 0.0f;
    if (o < 3) v = ecw[c * 3 + o];
    else if (o < 67) v = efw[c * 64 + (o - 3)];
    owT[j] = f2bf(v);
  }
}

// ---------------------------------------------------------------------------
// KNN: 2 queries per wave (8/block, 1250 blocks). Top-17 distributed in
// lanes 0..16 (sorted asc) INCLUDING self (d' = |pj|^2 - 2 pi.pj makes self
// the strict global min -> lane 0; neighbors lanes 1..16). 256 cands/round.
// Insert chain shortened: threshold refreshed ONCE PER GROUP (not per
// insert) and no per-insert recheck — inserting a stale non-qualifying
// value is a no-op in the branchless sorted insert (all lanes keep v<=db),
// so selection and tie semantics are unchanged (ascending chunk/group/lane
// order + strict < + stay-on-equal = lowest-index-wins). Fused deg count.
// ---------------------------------------------------------------------------
#define DIST2(pp, d0, d1)                                                    \
  d0 = fmaf(ax0, (pp).x, fmaf(ay0, (pp).y, fmaf(az0, (pp).z, (pp).w)));      \
  d1 = fmaf(ax1, (pp).x, fmaf(ay1, (pp).y, fmaf(az1, (pp).z, (pp).w)));

#define PAIR(dv0, dv1, gbase)                                                \
  {                                                                          \
    unsigned long long m0 = __ballot((dv0) < th0);                           \
    unsigned long long m1 = __ballot((dv1) < th1);                           \
    if (m0 | m1) {                                                           \
      while (m0 | m1) {                                                      \
        if (m0) {                                                            \
          int sl = __ffsll((long long)m0) - 1;                               \
          m0 &= m0 - 1;                                                      \
          float db = __shfl((dv0), sl, 64);                                  \
          int gj = (gbase) + sl;                                             \
          float pv = __shfl_up(v0, 1, 64);                                   \
          int pid = __shfl_up(id0, 1, 64);                                   \
          bool stay = (v0 <= db);                                            \
          bool tk = (lane == 0) || (pv <= db);                               \
          v0 = stay ? v0 : (tk ? db : pv);                                   \
          id0 = stay ? id0 : (tk ? gj : pid);                                \
        }                                                                    \
        if (m1) {                                                            \
          int sl = __ffsll((long long)m1) - 1;                               \
          m1 &= m1 - 1;                                                      \
          float db = __shfl((dv1), sl, 64);                                  \
          int gj = (gbase) + sl;                                             \
          float pv = __shfl_up(v1, 1, 64);                                   \
          int pid = __shfl_up(id1, 1, 64);                                   \
          bool stay = (v1 <= db);                                            \
          bool tk = (lane == 0) || (pv <= db);                               \
          v1 = stay ? v1 : (tk ? db : pv);                                   \
          id1 = stay ? id1 : (tk ? gj : pid);                                \
        }                                                                    \
      }                                                                      \
      th0 = __shfl(v0, 16, 64);                                              \
      th1 = __shfl(v1, 16, 64);                                              \
    }                                                                        \
  }

__global__ __launch_bounds__(256) void knn_kernel(const float4* __restrict__ pos4,
                                                  int* __restrict__ nbr,
                                                  int* __restrict__ degi) {
  __shared__ float4 C[KC];
  int tid = threadIdx.x;
  int lane = tid & 63;
  int wid = tid >> 6;
  int qb = blockIdx.x * 8 + wid * 2;
  float4 q0 = pos4[qb];
  float4 q1 = pos4[qb + 1];
  float ax0 = -2.0f * q0.x, ay0 = -2.0f * q0.y, az0 = -2.0f * q0.z;
  float ax1 = -2.0f * q1.x, ay1 = -2.0f * q1.y, az1 = -2.0f * q1.z;
  float v0 = __builtin_inff(), v1 = __builtin_inff();
  int id0 = 0, id1 = 0;
  float th0 = __builtin_inff(), th1 = __builtin_inff();
  for (int base = 0; base < N_NODES; base += KC) {
    __syncthreads();
    for (int jj = tid; jj < KC; jj += 256) C[jj] = pos4[base + jj];
    __syncthreads();
    // 4 guard-free full rounds (j0 = 0,256,512,768)
    for (int j0 = 0; j0 < 1024; j0 += 256) {
      float4 pA = C[j0 + lane], pB = C[j0 + 64 + lane];
      float4 pC = C[j0 + 128 + lane], pD = C[j0 + 192 + lane];
      float dA0, dA1, dB0, dB1, dC0, dC1, dD0, dD1;
      DIST2(pA, dA0, dA1);
      DIST2(pB, dB0, dB1);
      DIST2(pC, dC0, dC1);
      DIST2(pD, dD0, dD1);
      float mn0 = fminf(fminf(dA0, dB0), fminf(dC0, dD0));
      float mn1 = fminf(fminf(dA1, dB1), fminf(dC1, dD1));
      if (__ballot((mn0 < th0) | (mn1 < th1))) {
        int gb = base + j0;
        PAIR(dA0, dA1, gb);
        PAIR(dB0, dB1, gb + 64);
        PAIR(dC0, dC1, gb + 128);
        PAIR(dD0, dD1, gb + 192);
      }
    }
    // tail round j0=1024: A,B,C full; D partial (34 lanes)
    {
      float4 pA = C[1024 + lane], pB = C[1088 + lane], pC = C[1152 + lane];
      float dA0, dA1, dB0, dB1, dC0, dC1;
      float dD0 = __builtin_inff(), dD1 = __builtin_inff();
      DIST2(pA, dA0, dA1);
      DIST2(pB, dB0, dB1);
      DIST2(pC, dC0, dC1);
      if (lane < 34) {
        float4 pD = C[1216 + lane];
        DIST2(pD, dD0, dD1);
      }
      float mn0 = fminf(fminf(dA0, dB0), fminf(dC0, dD0));
      float mn1 = fminf(fminf(dA1, dB1), fminf(dC1, dD1));
      if (__ballot((mn0 < th0) | (mn1 < th1))) {
        int gb = base + 1024;
        PAIR(dA0, dA1, gb);
        PAIR(dB0, dB1, gb + 64);
        PAIR(dC0, dC1, gb + 128);
        PAIR(dD0, dD1, gb + 192);
      }
    }
  }
  if (lane >= 1 && lane < 17) {
    nbr[qb * KNN + lane - 1] = id0;
    atomicAdd(&degi[id0], 1);
    nbr[(qb + 1) * KNN + lane - 1] = id1;
    atomicAdd(&degi[id1], 1);
  }
}

// ---------------------------------------------------------------------------
// CSR build (deterministic): scan -> scatter(+dstof) -> per-node sort
// ---------------------------------------------------------------------------
__global__ __launch_bounds__(1024) void scan_kernel(const int* __restrict__ degi,
                                                    int* __restrict__ off,
                                                    int* __restrict__ cursor) {
  __shared__ int part[1024];
  int t = threadIdx.x;
  int base = t * 10;
  int sum = 0;
  if (t < 1000)
    for (int i = 0; i < 10; ++i) sum += degi[base + i];
  part[t] = sum;
  __syncthreads();
  for (int stp = 1; stp < 1024; stp <<= 1) {
    int v = (t >= stp) ? part[t - stp] : 0;
    __syncthreads();
    part[t] += v;
    __syncthreads();
  }
  if (t < 1000) {
    int run = (t == 0) ? 0 : part[t - 1];
    for (int i = 0; i < 10; ++i) {
      off[base + i] = run;
      cursor[base + i] = run;
      run += degi[base + i];
    }
  }
  if (t == 0) off[N_NODES] = E_EDGES;
}

__global__ void scatter_kernel(const int* __restrict__ nbr, int* __restrict__ cursor,
                               int* __restrict__ eid, int* __restrict__ dstof) {
  int e = blockIdx.x * 256 + threadIdx.x;
  if (e < E_EDGES) {
    int d = nbr[e];
    int p = atomicAdd(&cursor[d], 1);
    eid[p] = e;
    dstof[p] = d;
  }
}

__global__ void sort_kernel(const int* __restrict__ off, int* __restrict__ eid) {
  int n = blockIdx.x * 256 + threadIdx.x;
  if (n >= N_NODES) return;
  int a = off[n], b = off[n + 1];
  for (int i = a + 1; i < b; ++i) {
    int v = eid[i];
    int j = i - 1;
    while (j >= a && eid[j] > v) { eid[j + 1] = eid[j]; --j; }
    eid[j + 1] = v;
  }
}

// ---------------------------------------------------------------------------
// Fused proj + layer-0 A/B, MFMA. 16 nodes/block, 4 waves.
// ---------------------------------------------------------------------------
__global__ __launch_bounds__(256) void proj_ab_kernel(
    const float* __restrict__ x, const float* __restrict__ s,
    const float* __restrict__ tptr, const unsigned short* __restrict__ pwT,
    const float* __restrict__ pb, const unsigned short* __restrict__ ew1T,
    const float* __restrict__ eb1, float* __restrict__ h_out,
    unsigned short* __restrict__ Abf, unsigned short* __restrict__ Bbf) {
  __shared__ unsigned short inpb[16][104];
  __shared__ unsigned short hb[16][136];
  int tid = threadIdx.x;
  int n0 = blockIdx.x * 16;
  float t = tptr[0];
  for (int idx = tid; idx < 16 * 104; idx += 256) {
    int n = idx / 104, c = idx - n * 104;
    int gn = n0 + n;
    float val;
    if (c < 64) val = x[gn * ND + c];
    else if (c == 64) val = s[gn];
    else if (c < 81) {
      int j = c - 65;
      int jj = (j < 8) ? j : (j - 8);
      float f = __expf(-4.0f * (float)jj / 7.0f);
      float a = t * f;
      val = (j < 8) ? sinf(a) : cosf(a);
    } else val = 0.0f;
    inpb[n][c] = f2bf(val);
  }
  __syncthreads();
  int w = tid >> 6, lane = tid & 63, fr = lane & 15, kg = lane >> 4;
  f32x4 acc[2];
  acc[0] = (f32x4){0.f, 0.f, 0.f, 0.f};
  acc[1] = (f32x4){0.f, 0.f, 0.f, 0.f};
#pragma unroll
  for (int ks = 0; ks < 3; ++ks) {
    int k = ks * 32 + kg * 8;
    short8 a = *(const short8*)&inpb[fr][k];
#pragma unroll
    for (int nt = 0; nt < 2; ++nt) {
      int col = w * 32 + nt * 16 + fr;
      short8 b = *(const short8*)&pwT[col * 96 + k];
      acc[nt] = __builtin_amdgcn_mfma_f32_16x16x32_bf16(a, b, acc[nt], 0, 0, 0);
    }
  }
#pragma unroll
  for (int nt = 0; nt < 2; ++nt) {
    int col = w * 32 + nt * 16 + fr;
    float bias = pb[col];
#pragma unroll
    for (int r = 0; r < 4; ++r) {
      int row = kg * 4 + r;
      float hv = acc[nt][r] + bias;
      h_out[(n0 + row) * H + col] = hv;
      hb[row][col] = f2bf(hv);
    }
  }
  __syncthreads();
  f32x4 acc2[4];
#pragma unroll
  for (int nt = 0; nt < 4; ++nt) acc2[nt] = (f32x4){0.f, 0.f, 0.f, 0.f};
#pragma unroll
  for (int ks = 0; ks < 4; ++ks) {
    int k = ks * 32 + kg * 8;
    short8 a = *(const short8*)&hb[fr][k];
#pragma unroll
    for (int nt = 0; nt < 4; ++nt) {
      int col = w * 64 + nt * 16 + fr;
      short8 b = *(const short8*)&ew1T[col * H + k];
      acc2[nt] = __builtin_amdgcn_mfma_f32_16x16x32_bf16(a, b, acc2[nt], 0, 0, 0);
    }
  }
#pragma unroll
  for (int nt = 0; nt < 4; ++nt) {
    int col = w * 64 + nt * 16 + fr;
    float bias = (col < H) ? eb1[col] : 0.0f;
#pragma unroll
    for (int r = 0; r < 4; ++r) {
      int row = kg * 4 + r;
      float val = acc2[nt][r] + bias;
      if (col < H) Abf[(n0 + row) * H + col] = f2bf(val);
      else Bbf[(n0 + row) * H + (col - H)] = f2bf(val);
    }
  }
}

// ---------------------------------------------------------------------------
// Edge phase, MFMA: 128 CSR positions per block. A/B gathered as bf16 uint4.
// ---------------------------------------------------------------------------
__global__ __launch_bounds__(256) void edge_mfma_kernel(
    const unsigned short* __restrict__ Abf, const unsigned short* __restrict__ Bbf,
    const float* __restrict__ p, const float* __restrict__ s,
    const int* __restrict__ csr_off, const int* __restrict__ eid,
    const int* __restrict__ dstof, const float* __restrict__ wr,
    const unsigned short* __restrict__ w2T, const float* __restrict__ eb2,
    const float* __restrict__ cw, const float* __restrict__ cbp,
    float* __restrict__ msA, float* __restrict__ msB,
    float* __restrict__ cuA, float* __restrict__ cuB) {
  __shared__ unsigned short t1s[TILE_E][136];  // t1 (bf16), later reused for m
  __shared__ float r2A[TILE_E], sA[TILE_E], dirA[TILE_E][3], gA[TILE_E];
  __shared__ float gpart[2][TILE_E];
  __shared__ int srcA[TILE_E], dstA[TILE_E];
  __shared__ float wrs[H], b2s[H], cws[H];

  int tid = threadIdx.x;
  int P0 = blockIdx.x * TILE_E;
  int P1 = P0 + TILE_E;

  if (tid < H) { wrs[tid] = wr[tid]; b2s[tid] = eb2[tid]; cws[tid] = cw[tid]; }
  if (tid < TILE_E) {
    int e = tid;
    int edge = eid[P0 + e];
    int src = edge >> 4;  // edge / KNN
    int d = dstof[P0 + e];
    srcA[e] = src;
    dstA[e] = d;
    float dx = p[d * 3 + 0] - p[src * 3 + 0];
    float dy = p[d * 3 + 1] - p[src * 3 + 1];
    float dz = p[d * 3 + 2] - p[src * 3 + 2];
    float r2 = dx * dx + dy * dy + dz * dz;
    r2A[e] = r2;
    float rinv = 1.0f / sqrtf(r2 + 1e-8f);
    dirA[e][0] = dx * rinv;
    dirA[e][1] = dy * rinv;
    dirA[e][2] = dz * rinv;
    sA[e] = s[src];
  }
  __syncthreads();

  int nA = dstA[0], nB = dstA[TILE_E - 1];
  int nn = nB - nA + 1;

  // stage 1: t1 tile (bf16); 8 cols per thread per iter, uint4 gathers
  for (int idx = tid; idx < TILE_E * 16; idx += 256) {
    int e = idx >> 4, cp = (idx & 15) * 8;
    uint4 au = *(const uint4*)&Abf[dstA[e] * H + cp];
    uint4 bu = *(const uint4*)&Bbf[srcA[e] * H + cp];
    float r2v = r2A[e];
    unsigned int as[4] = {au.x, au.y, au.z, au.w};
    unsigned int bs[4] = {bu.x, bu.y, bu.z, bu.w};
    unsigned int res[4];
#pragma unroll
    for (int q = 0; q < 4; ++q) {
      float pr0 = silu(bf2f((unsigned short)(as[q] & 0xffffu)) +
                       bf2f((unsigned short)(bs[q] & 0xffffu)) +
                       r2v * wrs[cp + 2 * q]);
      float pr1 = silu(bf2f((unsigned short)(as[q] >> 16)) +
                       bf2f((unsigned short)(bs[q] >> 16)) +
                       r2v * wrs[cp + 2 * q + 1]);
      res[q] = ((unsigned int)f2bf(pr1) << 16) | (unsigned int)f2bf(pr0);
    }
    *(uint4*)&t1s[e][cp] = make_uint4(res[0], res[1], res[2], res[3]);
  }
  __syncthreads();

  // stage 2: GEMM m_pre = t1 @ w2. Wave w -> out cols [w*32, w*32+32).
  int w = tid >> 6, lane = tid & 63;
  int fr = lane & 15, kg = lane >> 4;
  f32x4 acc[8][2];
#pragma unroll
  for (int mt = 0; mt < 8; ++mt)
#pragma unroll
    for (int nt = 0; nt < 2; ++nt) acc[mt][nt] = (f32x4){0.f, 0.f, 0.f, 0.f};
#pragma unroll
  for (int ks = 0; ks < 4; ++ks) {
    int k = ks * 32 + kg * 8;
    short8 bf0 = *(const short8*)&w2T[(w * 32 + fr) * H + k];
    short8 bf1 = *(const short8*)&w2T[(w * 32 + 16 + fr) * H + k];
#pragma unroll
    for (int mt = 0; mt < 8; ++mt) {
      short8 a = *(const short8*)&t1s[mt * 16 + fr][k];
      acc[mt][0] = __builtin_amdgcn_mfma_f32_16x16x32_bf16(a, bf0, acc[mt][0], 0, 0, 0);
      acc[mt][1] = __builtin_amdgcn_mfma_f32_16x16x32_bf16(a, bf1, acc[mt][1], 0, 0, 0);
    }
  }
  __syncthreads();  // all t1s reads done

  // epilogue: m = silu(acc + b2) * s[src] -> back into t1s (bf16)
#pragma unroll
  for (int mt = 0; mt < 8; ++mt) {
#pragma unroll
    for (int nt = 0; nt < 2; ++nt) {
      int col = w * 32 + nt * 16 + fr;
      float b2v = b2s[col];
#pragma unroll
      for (int r = 0; r < 4; ++r) {
        int row = mt * 16 + kg * 4 + r;
        float mv = silu(acc[mt][nt][r] + b2v) * sA[row];
        t1s[row][col] = f2bf(mv);
      }
    }
  }
  __syncthreads();

  // gamma per edge: 2 threads/row (64 cols each), LDS combine
  {
    int e = tid & 127, half = tid >> 7;
    int c0 = half * 64;
    float g = 0.f;
    for (int c = c0; c < c0 + 64; c += 4) {
      uint2 u = *(const uint2*)&t1s[e][c];
      g = fmaf(bf2f((unsigned short)(u.x & 0xffffu)), cws[c], g);
      g = fmaf(bf2f((unsigned short)(u.x >> 16)), cws[c + 1], g);
      g = fmaf(bf2f((unsigned short)(u.y & 0xffffu)), cws[c + 2], g);
      g = fmaf(bf2f((unsigned short)(u.y >> 16)), cws[c + 3], g);
    }
    gpart[half][e] = g;
  }
  __syncthreads();
  if (tid < TILE_E) gA[tid] = gpart[0][tid] + gpart[1][tid] + cbp[0];
  __syncthreads();

  // per-node partial msum -> slots (4 cols per item, float4 writes)
  for (int idx = tid; idx < nn * 32; idx += 256) {
    int ni = idx >> 5, cq = (idx & 31) * 4;
    int n = nA + ni;
    int o0 = csr_off[n], o1 = csr_off[n + 1];
    int lo = max(o0, P0), hi = min(o1, P1);
    float s0 = 0.f, s1 = 0.f, s2 = 0.f, s3 = 0.f;
    for (int pos = lo; pos < hi; ++pos) {
      uint2 u = *(const uint2*)&t1s[pos - P0][cq];
      s0 += bf2f((unsigned short)(u.x & 0xffffu));
      s1 += bf2f((unsigned short)(u.x >> 16));
      s2 += bf2f((unsigned short)(u.y & 0xffffu));
      s3 += bf2f((unsigned short)(u.y >> 16));
    }
    float4 sv = make_float4(s0, s1, s2, s3);
    if (o0 >= P0) {
      *(float4*)&msA[n * H + cq] = sv;
      if (o1 <= P1) *(float4*)&msB[n * H + cq] = make_float4(0.f, 0.f, 0.f, 0.f);
    } else {
      *(float4*)&msB[n * H + cq] = sv;
    }
  }
  // per-node partial cu -> slots
  for (int idx = tid; idx < nn * 3; idx += 256) {
    int ni = idx / 3, comp = idx - ni * 3;
    int n = nA + ni;
    int o0 = csr_off[n], o1 = csr_off[n + 1];
    int lo = max(o0, P0), hi = min(o1, P1);
    float sum = 0.f;
    for (int pos = lo; pos < hi; ++pos)
      sum += gA[pos - P0] * dirA[pos - P0][comp];
    if (o0 >= P0) {
      cuA[n * 3 + comp] = sum;
      if (o1 <= P1) cuB[n * 3 + comp] = 0.0f;
    } else {
      cuB[n * 3 + comp] = sum;
    }
  }
}

// ---------------------------------------------------------------------------
// Node update via MFMA: 16 nodes/block, 4 waves. GEMM1 (K=256) -> silu ->
// GEMM2 (K=128) -> h_out; optional fused next-layer A/B GEMM.
// ---------------------------------------------------------------------------
__global__ __launch_bounds__(256) void node_mfma_kernel(
    const float* __restrict__ h, const float* __restrict__ msA,
    const float* __restrict__ msB, const int* __restrict__ degi,
    const float* __restrict__ cuA, const float* __restrict__ cuB,
    const float* __restrict__ p_in, const unsigned short* __restrict__ w1T,
    const float* __restrict__ nb1, const unsigned short* __restrict__ w2T,
    const float* __restrict__ nb2, const unsigned short* __restrict__ ew1Tn,
    const float* __restrict__ eb1n, int doab, float* __restrict__ h_out,
    float* __restrict__ p_out, unsigned short* __restrict__ Abf,
    unsigned short* __restrict__ Bbf) {
  __shared__ unsigned short insb[16][264];
  __shared__ unsigned short hnsb[16][136];
  int tid = threadIdx.x;
  int n0 = blockIdx.x * 16;
  // staging: float4 loads, uint2 bf16 LDS writes (2 iters/thread)
  for (int idx = tid; idx < 16 * 32; idx += 256) {
    int n = idx >> 5, cq = (idx & 31) * 4;
    int gn = n0 + n;
    float4 hv = *(const float4*)&h[gn * H + cq];
    int dg = degi[gn];
    float m0 = 0.f, m1 = 0.f, m2 = 0.f, m3 = 0.f;
    if (dg > 0) {
      float4 a = *(const float4*)&msA[gn * H + cq];
      float4 b = *(const float4*)&msB[gn * H + cq];
      float fdg = (float)dg;
      m0 = (a.x + b.x) / fdg;
      m1 = (a.y + b.y) / fdg;
      m2 = (a.z + b.z) / fdg;
      m3 = (a.w + b.w) / fdg;
    }
    uint2 uh, um;
    uh.x = ((unsigned int)f2bf(hv.y) << 16) | (unsigned int)f2bf(hv.x);
    uh.y = ((unsigned int)f2bf(hv.w) << 16) | (unsigned int)f2bf(hv.z);
    um.x = ((unsigned int)f2bf(m1) << 16) | (unsigned int)f2bf(m0);
    um.y = ((unsigned int)f2bf(m3) << 16) | (unsigned int)f2bf(m2);
    *(uint2*)&insb[n][cq] = uh;
    *(uint2*)&insb[n][H + cq] = um;
  }
  __syncthreads();
  int w = tid >> 6, lane = tid & 63, fr = lane & 15, kg = lane >> 4;
  f32x4 acc[2];
  acc[0] = (f32x4){0.f, 0.f, 0.f, 0.f};
  acc[1] = (f32x4){0.f, 0.f, 0.f, 0.f};
#pragma unroll
  for (int ks = 0; ks < 8; ++ks) {
    int k = ks * 32 + kg * 8;
    short8 a = *(const short8*)&insb[fr][k];
#pragma unroll
    for (int nt = 0; nt < 2; ++nt) {
      int col = w * 32 + nt * 16 + fr;
      short8 b = *(const short8*)&w1T[col * 256 + k];
      acc[nt] = __builtin_amdgcn_mfma_f32_16x16x32_bf16(a, b, acc[nt], 0, 0, 0);
    }
  }
#pragma unroll
  for (int nt = 0; nt < 2; ++nt) {
    int col = w * 32 + nt * 16 + fr;
    float b1 = nb1[col];
#pragma unroll
    for (int r = 0; r < 4; ++r) {
      int row = kg * 4 + r;
      hnsb[row][col] = f2bf(silu(acc[nt][r] + b1));
    }
  }
  __syncthreads();
  f32x4 acc2[2];
  acc2[0] = (f32x4){0.f, 0.f, 0.f, 0.f};
  acc2[1] = (f32x4){0.f, 0.f, 0.f, 0.f};
#pragma unroll
  for (int ks = 0; ks < 4; ++ks) {
    int k = ks * 32 + kg * 8;
    short8 a = *(const short8*)&hnsb[fr][k];
#pragma unroll
    for (int nt = 0; nt < 2; ++nt) {
      int col = w * 32 + nt * 16 + fr;
      short8 b = *(const short8*)&w2T[col * H + k];
      acc2[nt] = __builtin_amdgcn_mfma_f32_16x16x32_bf16(a, b, acc2[nt], 0, 0, 0);
    }
  }
  unsigned short (*hb)[136] = (unsigned short(*)[136])insb;
#pragma unroll
  for (int nt = 0; nt < 2; ++nt) {
    int col = w * 32 + nt * 16 + fr;
    float b2 = nb2[col];
#pragma unroll
    for (int r = 0; r < 4; ++r) {
      int row = kg * 4 + r;
      float hv = acc2[nt][r] + b2;
      h_out[(n0 + row) * H + col] = hv;
      hb[row][col] = f2bf(hv);
    }
  }
  if (tid < 48) {
    int nl = tid / 3, comp = tid - nl * 3;
    int gn = n0 + nl;
    int dg = degi[gn];
    float add = 0.0f;
    if (dg > 0)
      add = (cuA[gn * 3 + comp] + cuB[gn * 3 + comp]) / (float)dg;
    p_out[gn * 3 + comp] = p_in[gn * 3 + comp] + add;
  }
  if (doab) {
    __syncthreads();
    f32x4 acc3[4];
#pragma unroll
    for (int nt = 0; nt < 4; ++nt) acc3[nt] = (f32x4){0.f, 0.f, 0.f, 0.f};
#pragma unroll
    for (int ks = 0; ks < 4; ++ks) {
      int k = ks * 32 + kg * 8;
      short8 a = *(const short8*)&hb[fr][k];
#pragma unroll
      for (int nt = 0; nt < 4; ++nt) {
        int col = w * 64 + nt * 16 + fr;
        short8 b = *(const short8*)&ew1Tn[col * H + k];
        acc3[nt] = __builtin_amdgcn_mfma_f32_16x16x32_bf16(a, b, acc3[nt], 0, 0, 0);
      }
    }
#pragma unroll
    for (int nt = 0; nt < 4; ++nt) {
      int col = w * 64 + nt * 16 + fr;
      float bias = (col < H) ? eb1n[col] : 0.0f;
#pragma unroll
      for (int r = 0; r < 4; ++r) {
        int row = kg * 4 + r;
        float val = acc3[nt][r] + bias;
        if (col < H) Abf[(n0 + row) * H + col] = f2bf(val);
        else Bbf[(n0 + row) * H + (col - H)] = f2bf(val);
      }
    }
  }
}

// ---------------------------------------------------------------------------
// Output head via MFMA: 16 nodes/block.
// ---------------------------------------------------------------------------
__global__ __launch_bounds__(256) void out_mfma_kernel(
    const float* __restrict__ h, const float* __restrict__ p,
    const unsigned short* __restrict__ owT, const float* __restrict__ ecb,
    const float* __restrict__ efb, float* __restrict__ out) {
  __shared__ unsigned short hb[16][136];
  int tid = threadIdx.x;
  int n0 = blockIdx.x * 16;
  for (int idx = tid; idx < 16 * H; idx += 256) {
    int n = idx >> 7, c = idx & 127;
    hb[n][c] = f2bf(h[(n0 + n) * H + c]);
  }
  __syncthreads();
  int w = tid >> 6, lane = tid & 63, fr = lane & 15, kg = lane >> 4;
  int ntiles = (w == 0) ? 2 : 1;
  for (int tt = 0; tt < ntiles; ++tt) {
    int tile = (tt == 0) ? w : 4;
    f32x4 acc = (f32x4){0.f, 0.f, 0.f, 0.f};
    int col = tile * 16 + fr;
#pragma unroll
    for (int ks = 0; ks < 4; ++ks) {
      int k = ks * 32 + kg * 8;
      short8 a = *(const short8*)&hb[fr][k];
      short8 b = *(const short8*)&owT[col * H + k];
      acc = __builtin_amdgcn_mfma_f32_16x16x32_bf16(a, b, acc, 0, 0, 0);
    }
    if (col < 67) {
      float bias = (col < 3) ? ecb[col] : efb[col - 3];
#pragma unroll
      for (int r = 0; r < 4; ++r) {
        int row = kg * 4 + r;
        out[(n0 + row) * 70 + col] = acc[r] + bias;
      }
    }
  }
  if (tid < 48) {
    int nl = tid / 3, comp = tid - nl * 3;
    int gn = n0 + nl;
    out[gn * 70 + 67 + comp] = p[gn * 3 + comp];
  }
}

// ---------------------------------------------------------------------------
extern "C" void kernel_launch(void* const* d_in, const int* in_sizes, int n_in,
                              void* d_out, int out_size, void* d_ws, size_t ws_size,
                              hipStream_t stream) {
  const float* x = (const float*)d_in[0];
  const float* pos = (const float*)d_in[1];
  const float* t = (const float*)d_in[2];
  const float* s = (const float*)d_in[3];
  const float* pw = (const float*)d_in[4];
  const float* pb = (const float*)d_in[5];
  const float* ew1 = (const float*)d_in[6];
  const float* eb1 = (const float*)d_in[7];
  const float* ew2 = (const float*)d_in[8];
  const float* eb2 = (const float*)d_in[9];
  const float* nw1 = (const float*)d_in[10];
  const float* nb1 = (const float*)d_in[11];
  const float* nw2 = (const float*)d_in[12];
  const float* nb2 = (const float*)d_in[13];
  const float* cw = (const float*)d_in[14];
  const float* cb = (const float*)d_in[15];
  const float* ecw = (const float*)d_in[16];
  const float* ecb = (const float*)d_in[17];
  const float* efw = (const float*)d_in[18];
  const float* efb = (const float*)d_in[19];

  char* wp = (char*)d_ws;
  auto alloc = [&](size_t bytes) {
    char* r = wp;
    wp += (bytes + 255) & ~(size_t)255;
    return r;
  };
  float* h0 = (float*)alloc((size_t)N_NODES * H * 4);
  float* h1 = (float*)alloc((size_t)N_NODES * H * 4);
  unsigned short* Abf = (unsigned short*)alloc((size_t)N_NODES * H * 2);
  unsigned short* Bbf = (unsigned short*)alloc((size_t)N_NODES * H * 2);
  float* msAb = (float*)alloc((size_t)N_NODES * H * 4);
  float* msBb = (float*)alloc((size_t)N_NODES * H * 4);
  float* cuAb = (float*)alloc((size_t)N_NODES * 3 * 4);
  float* cuBb = (float*)alloc((size_t)N_NODES * 3 * 4);
  float* p0 = (float*)alloc((size_t)N_NODES * 3 * 4);
  float* p1 = (float*)alloc((size_t)N_NODES * 3 * 4);
  int* degi = (int*)alloc((size_t)N_NODES * 4);
  int* nbr = (int*)alloc((size_t)E_EDGES * 4);
  int* off = (int*)alloc((size_t)(N_NODES + 1) * 4);
  int* cursor = (int*)alloc((size_t)N_NODES * 4);
  int* eid = (int*)alloc((size_t)E_EDGES * 4);
  int* dstof = (int*)alloc((size_t)E_EDGES * 4);
  unsigned short* w2Tb = (unsigned short*)alloc((size_t)LAYERS * H * H * 2);
  unsigned short* nw1Tb = (unsigned short*)alloc((size_t)LAYERS * 2 * H * H * 2);
  unsigned short* nw2Tb = (unsigned short*)alloc((size_t)LAYERS * H * H * 2);
  unsigned short* ew1Tb = (unsigned short*)alloc((size_t)LAYERS * 2 * H * H * 2);
  unsigned short* pwTb = (unsigned short*)alloc((size_t)H * 96 * 2);
  unsigned short* owTb = (unsigned short*)alloc((size_t)80 * H * 2);

  // pos4 aliases msAb (first written by edge_mfma, after KNN is done)
  float4* pos4 = (float4*)msAb;

  wcvt_kernel<<<1624, 256, 0, stream>>>(ew2, nw1, nw2, ew1, pw, ecw, efw,
                                        w2Tb, nw1Tb, nw2Tb, ew1Tb, pwTb, owTb);
  pos4_kernel<<<(N_NODES + 255) / 256, 256, 0, stream>>>(pos, pos4, p0, degi);
  knn_kernel<<<N_NODES / 8, 256, 0, stream>>>(pos4, nbr, degi);
  scan_kernel<<<1, 1024, 0, stream>>>(degi, off, cursor);
  scatter_kernel<<<(E_EDGES + 255) / 256, 256, 0, stream>>>(nbr, cursor, eid, dstof);
  sort_kernel<<<(N_NODES + 255) / 256, 256, 0, stream>>>(off, eid);
  proj_ab_kernel<<<N_NODES / 16, 256, 0, stream>>>(x, s, t, pwTb, pb, ew1Tb, eb1,
                                                   h0, Abf, Bbf);

  float* hc = h0;
  float* hn = h1;
  float* pc = p0;
  float* pn = p1;
  for (int l = 0; l < LAYERS; ++l) {
    const float* ew1l = ew1 + (size_t)l * 257 * H;
    int doab = (l < LAYERS - 1) ? 1 : 0;
    edge_mfma_kernel<<<E_EDGES / TILE_E, 256, 0, stream>>>(
        Abf, Bbf, pc, s, off, eid, dstof, ew1l + 256 * H,
        w2Tb + (size_t)l * H * H, eb2 + l * H, cw + l * H, cb + l,
        msAb, msBb, cuAb, cuBb);
    node_mfma_kernel<<<N_NODES / 16, 256, 0, stream>>>(
        hc, msAb, msBb, degi, cuAb, cuBb, pc, nw1Tb + (size_t)l * 2 * H * H,
        nb1 + l * H, nw2Tb + (size_t)l * H * H, nb2 + l * H,
        ew1Tb + (size_t)(l + doab) * 2 * H * H, eb1 + (size_t)(l + doab) * H,
        doab, hn, pn, Abf, Bbf);
    float* tmp = hc; hc = hn; hn = tmp;
    tmp = pc; pc = pn; pn = tmp;
  }
  out_mfma_kernel<<<N_NODES / 16, 256, 0, stream>>>(hc, pc, owTb, ecb, efb,
                                                    (float*)d_out);
}

// Round 12
// 369.531 us; speedup vs baseline: 1.7788x; 1.0851x over previous
//
#include <hip/hip_runtime.h>
#include <math.h>

#define N_NODES 10000
#define ND 64
#define H 128
#define LAYERS 4
#define KNN 16
#define TD 16
#define E_EDGES (N_NODES * KNN)
#define KC 1250    // knn candidates per LDS chunk (20 KB)
#define TILE_E 128 // edges per block in edge_mfma_kernel
#define INF __builtin_inff()

typedef __attribute__((ext_vector_type(8))) short short8;
typedef __attribute__((ext_vector_type(4))) float f32x4;

__device__ __forceinline__ float silu(float x) {
  return x * __builtin_amdgcn_rcpf(1.0f + __expf(-x));
}

__device__ __forceinline__ unsigned short f2bf(float f) {
  unsigned int u = __float_as_uint(f);
  u += 0x7fffu + ((u >> 16) & 1u);  // RNE
  return (unsigned short)(u >> 16);
}
__device__ __forceinline__ float bf2f(unsigned short h) {
  return __uint_as_float(((unsigned int)h) << 16);
}

// DPP row_shr:1 (within 16-lane rows) — VALU-pipe lane shift, ~2cy.
__device__ __forceinline__ float dpp_shr1_f(float x) {
  return __int_as_float(__builtin_amdgcn_update_dpp(
      0, __float_as_int(x), 0x111, 0xF, 0xF, true));
}
__device__ __forceinline__ int dpp_shr1_i(int x) {
  return __builtin_amdgcn_update_dpp(0, x, 0x111, 0xF, 0xF, true);
}
__device__ __forceinline__ float rdlane_f(float x, int sl) {
  return __int_as_float(__builtin_amdgcn_readlane(__float_as_int(x), sl));
}

// ---------------------------------------------------------------------------
// init: wcvt (blocks 0..1623) | pos4+p0copy+deg-zero (blocks 1624..1663)
// ---------------------------------------------------------------------------
__global__ __launch_bounds__(256) void init_kernel(
    const float* __restrict__ ew2, const float* __restrict__ nw1,
    const float* __restrict__ nw2, const float* __restrict__ ew1,
    const float* __restrict__ pw, const float* __restrict__ ecw,
    const float* __restrict__ efw, unsigned short* __restrict__ w2T,
    unsigned short* __restrict__ nw1T, unsigned short* __restrict__ nw2T,
    unsigned short* __restrict__ ew1T, unsigned short* __restrict__ pwT,
    unsigned short* __restrict__ owT, const float* __restrict__ pos,
    float4* __restrict__ pos4, float* __restrict__ p0,
    int* __restrict__ degi) {
  int bid = blockIdx.x;
  if (bid < 1624) {
    int i = bid * 256 + threadIdx.x;  // 415744 total
    if (i < 65536) {
      int l = i >> 14, rem = i & 16383, c = rem >> 7, o = rem & 127;
      w2T[l * 16384 + o * 128 + c] = f2bf(ew2[i]);
    } else if (i < 196608) {
      int j = i - 65536;
      int l = j >> 15, rem = j & 32767, c2 = rem >> 7, o = rem & 127;
      nw1T[l * 32768 + o * 256 + c2] = f2bf(nw1[j]);
    } else if (i < 262144) {
      int j = i - 196608;
      int l = j >> 14, rem = j & 16383, c = rem >> 7, o = rem & 127;
      nw2T[l * 16384 + o * 128 + c] = f2bf(nw2[j]);
    } else if (i < 393216) {
      int j = i - 262144;
      int l = j >> 15, rem = j & 32767, r = rem >> 7, o = rem & 127;
      int o2 = o + ((r >> 7) << 7);
      int c = r & 127;
      ew1T[l * 32768 + o2 * 128 + c] = f2bf(ew1[l * 257 * 128 + r * 128 + o]);
    } else if (i < 405504) {
      int j = i - 393216;
      int o = j / 96, c = j - o * 96;
      pwT[j] = (c < 81) ? f2bf(pw[c * 128 + o]) : 0;
    } else if (i < 415744) {
      int j = i - 405504;
      int o = j >> 7, c = j & 127;
      float v = 0.0f;
      if (o < 3) v = ecw[c * 3 + o];
      else if (o < 67) v = efw[c * 64 + (o - 3)];
      owT[j] = f2bf(v);
    }
  } else {
    int i = (bid - 1624) * 256 + threadIdx.x;
    if (i >= N_NODES) return;
    float x = pos[i * 3 + 0], y = pos[i * 3 + 1], z = pos[i * 3 + 2];
    pos4[i] = make_float4(x, y, z, x * x + y * y + z * z);
    p0[i * 3 + 0] = x;
    p0[i * 3 + 1] = y;
    p0[i * 3 + 2] = z;
    degi[i] = 0;
  }
}

// ---------------------------------------------------------------------------
// KNN: 2 queries per wave (8/block, 1250 blocks). Top-16 distributed sorted
// ascending in lanes 0..15. ALL cross-lane ops on the VALU pipe: DPP
// row_shr:1 for the insert shift, v_readlane for the passer broadcast and
// the per-group threshold refresh (SGPR compare operand). Self excluded by
// per-candidate index check. Ascending chunk/group/lane order + strict <
// gate + stay-on-equal = lowest-index-wins ties (round-8 proven semantics).
// Per-group threshold refresh: stale extra inserts are provable no-ops.
// Fused in-degree count.
// ---------------------------------------------------------------------------
#define DIST2(pp, d0, d1)                                                    \
  d0 = fmaf(ax0, (pp).x, fmaf(ay0, (pp).y, fmaf(az0, (pp).z, (pp).w)));      \
  d1 = fmaf(ax1, (pp).x, fmaf(ay1, (pp).y, fmaf(az1, (pp).z, (pp).w)));

#define INS1(dv, V, ID, gbase, mreg)                                         \
  if (mreg) {                                                                \
    int sl = __ffsll((long long)mreg) - 1;                                   \
    mreg &= mreg - 1;                                                        \
    float db = rdlane_f((dv), sl);                                           \
    int gj = (gbase) + sl;                                                   \
    float pv = dpp_shr1_f(V);                                                \
    int pid = dpp_shr1_i(ID);                                                \
    bool stay = ((V) <= db);                                                 \
    bool tk = (lane == 0) || (pv <= db);                                     \
    (V) = stay ? (V) : (tk ? db : pv);                                       \
    (ID) = stay ? (ID) : (tk ? gj : pid);                                    \
  }

#define PAIR(dv0, dv1, gbase)                                                \
  {                                                                          \
    unsigned long long m0 = __ballot((dv0) < th0);                           \
    unsigned long long m1 = __ballot((dv1) < th1);                           \
    if (m0 | m1) {                                                           \
      while (m0 | m1) {                                                      \
        INS1(dv0, v0, id0, gbase, m0);                                       \
        INS1(dv1, v1, id1, gbase, m1);                                       \
      }                                                                      \
      th0 = rdlane_f(v0, 15);                                                \
      th1 = rdlane_f(v1, 15);                                                \
    }                                                                        \
  }

__global__ __launch_bounds__(256) void knn_kernel(const float4* __restrict__ pos4,
                                                  int* __restrict__ nbr,
                                                  int* __restrict__ degi) {
  __shared__ float4 C[KC];
  int tid = threadIdx.x;
  int lane = tid & 63;
  int wid = tid >> 6;
  int qb = blockIdx.x * 8 + wid * 2;
  float4 q0 = pos4[qb];
  float4 q1 = pos4[qb + 1];
  float ax0 = -2.0f * q0.x, ay0 = -2.0f * q0.y, az0 = -2.0f * q0.z;
  float ax1 = -2.0f * q1.x, ay1 = -2.0f * q1.y, az1 = -2.0f * q1.z;
  float v0 = INF, v1 = INF;
  int id0 = 0, id1 = 0;
  float th0 = INF, th1 = INF;
  for (int base = 0; base < N_NODES; base += KC) {
    __syncthreads();
    for (int jj = tid; jj < KC; jj += 256) C[jj] = pos4[base + jj];
    __syncthreads();
    // 4 guard-free full rounds (j0 = 0,256,512,768)
    for (int j0 = 0; j0 < 1024; j0 += 256) {
      float4 pA = C[j0 + lane], pB = C[j0 + 64 + lane];
      float4 pC = C[j0 + 128 + lane], pD = C[j0 + 192 + lane];
      float dA0, dA1, dB0, dB1, dC0, dC1, dD0, dD1;
      DIST2(pA, dA0, dA1);
      DIST2(pB, dB0, dB1);
      DIST2(pC, dC0, dC1);
      DIST2(pD, dD0, dD1);
      int ga = base + j0 + lane;
      if (ga == qb) dA0 = INF;
      if (ga == qb + 1) dA1 = INF;
      if (ga + 64 == qb) dB0 = INF;
      if (ga + 64 == qb + 1) dB1 = INF;
      if (ga + 128 == qb) dC0 = INF;
      if (ga + 128 == qb + 1) dC1 = INF;
      if (ga + 192 == qb) dD0 = INF;
      if (ga + 192 == qb + 1) dD1 = INF;
      float mn0 = fminf(fminf(dA0, dB0), fminf(dC0, dD0));
      float mn1 = fminf(fminf(dA1, dB1), fminf(dC1, dD1));
      if (__ballot((mn0 < th0) | (mn1 < th1))) {
        int gb = base + j0;
        PAIR(dA0, dA1, gb);
        PAIR(dB0, dB1, gb + 64);
        PAIR(dC0, dC1, gb + 128);
        PAIR(dD0, dD1, gb + 192);
      }
    }
    // tail round j0=1024: A,B,C full; D partial (34 lanes)
    {
      float4 pA = C[1024 + lane], pB = C[1088 + lane], pC = C[1152 + lane];
      float dA0, dA1, dB0, dB1, dC0, dC1;
      float dD0 = INF, dD1 = INF;
      DIST2(pA, dA0, dA1);
      DIST2(pB, dB0, dB1);
      DIST2(pC, dC0, dC1);
      if (lane < 34) {
        float4 pD = C[1216 + lane];
        DIST2(pD, dD0, dD1);
      }
      int ga = base + 1024 + lane;
      if (ga == qb) dA0 = INF;
      if (ga == qb + 1) dA1 = INF;
      if (ga + 64 == qb) dB0 = INF;
      if (ga + 64 == qb + 1) dB1 = INF;
      if (ga + 128 == qb) dC0 = INF;
      if (ga + 128 == qb + 1) dC1 = INF;
      if (ga + 192 == qb) dD0 = INF;
      if (ga + 192 == qb + 1) dD1 = INF;
      float mn0 = fminf(fminf(dA0, dB0), fminf(dC0, dD0));
      float mn1 = fminf(fminf(dA1, dB1), fminf(dC1, dD1));
      if (__ballot((mn0 < th0) | (mn1 < th1))) {
        int gb = base + 1024;
        PAIR(dA0, dA1, gb);
        PAIR(dB0, dB1, gb + 64);
        PAIR(dC0, dC1, gb + 128);
        PAIR(dD0, dD1, gb + 192);
      }
    }
  }
  if (lane < KNN) {
    nbr[qb * KNN + lane] = id0;
    atomicAdd(&degi[id0], 1);
    nbr[(qb + 1) * KNN + lane] = id1;
    atomicAdd(&degi[id1], 1);
  }
}

// ---------------------------------------------------------------------------
// CSR build (deterministic): scan -> scatter(+dstof) -> per-node sort
// ---------------------------------------------------------------------------
__global__ __launch_bounds__(1024) void scan_kernel(const int* __restrict__ degi,
                                                    int* __restrict__ off,
                                                    int* __restrict__ cursor) {
  __shared__ int part[1024];
  int t = threadIdx.x;
  int base = t * 10;
  int sum = 0;
  if (t < 1000)
    for (int i = 0; i < 10; ++i) sum += degi[base + i];
  part[t] = sum;
  __syncthreads();
  for (int stp = 1; stp < 1024; stp <<= 1) {
    int v = (t >= stp) ? part[t - stp] : 0;
    __syncthreads();
    part[t] += v;
    __syncthreads();
  }
  if (t < 1000) {
    int run = (t == 0) ? 0 : part[t - 1];
    for (int i = 0; i < 10; ++i) {
      off[base + i] = run;
      cursor[base + i] = run;
      run += degi[base + i];
    }
  }
  if (t == 0) off[N_NODES] = E_EDGES;
}

__global__ void scatter_kernel(const int* __restrict__ nbr, int* __restrict__ cursor,
                               int* __restrict__ eid, int* __restrict__ dstof) {
  int e = blockIdx.x * 256 + threadIdx.x;
  if (e < E_EDGES) {
    int d = nbr[e];
    int p = atomicAdd(&cursor[d], 1);
    eid[p] = e;
    dstof[p] = d;
  }
}

// ---------------------------------------------------------------------------
// sort_proj: proj+layer0 A/B MFMA (blocks 0..624) | per-node eid sort (625..664)
// ---------------------------------------------------------------------------
__global__ __launch_bounds__(256) void sort_proj_kernel(
    const float* __restrict__ x, const float* __restrict__ s,
    const float* __restrict__ tptr, const unsigned short* __restrict__ pwT,
    const float* __restrict__ pb, const unsigned short* __restrict__ ew1T,
    const float* __restrict__ eb1, float* __restrict__ h_out,
    unsigned short* __restrict__ Abf, unsigned short* __restrict__ Bbf,
    const int* __restrict__ off, int* __restrict__ eid) {
  __shared__ unsigned short inpb[16][104];
  __shared__ unsigned short hb[16][136];
  int tid = threadIdx.x;
  int bid = blockIdx.x;
  if (bid >= 625) {
    int n = (bid - 625) * 256 + tid;
    if (n >= N_NODES) return;
    int a = off[n], b = off[n + 1];
    for (int i = a + 1; i < b; ++i) {
      int v = eid[i];
      int j = i - 1;
      while (j >= a && eid[j] > v) { eid[j + 1] = eid[j]; --j; }
      eid[j + 1] = v;
    }
    return;
  }
  int n0 = bid * 16;
  float t = tptr[0];
  for (int idx = tid; idx < 16 * 104; idx += 256) {
    int n = idx / 104, c = idx - n * 104;
    int gn = n0 + n;
    float val;
    if (c < 64) val = x[gn * ND + c];
    else if (c == 64) val = s[gn];
    else if (c < 81) {
      int j = c - 65;
      int jj = (j < 8) ? j : (j - 8);
      float f = __expf(-4.0f * (float)jj / 7.0f);
      float a = t * f;
      val = (j < 8) ? sinf(a) : cosf(a);
    } else val = 0.0f;
    inpb[n][c] = f2bf(val);
  }
  __syncthreads();
  int w = tid >> 6, lane = tid & 63, fr = lane & 15, kg = lane >> 4;
  f32x4 acc[2];
  acc[0] = (f32x4){0.f, 0.f, 0.f, 0.f};
  acc[1] = (f32x4){0.f, 0.f, 0.f, 0.f};
#pragma unroll
  for (int ks = 0; ks < 3; ++ks) {
    int k = ks * 32 + kg * 8;
    short8 a = *(const short8*)&inpb[fr][k];
#pragma unroll
    for (int nt = 0; nt < 2; ++nt) {
      int col = w * 32 + nt * 16 + fr;
      short8 b = *(const short8*)&pwT[col * 96 + k];
      acc[nt] = __builtin_amdgcn_mfma_f32_16x16x32_bf16(a, b, acc[nt], 0, 0, 0);
    }
  }
#pragma unroll
  for (int nt = 0; nt < 2; ++nt) {
    int col = w * 32 + nt * 16 + fr;
    float bias = pb[col];
#pragma unroll
    for (int r = 0; r < 4; ++r) {
      int row = kg * 4 + r;
      float hv = acc[nt][r] + bias;
      h_out[(n0 + row) * H + col] = hv;
      hb[row][col] = f2bf(hv);
    }
  }
  __syncthreads();
  f32x4 acc2[4];
#pragma unroll
  for (int nt = 0; nt < 4; ++nt) acc2[nt] = (f32x4){0.f, 0.f, 0.f, 0.f};
#pragma unroll
  for (int ks = 0; ks < 4; ++ks) {
    int k = ks * 32 + kg * 8;
    short8 a = *(const short8*)&hb[fr][k];
#pragma unroll
    for (int nt = 0; nt < 4; ++nt) {
      int col = w * 64 + nt * 16 + fr;
      short8 b = *(const short8*)&ew1T[col * H + k];
      acc2[nt] = __builtin_amdgcn_mfma_f32_16x16x32_bf16(a, b, acc2[nt], 0, 0, 0);
    }
  }
#pragma unroll
  for (int nt = 0; nt < 4; ++nt) {
    int col = w * 64 + nt * 16 + fr;
    float bias = (col < H) ? eb1[col] : 0.0f;
#pragma unroll
    for (int r = 0; r < 4; ++r) {
      int row = kg * 4 + r;
      float val = acc2[nt][r] + bias;
      if (col < H) Abf[(n0 + row) * H + col] = f2bf(val);
      else Bbf[(n0 + row) * H + (col - H)] = f2bf(val);
    }
  }
}

// ---------------------------------------------------------------------------
// Edge phase, MFMA: 128 CSR positions per block. A/B gathered as bf16 uint4.
// ---------------------------------------------------------------------------
__global__ __launch_bounds__(256) void edge_mfma_kernel(
    const unsigned short* __restrict__ Abf, const unsigned short* __restrict__ Bbf,
    const float* __restrict__ p, const float* __restrict__ s,
    const int* __restrict__ csr_off, const int* __restrict__ eid,
    const int* __restrict__ dstof, const float* __restrict__ wr,
    const unsigned short* __restrict__ w2T, const float* __restrict__ eb2,
    const float* __restrict__ cw, const float* __restrict__ cbp,
    float* __restrict__ msA, float* __restrict__ msB,
    float* __restrict__ cuA, float* __restrict__ cuB) {
  __shared__ unsigned short t1s[TILE_E][136];  // t1 (bf16), later reused for m
  __shared__ float r2A[TILE_E], sA[TILE_E], dirA[TILE_E][3], gA[TILE_E];
  __shared__ float gpart[2][TILE_E];
  __shared__ int srcA[TILE_E], dstA[TILE_E];
  __shared__ float wrs[H], b2s[H], cws[H];

  int tid = threadIdx.x;
  int P0 = blockIdx.x * TILE_E;
  int P1 = P0 + TILE_E;

  if (tid < H) { wrs[tid] = wr[tid]; b2s[tid] = eb2[tid]; cws[tid] = cw[tid]; }
  if (tid < TILE_E) {
    int e = tid;
    int edge = eid[P0 + e];
    int src = edge >> 4;  // edge / KNN
    int d = dstof[P0 + e];
    srcA[e] = src;
    dstA[e] = d;
    float dx = p[d * 3 + 0] - p[src * 3 + 0];
    float dy = p[d * 3 + 1] - p[src * 3 + 1];
    float dz = p[d * 3 + 2] - p[src * 3 + 2];
    float r2 = dx * dx + dy * dy + dz * dz;
    r2A[e] = r2;
    float rinv = 1.0f / sqrtf(r2 + 1e-8f);
    dirA[e][0] = dx * rinv;
    dirA[e][1] = dy * rinv;
    dirA[e][2] = dz * rinv;
    sA[e] = s[src];
  }
  __syncthreads();

  int nA = dstA[0], nB = dstA[TILE_E - 1];
  int nn = nB - nA + 1;

  // stage 1: t1 tile (bf16); 8 cols per thread per iter, uint4 gathers
  for (int idx = tid; idx < TILE_E * 16; idx += 256) {
    int e = idx >> 4, cp = (idx & 15) * 8;
    uint4 au = *(const uint4*)&Abf[dstA[e] * H + cp];
    uint4 bu = *(const uint4*)&Bbf[srcA[e] * H + cp];
    float r2v = r2A[e];
    unsigned int as[4] = {au.x, au.y, au.z, au.w};
    unsigned int bs[4] = {bu.x, bu.y, bu.z, bu.w};
    unsigned int res[4];
#pragma unroll
    for (int q = 0; q < 4; ++q) {
      float pr0 = silu(bf2f((unsigned short)(as[q] & 0xffffu)) +
                       bf2f((unsigned short)(bs[q] & 0xffffu)) +
                       r2v * wrs[cp + 2 * q]);
      float pr1 = silu(bf2f((unsigned short)(as[q] >> 16)) +
                       bf2f((unsigned short)(bs[q] >> 16)) +
                       r2v * wrs[cp + 2 * q + 1]);
      res[q] = ((unsigned int)f2bf(pr1) << 16) | (unsigned int)f2bf(pr0);
    }
    *(uint4*)&t1s[e][cp] = make_uint4(res[0], res[1], res[2], res[3]);
  }
  __syncthreads();

  // stage 2: GEMM m_pre = t1 @ w2. Wave w -> out cols [w*32, w*32+32).
  int w = tid >> 6, lane = tid & 63;
  int fr = lane & 15, kg = lane >> 4;
  f32x4 acc[8][2];
#pragma unroll
  for (int mt = 0; mt < 8; ++mt)
#pragma unroll
    for (int nt = 0; nt < 2; ++nt) acc[mt][nt] = (f32x4){0.f, 0.f, 0.f, 0.f};
#pragma unroll
  for (int ks = 0; ks < 4; ++ks) {
    int k = ks * 32 + kg * 8;
    short8 bf0 = *(const short8*)&w2T[(w * 32 + fr) * H + k];
    short8 bf1 = *(const short8*)&w2T[(w * 32 + 16 + fr) * H + k];
#pragma unroll
    for (int mt = 0; mt < 8; ++mt) {
      short8 a = *(const short8*)&t1s[mt * 16 + fr][k];
      acc[mt][0] = __builtin_amdgcn_mfma_f32_16x16x32_bf16(a, bf0, acc[mt][0], 0, 0, 0);
      acc[mt][1] = __builtin_amdgcn_mfma_f32_16x16x32_bf16(a, bf1, acc[mt][1], 0, 0, 0);
    }
  }
  __syncthreads();  // all t1s reads done

  // epilogue: m = silu(acc + b2) * s[src] -> back into t1s (bf16)
#pragma unroll
  for (int mt = 0; mt < 8; ++mt) {
#pragma unroll
    for (int nt = 0; nt < 2; ++nt) {
      int col = w * 32 + nt * 16 + fr;
      float b2v = b2s[col];
#pragma unroll
      for (int r = 0; r < 4; ++r) {
        int row = mt * 16 + kg * 4 + r;
        float mv = silu(acc[mt][nt][r] + b2v) * sA[row];
        t1s[row][col] = f2bf(mv);
      }
    }
  }
  __syncthreads();

  // gamma per edge: 2 threads/row (64 cols each), LDS combine
  {
    int e = tid & 127, half = tid >> 7;
    int c0 = half * 64;
    float g = 0.f;
    for (int c = c0; c < c0 + 64; c += 4) {
      uint2 u = *(const uint2*)&t1s[e][c];
      g = fmaf(bf2f((unsigned short)(u.x & 0xffffu)), cws[c], g);
      g = fmaf(bf2f((unsigned short)(u.x >> 16)), cws[c + 1], g);
      g = fmaf(bf2f((unsigned short)(u.y & 0xffffu)), cws[c + 2], g);
      g = fmaf(bf2f((unsigned short)(u.y >> 16)), cws[c + 3], g);
    }
    gpart[half][e] = g;
  }
  __syncthreads();
  if (tid < TILE_E) gA[tid] = gpart[0][tid] + gpart[1][tid] + cbp[0];
  __syncthreads();

  // per-node partial msum -> slots (4 cols per item, float4 writes)
  for (int idx = tid; idx < nn * 32; idx += 256) {
    int ni = idx >> 5, cq = (idx & 31) * 4;
    int n = nA + ni;
    int o0 = csr_off[n], o1 = csr_off[n + 1];
    int lo = max(o0, P0), hi = min(o1, P1);
    float s0 = 0.f, s1 = 0.f, s2 = 0.f, s3 = 0.f;
    for (int pos = lo; pos < hi; ++pos) {
      uint2 u = *(const uint2*)&t1s[pos - P0][cq];
      s0 += bf2f((unsigned short)(u.x & 0xffffu));
      s1 += bf2f((unsigned short)(u.x >> 16));
      s2 += bf2f((unsigned short)(u.y & 0xffffu));
      s3 += bf2f((unsigned short)(u.y >> 16));
    }
    float4 sv = make_float4(s0, s1, s2, s3);
    if (o0 >= P0) {
      *(float4*)&msA[n * H + cq] = sv;
      if (o1 <= P1) *(float4*)&msB[n * H + cq] = make_float4(0.f, 0.f, 0.f, 0.f);
    } else {
      *(float4*)&msB[n * H + cq] = sv;
    }
  }
  // per-node partial cu -> slots
  for (int idx = tid; idx < nn * 3; idx += 256) {
    int ni = idx / 3, comp = idx - ni * 3;
    int n = nA + ni;
    int o0 = csr_off[n], o1 = csr_off[n + 1];
    int lo = max(o0, P0), hi = min(o1, P1);
    float sum = 0.f;
    for (int pos = lo; pos < hi; ++pos)
      sum += gA[pos - P0] * dirA[pos - P0][comp];
    if (o0 >= P0) {
      cuA[n * 3 + comp] = sum;
      if (o1 <= P1) cuB[n * 3 + comp] = 0.0f;
    } else {
      cuB[n * 3 + comp] = sum;
    }
  }
}

// ---------------------------------------------------------------------------
// Node update via MFMA: 16 nodes/block, 4 waves. GEMM1 (K=256) -> silu ->
// GEMM2 (K=128) -> h_out; optional fused next-layer A/B GEMM.
// ---------------------------------------------------------------------------
__global__ __launch_bounds__(256) void node_mfma_kernel(
    const float* __restrict__ h, const float* __restrict__ msA,
    const float* __restrict__ msB, const int* __restrict__ degi,
    const float* __restrict__ cuA, const float* __restrict__ cuB,
    const float* __restrict__ p_in, const unsigned short* __restrict__ w1T,
    const float* __restrict__ nb1, const unsigned short* __restrict__ w2T,
    const float* __restrict__ nb2, const unsigned short* __restrict__ ew1Tn,
    const float* __restrict__ eb1n, int doab, float* __restrict__ h_out,
    float* __restrict__ p_out, unsigned short* __restrict__ Abf,
    unsigned short* __restrict__ Bbf) {
  __shared__ unsigned short insb[16][264];
  __shared__ unsigned short hnsb[16][136];
  int tid = threadIdx.x;
  int n0 = blockIdx.x * 16;
  // staging: float4 loads, uint2 bf16 LDS writes (2 iters/thread)
  for (int idx = tid; idx < 16 * 32; idx += 256) {
    int n = idx >> 5, cq = (idx & 31) * 4;
    int gn = n0 + n;
    float4 hv = *(const float4*)&h[gn * H + cq];
    int dg = degi[gn];
    float m0 = 0.f, m1 = 0.f, m2 = 0.f, m3 = 0.f;
    if (dg > 0) {
      float4 a = *(const float4*)&msA[gn * H + cq];
      float4 b = *(const float4*)&msB[gn * H + cq];
      float fdg = (float)dg;
      m0 = (a.x + b.x) / fdg;
      m1 = (a.y + b.y) / fdg;
      m2 = (a.z + b.z) / fdg;
      m3 = (a.w + b.w) / fdg;
    }
    uint2 uh, um;
    uh.x = ((unsigned int)f2bf(hv.y) << 16) | (unsigned int)f2bf(hv.x);
    uh.y = ((unsigned int)f2bf(hv.w) << 16) | (unsigned int)f2bf(hv.z);
    um.x = ((unsigned int)f2bf(m1) << 16) | (unsigned int)f2bf(m0);
    um.y = ((unsigned int)f2bf(m3) << 16) | (unsigned int)f2bf(m2);
    *(uint2*)&insb[n][cq] = uh;
    *(uint2*)&insb[n][H + cq] = um;
  }
  __syncthreads();
  int w = tid >> 6, lane = tid & 63, fr = lane & 15, kg = lane >> 4;
  f32x4 acc[2];
  acc[0] = (f32x4){0.f, 0.f, 0.f, 0.f};
  acc[1] = (f32x4){0.f, 0.f, 0.f, 0.f};
#pragma unroll
  for (int ks = 0; ks < 8; ++ks) {
    int k = ks * 32 + kg * 8;
    short8 a = *(const short8*)&insb[fr][k];
#pragma unroll
    for (int nt = 0; nt < 2; ++nt) {
      int col = w * 32 + nt * 16 + fr;
      short8 b = *(const short8*)&w1T[col * 256 + k];
      acc[nt] = __builtin_amdgcn_mfma_f32_16x16x32_bf16(a, b, acc[nt], 0, 0, 0);
    }
  }
#pragma unroll
  for (int nt = 0; nt < 2; ++nt) {
    int col = w * 32 + nt * 16 + fr;
    float b1 = nb1[col];
#pragma unroll
    for (int r = 0; r < 4; ++r) {
      int row = kg * 4 + r;
      hnsb[row][col] = f2bf(silu(acc[nt][r] + b1));
    }
  }
  __syncthreads();
  f32x4 acc2[2];
  acc2[0] = (f32x4){0.f, 0.f, 0.f, 0.f};
  acc2[1] = (f32x4){0.f, 0.f, 0.f, 0.f};
#pragma unroll
  for (int ks = 0; ks < 4; ++ks) {
    int k = ks * 32 + kg * 8;
    short8 a = *(const short8*)&hnsb[fr][k];
#pragma unroll
    for (int nt = 0; nt < 2; ++nt) {
      int col = w * 32 + nt * 16 + fr;
      short8 b = *(const short8*)&w2T[col * H + k];
      acc2[nt] = __builtin_amdgcn_mfma_f32_16x16x32_bf16(a, b, acc2[nt], 0, 0, 0);
    }
  }
  unsigned short (*hb)[136] = (unsigned short(*)[136])insb;
#pragma unroll
  for (int nt = 0; nt < 2; ++nt) {
    int col = w * 32 + nt * 16 + fr;
    float b2 = nb2[col];
#pragma unroll
    for (int r = 0; r < 4; ++r) {
      int row = kg * 4 + r;
      float hv = acc2[nt][r] + b2;
      h_out[(n0 + row) * H + col] = hv;
      hb[row][col] = f2bf(hv);
    }
  }
  if (tid < 48) {
    int nl = tid / 3, comp = tid - nl * 3;
    int gn = n0 + nl;
    int dg = degi[gn];
    float add = 0.0f;
    if (dg > 0)
      add = (cuA[gn * 3 + comp] + cuB[gn * 3 + comp]) / (float)dg;
    p_out[gn * 3 + comp] = p_in[gn * 3 + comp] + add;
  }
  if (doab) {
    __syncthreads();
    f32x4 acc3[4];
#pragma unroll
    for (int nt = 0; nt < 4; ++nt) acc3[nt] = (f32x4){0.f, 0.f, 0.f, 0.f};
#pragma unroll
    for (int ks = 0; ks < 4; ++ks) {
      int k = ks * 32 + kg * 8;
      short8 a = *(const short8*)&hb[fr][k];
#pragma unroll
      for (int nt = 0; nt < 4; ++nt) {
        int col = w * 64 + nt * 16 + fr;
        short8 b = *(const short8*)&ew1Tn[col * H + k];
        acc3[nt] = __builtin_amdgcn_mfma_f32_16x16x32_bf16(a, b, acc3[nt], 0, 0, 0);
      }
    }
#pragma unroll
    for (int nt = 0; nt < 4; ++nt) {
      int col = w * 64 + nt * 16 + fr;
      float bias = (col < H) ? eb1n[col] : 0.0f;
#pragma unroll
      for (int r = 0; r < 4; ++r) {
        int row = kg * 4 + r;
        float val = acc3[nt][r] + bias;
        if (col < H) Abf[(n0 + row) * H + col] = f2bf(val);
        else Bbf[(n0 + row) * H + (col - H)] = f2bf(val);
      }
    }
  }
}

// ---------------------------------------------------------------------------
// Output head via MFMA: 16 nodes/block.
// ---------------------------------------------------------------------------
__global__ __launch_bounds__(256) void out_mfma_kernel(
    const float* __restrict__ h, const float* __restrict__ p,
    const unsigned short* __restrict__ owT, const float* __restrict__ ecb,
    const float* __restrict__ efb, float* __restrict__ out) {
  __shared__ unsigned short hb[16][136];
  int tid = threadIdx.x;
  int n0 = blockIdx.x * 16;
  for (int idx = tid; idx < 16 * H; idx += 256) {
    int n = idx >> 7, c = idx & 127;
    hb[n][c] = f2bf(h[(n0 + n) * H + c]);
  }
  __syncthreads();
  int w = tid >> 6, lane = tid & 63, fr = lane & 15, kg = lane >> 4;
  int ntiles = (w == 0) ? 2 : 1;
  for (int tt = 0; tt < ntiles; ++tt) {
    int tile = (tt == 0) ? w : 4;
    f32x4 acc = (f32x4){0.f, 0.f, 0.f, 0.f};
    int col = tile * 16 + fr;
#pragma unroll
    for (int ks = 0; ks < 4; ++ks) {
      int k = ks * 32 + kg * 8;
      short8 a = *(const short8*)&hb[fr][k];
      short8 b = *(const short8*)&owT[col * H + k];
      acc = __builtin_amdgcn_mfma_f32_16x16x32_bf16(a, b, acc, 0, 0, 0);
    }
    if (col < 67) {
      float bias = (col < 3) ? ecb[col] : efb[col - 3];
#pragma unroll
      for (int r = 0; r < 4; ++r) {
        int row = kg * 4 + r;
        out[(n0 + row) * 70 + col] = acc[r] + bias;
      }
    }
  }
  if (tid < 48) {
    int nl = tid / 3, comp = tid - nl * 3;
    int gn = n0 + nl;
    out[gn * 70 + 67 + comp] = p[gn * 3 + comp];
  }
}

// ---------------------------------------------------------------------------
extern "C" void kernel_launch(void* const* d_in, const int* in_sizes, int n_in,
                              void* d_out, int out_size, void* d_ws, size_t ws_size,
                              hipStream_t stream) {
  const float* x = (const float*)d_in[0];
  const float* pos = (const float*)d_in[1];
  const float* t = (const float*)d_in[2];
  const float* s = (const float*)d_in[3];
  const float* pw = (const float*)d_in[4];
  const float* pb = (const float*)d_in[5];
  const float* ew1 = (const float*)d_in[6];
  const float* eb1 = (const float*)d_in[7];
  const float* ew2 = (const float*)d_in[8];
  const float* eb2 = (const float*)d_in[9];
  const float* nw1 = (const float*)d_in[10];
  const float* nb1 = (const float*)d_in[11];
  const float* nw2 = (const float*)d_in[12];
  const float* nb2 = (const float*)d_in[13];
  const float* cw = (const float*)d_in[14];
  const float* cb = (const float*)d_in[15];
  const float* ecw = (const float*)d_in[16];
  const float* ecb = (const float*)d_in[17];
  const float* efw = (const float*)d_in[18];
  const float* efb = (const float*)d_in[19];

  char* wp = (char*)d_ws;
  auto alloc = [&](size_t bytes) {
    char* r = wp;
    wp += (bytes + 255) & ~(size_t)255;
    return r;
  };
  float* h0 = (float*)alloc((size_t)N_NODES * H * 4);
  float* h1 = (float*)alloc((size_t)N_NODES * H * 4);
  unsigned short* Abf = (unsigned short*)alloc((size_t)N_NODES * H * 2);
  unsigned short* Bbf = (unsigned short*)alloc((size_t)N_NODES * H * 2);
  float* msAb = (float*)alloc((size_t)N_NODES * H * 4);
  float* msBb = (float*)alloc((size_t)N_NODES * H * 4);
  float* cuAb = (float*)alloc((size_t)N_NODES * 3 * 4);
  float* cuBb = (float*)alloc((size_t)N_NODES * 3 * 4);
  float* p0 = (float*)alloc((size_t)N_NODES * 3 * 4);
  float* p1 = (float*)alloc((size_t)N_NODES * 3 * 4);
  int* degi = (int*)alloc((size_t)N_NODES * 4);
  int* nbr = (int*)alloc((size_t)E_EDGES * 4);
  int* off = (int*)alloc((size_t)(N_NODES + 1) * 4);
  int* cursor = (int*)alloc((size_t)N_NODES * 4);
  int* eid = (int*)alloc((size_t)E_EDGES * 4);
  int* dstof = (int*)alloc((size_t)E_EDGES * 4);
  unsigned short* w2Tb = (unsigned short*)alloc((size_t)LAYERS * H * H * 2);
  unsigned short* nw1Tb = (unsigned short*)alloc((size_t)LAYERS * 2 * H * H * 2);
  unsigned short* nw2Tb = (unsigned short*)alloc((size_t)LAYERS * H * H * 2);
  unsigned short* ew1Tb = (unsigned short*)alloc((size_t)LAYERS * 2 * H * H * 2);
  unsigned short* pwTb = (unsigned short*)alloc((size_t)H * 96 * 2);
  unsigned short* owTb = (unsigned short*)alloc((size_t)80 * H * 2);

  // pos4 aliases msAb (first written by edge_mfma, after KNN is done)
  float4* pos4 = (float4*)msAb;

  init_kernel<<<1664, 256, 0, stream>>>(ew2, nw1, nw2, ew1, pw, ecw, efw,
                                        w2Tb, nw1Tb, nw2Tb, ew1Tb, pwTb, owTb,
                                        pos, pos4, p0, degi);
  knn_kernel<<<N_NODES / 8, 256, 0, stream>>>(pos4, nbr, degi);
  scan_kernel<<<1, 1024, 0, stream>>>(degi, off, cursor);
  scatter_kernel<<<(E_EDGES + 255) / 256, 256, 0, stream>>>(nbr, cursor, eid, dstof);
  sort_proj_kernel<<<665, 256, 0, stream>>>(x, s, t, pwTb, pb, ew1Tb, eb1,
                                            h0, Abf, Bbf, off, eid);

  float* hc = h0;
  float* hn = h1;
  float* pc = p0;
  float* pn = p1;
  for (int l = 0; l < LAYERS; ++l) {
    const float* ew1l = ew1 + (size_t)l * 257 * H;
    int doab = (l < LAYERS - 1) ? 1 : 0;
    edge_mfma_kernel<<<E_EDGES / TILE_E, 256, 0, stream>>>(
        Abf, Bbf, pc, s, off, eid, dstof, ew1l + 256 * H,
        w2Tb + (size_t)l * H * H, eb2 + l * H, cw + l * H, cb + l,
        msAb, msBb, cuAb, cuBb);
    node_mfma_kernel<<<N_NODES / 16, 256, 0, stream>>>(
        hc, msAb, msBb, degi, cuAb, cuBb, pc, nw1Tb + (size_t)l * 2 * H * H,
        nb1 + l * H, nw2Tb + (size_t)l * H * H, nb2 + l * H,
        ew1Tb + (size_t)(l + doab) * 2 * H * H, eb1 + (size_t)(l + doab) * H,
        doab, hn, pn, Abf, Bbf);
    float* tmp = hc; hc = hn; hn = tmp;
    tmp = pc; pc = pn; pn = tmp;
  }
  out_mfma_kernel<<<N_NODES / 16, 256, 0, stream>>>(hc, pc, owTb, ecb, efb,
                                                    (float*)d_out);
}

// Round 13
// 360.492 us; speedup vs baseline: 1.8234x; 1.0251x over previous
//
#include <hip/hip_runtime.h>
#include <math.h>

#define N_NODES 10000
#define ND 64
#define H 128
#define LAYERS 4
#define KNN 16
#define TD 16
#define E_EDGES (N_NODES * KNN)
#define KC 1250    // knn candidates per LDS chunk (20 KB)
#define TILE_E 128 // edges per block in edge_mfma_kernel
#define INF __builtin_inff()

typedef __attribute__((ext_vector_type(8))) short short8;
typedef __attribute__((ext_vector_type(4))) float f32x4;

__device__ __forceinline__ float silu(float x) {
  return x * __builtin_amdgcn_rcpf(1.0f + __expf(-x));
}

__device__ __forceinline__ unsigned short f2bf(float f) {
  unsigned int u = __float_as_uint(f);
  u += 0x7fffu + ((u >> 16) & 1u);  // RNE
  return (unsigned short)(u >> 16);
}
__device__ __forceinline__ float bf2f(unsigned short h) {
  return __uint_as_float(((unsigned int)h) << 16);
}

// DPP row_shr:1 (within 16-lane rows) — VALU-pipe lane shift, ~2cy.
__device__ __forceinline__ float dpp_shr1_f(float x) {
  return __int_as_float(__builtin_amdgcn_update_dpp(
      0, __float_as_int(x), 0x111, 0xF, 0xF, true));
}
__device__ __forceinline__ int dpp_shr1_i(int x) {
  return __builtin_amdgcn_update_dpp(0, x, 0x111, 0xF, 0xF, true);
}
__device__ __forceinline__ float rdlane_f(float x, int sl) {
  return __int_as_float(__builtin_amdgcn_readlane(__float_as_int(x), sl));
}

// ---------------------------------------------------------------------------
// init: wcvt (blocks 0..1623) | pos4+p0copy+deg-zero (blocks 1624..1663)
// ---------------------------------------------------------------------------
__global__ __launch_bounds__(256) void init_kernel(
    const float* __restrict__ ew2, const float* __restrict__ nw1,
    const float* __restrict__ nw2, const float* __restrict__ ew1,
    const float* __restrict__ pw, const float* __restrict__ ecw,
    const float* __restrict__ efw, unsigned short* __restrict__ w2T,
    unsigned short* __restrict__ nw1T, unsigned short* __restrict__ nw2T,
    unsigned short* __restrict__ ew1T, unsigned short* __restrict__ pwT,
    unsigned short* __restrict__ owT, const float* __restrict__ pos,
    float4* __restrict__ pos4, float* __restrict__ p0,
    int* __restrict__ degi) {
  int bid = blockIdx.x;
  if (bid < 1624) {
    int i = bid * 256 + threadIdx.x;  // 415744 total
    if (i < 65536) {
      int l = i >> 14, rem = i & 16383, c = rem >> 7, o = rem & 127;
      w2T[l * 16384 + o * 128 + c] = f2bf(ew2[i]);
    } else if (i < 196608) {
      int j = i - 65536;
      int l = j >> 15, rem = j & 32767, c2 = rem >> 7, o = rem & 127;
      nw1T[l * 32768 + o * 256 + c2] = f2bf(nw1[j]);
    } else if (i < 262144) {
      int j = i - 196608;
      int l = j >> 14, rem = j & 16383, c = rem >> 7, o = rem & 127;
      nw2T[l * 16384 + o * 128 + c] = f2bf(nw2[j]);
    } else if (i < 393216) {
      int j = i - 262144;
      int l = j >> 15, rem = j & 32767, r = rem >> 7, o = rem & 127;
      int o2 = o + ((r >> 7) << 7);
      int c = r & 127;
      ew1T[l * 32768 + o2 * 128 + c] = f2bf(ew1[l * 257 * 128 + r * 128 + o]);
    } else if (i < 405504) {
      int j = i - 393216;
      int o = j / 96, c = j - o * 96;
      pwT[j] = (c < 81) ? f2bf(pw[c * 128 + o]) : 0;
    } else if (i < 415744) {
      int j = i - 405504;
      int o = j >> 7, c = j & 127;
      float v = 0.0f;
      if (o < 3) v = ecw[c * 3 + o];
      else if (o < 67) v = efw[c * 64 + (o - 3)];
      owT[j] = f2bf(v);
    }
  } else {
    int i = (bid - 1624) * 256 + threadIdx.x;
    if (i >= N_NODES) return;
    float x = pos[i * 3 + 0], y = pos[i * 3 + 1], z = pos[i * 3 + 2];
    pos4[i] = make_float4(x, y, z, x * x + y * y + z * z);
    p0[i * 3 + 0] = x;
    p0[i * 3 + 1] = y;
    p0[i * 3 + 2] = z;
    degi[i] = 0;
  }
}

// ---------------------------------------------------------------------------
// KNN: ONE query per wave (4/block, 2500 blocks -> saturates 32 waves/CU).
// Top-16 distributed sorted ascending in lanes 0..15. All cross-lane ops on
// the VALU pipe: DPP row_shr:1 insert shift, v_readlane broadcast/threshold.
// 256 cands/round (4 guard-free rounds + tail), per-group threshold refresh
// (stale extra inserts are provable no-ops). Self excluded by index check.
// Ascending chunk/group/lane order + strict < gate + stay-on-equal =
// lowest-index-wins ties (round-8/11/12 proven semantics). Fused deg count.
// ---------------------------------------------------------------------------
#define DIST1(pp, d)                                                         \
  d = fmaf(ax, (pp).x, fmaf(ay, (pp).y, fmaf(az, (pp).z, (pp).w)));

#define GRP(dv, gbase)                                                       \
  {                                                                          \
    unsigned long long m = __ballot((dv) < th);                              \
    if (m) {                                                                 \
      while (m) {                                                            \
        int sl = __ffsll((long long)m) - 1;                                  \
        m &= m - 1;                                                          \
        float db = rdlane_f((dv), sl);                                       \
        int gj = (gbase) + sl;                                               \
        float pv = dpp_shr1_f(v);                                            \
        int pid = dpp_shr1_i(id);                                            \
        bool stay = (v <= db);                                               \
        bool tk = (lane == 0) || (pv <= db);                                 \
        v = stay ? v : (tk ? db : pv);                                       \
        id = stay ? id : (tk ? gj : pid);                                    \
      }                                                                      \
      th = rdlane_f(v, 15);                                                  \
    }                                                                        \
  }

__global__ __launch_bounds__(256) void knn_kernel(const float4* __restrict__ pos4,
                                                  int* __restrict__ nbr,
                                                  int* __restrict__ degi) {
  __shared__ float4 C[KC];
  int tid = threadIdx.x;
  int lane = tid & 63;
  int wid = tid >> 6;
  int q = blockIdx.x * 4 + wid;
  float4 qp = pos4[q];
  float ax = -2.0f * qp.x, ay = -2.0f * qp.y, az = -2.0f * qp.z;
  float v = INF;
  int id = 0;
  float th = INF;
  for (int base = 0; base < N_NODES; base += KC) {
    __syncthreads();
    for (int jj = tid; jj < KC; jj += 256) C[jj] = pos4[base + jj];
    __syncthreads();
    // 4 guard-free full rounds (j0 = 0,256,512,768)
    for (int j0 = 0; j0 < 1024; j0 += 256) {
      float4 pA = C[j0 + lane], pB = C[j0 + 64 + lane];
      float4 pC = C[j0 + 128 + lane], pD = C[j0 + 192 + lane];
      float dA, dB, dC, dD;
      DIST1(pA, dA);
      DIST1(pB, dB);
      DIST1(pC, dC);
      DIST1(pD, dD);
      int ga = base + j0 + lane;
      if (ga == q) dA = INF;
      if (ga + 64 == q) dB = INF;
      if (ga + 128 == q) dC = INF;
      if (ga + 192 == q) dD = INF;
      float mn = fminf(fminf(dA, dB), fminf(dC, dD));
      if (__ballot(mn < th)) {
        int gb = base + j0;
        GRP(dA, gb);
        GRP(dB, gb + 64);
        GRP(dC, gb + 128);
        GRP(dD, gb + 192);
      }
    }
    // tail round j0=1024: A,B,C full; D partial (34 lanes)
    {
      float4 pA = C[1024 + lane], pB = C[1088 + lane], pC = C[1152 + lane];
      float dA, dB, dC;
      float dD = INF;
      DIST1(pA, dA);
      DIST1(pB, dB);
      DIST1(pC, dC);
      if (lane < 34) {
        float4 pD = C[1216 + lane];
        DIST1(pD, dD);
      }
      int ga = base + 1024 + lane;
      if (ga == q) dA = INF;
      if (ga + 64 == q) dB = INF;
      if (ga + 128 == q) dC = INF;
      if (ga + 192 == q) dD = INF;
      float mn = fminf(fminf(dA, dB), fminf(dC, dD));
      if (__ballot(mn < th)) {
        int gb = base + 1024;
        GRP(dA, gb);
        GRP(dB, gb + 64);
        GRP(dC, gb + 128);
        GRP(dD, gb + 192);
      }
    }
  }
  if (lane < KNN) {
    nbr[q * KNN + lane] = id;
    atomicAdd(&degi[id], 1);
  }
}

// ---------------------------------------------------------------------------
// CSR build (deterministic): scan -> scatter(+dstof) -> per-node sort
// ---------------------------------------------------------------------------
__global__ __launch_bounds__(1024) void scan_kernel(const int* __restrict__ degi,
                                                    int* __restrict__ off,
                                                    int* __restrict__ cursor) {
  __shared__ int part[1024];
  int t = threadIdx.x;
  int base = t * 10;
  int sum = 0;
  if (t < 1000)
    for (int i = 0; i < 10; ++i) sum += degi[base + i];
  part[t] = sum;
  __syncthreads();
  for (int stp = 1; stp < 1024; stp <<= 1) {
    int v = (t >= stp) ? part[t - stp] : 0;
    __syncthreads();
    part[t] += v;
    __syncthreads();
  }
  if (t < 1000) {
    int run = (t == 0) ? 0 : part[t - 1];
    for (int i = 0; i < 10; ++i) {
      off[base + i] = run;
      cursor[base + i] = run;
      run += degi[base + i];
    }
  }
  if (t == 0) off[N_NODES] = E_EDGES;
}

__global__ void scatter_kernel(const int* __restrict__ nbr, int* __restrict__ cursor,
                               int* __restrict__ eid, int* __restrict__ dstof) {
  int e = blockIdx.x * 256 + threadIdx.x;
  if (e < E_EDGES) {
    int d = nbr[e];
    int p = atomicAdd(&cursor[d], 1);
    eid[p] = e;
    dstof[p] = d;
  }
}

// ---------------------------------------------------------------------------
// sort_proj: proj+layer0 A/B MFMA (blocks 0..624) | per-node eid sort (625..664)
// ---------------------------------------------------------------------------
__global__ __launch_bounds__(256) void sort_proj_kernel(
    const float* __restrict__ x, const float* __restrict__ s,
    const float* __restrict__ tptr, const unsigned short* __restrict__ pwT,
    const float* __restrict__ pb, const unsigned short* __restrict__ ew1T,
    const float* __restrict__ eb1, float* __restrict__ h_out,
    unsigned short* __restrict__ Abf, unsigned short* __restrict__ Bbf,
    const int* __restrict__ off, int* __restrict__ eid) {
  __shared__ unsigned short inpb[16][104];
  __shared__ unsigned short hb[16][136];
  int tid = threadIdx.x;
  int bid = blockIdx.x;
  if (bid >= 625) {
    int n = (bid - 625) * 256 + tid;
    if (n >= N_NODES) return;
    int a = off[n], b = off[n + 1];
    for (int i = a + 1; i < b; ++i) {
      int v = eid[i];
      int j = i - 1;
      while (j >= a && eid[j] > v) { eid[j + 1] = eid[j]; --j; }
      eid[j + 1] = v;
    }
    return;
  }
  int n0 = bid * 16;
  float t = tptr[0];
  for (int idx = tid; idx < 16 * 104; idx += 256) {
    int n = idx / 104, c = idx - n * 104;
    int gn = n0 + n;
    float val;
    if (c < 64) val = x[gn * ND + c];
    else if (c == 64) val = s[gn];
    else if (c < 81) {
      int j = c - 65;
      int jj = (j < 8) ? j : (j - 8);
      float f = __expf(-4.0f * (float)jj / 7.0f);
      float a = t * f;
      val = (j < 8) ? sinf(a) : cosf(a);
    } else val = 0.0f;
    inpb[n][c] = f2bf(val);
  }
  __syncthreads();
  int w = tid >> 6, lane = tid & 63, fr = lane & 15, kg = lane >> 4;
  f32x4 acc[2];
  acc[0] = (f32x4){0.f, 0.f, 0.f, 0.f};
  acc[1] = (f32x4){0.f, 0.f, 0.f, 0.f};
#pragma unroll
  for (int ks = 0; ks < 3; ++ks) {
    int k = ks * 32 + kg * 8;
    short8 a = *(const short8*)&inpb[fr][k];
#pragma unroll
    for (int nt = 0; nt < 2; ++nt) {
      int col = w * 32 + nt * 16 + fr;
      short8 b = *(const short8*)&pwT[col * 96 + k];
      acc[nt] = __builtin_amdgcn_mfma_f32_16x16x32_bf16(a, b, acc[nt], 0, 0, 0);
    }
  }
#pragma unroll
  for (int nt = 0; nt < 2; ++nt) {
    int col = w * 32 + nt * 16 + fr;
    float bias = pb[col];
#pragma unroll
    for (int r = 0; r < 4; ++r) {
      int row = kg * 4 + r;
      float hv = acc[nt][r] + bias;
      h_out[(n0 + row) * H + col] = hv;
      hb[row][col] = f2bf(hv);
    }
  }
  __syncthreads();
  f32x4 acc2[4];
#pragma unroll
  for (int nt = 0; nt < 4; ++nt) acc2[nt] = (f32x4){0.f, 0.f, 0.f, 0.f};
#pragma unroll
  for (int ks = 0; ks < 4; ++ks) {
    int k = ks * 32 + kg * 8;
    short8 a = *(const short8*)&hb[fr][k];
#pragma unroll
    for (int nt = 0; nt < 4; ++nt) {
      int col = w * 64 + nt * 16 + fr;
      short8 b = *(const short8*)&ew1T[col * H + k];
      acc2[nt] = __builtin_amdgcn_mfma_f32_16x16x32_bf16(a, b, acc2[nt], 0, 0, 0);
    }
  }
#pragma unroll
  for (int nt = 0; nt < 4; ++nt) {
    int col = w * 64 + nt * 16 + fr;
    float bias = (col < H) ? eb1[col] : 0.0f;
#pragma unroll
    for (int r = 0; r < 4; ++r) {
      int row = kg * 4 + r;
      float val = acc2[nt][r] + bias;
      if (col < H) Abf[(n0 + row) * H + col] = f2bf(val);
      else Bbf[(n0 + row) * H + (col - H)] = f2bf(val);
    }
  }
}

// ---------------------------------------------------------------------------
// Edge phase, MFMA: 128 CSR positions per block. A/B gathered as bf16 uint4.
// ---------------------------------------------------------------------------
__global__ __launch_bounds__(256) void edge_mfma_kernel(
    const unsigned short* __restrict__ Abf, const unsigned short* __restrict__ Bbf,
    const float* __restrict__ p, const float* __restrict__ s,
    const int* __restrict__ csr_off, const int* __restrict__ eid,
    const int* __restrict__ dstof, const float* __restrict__ wr,
    const unsigned short* __restrict__ w2T, const float* __restrict__ eb2,
    const float* __restrict__ cw, const float* __restrict__ cbp,
    float* __restrict__ msA, float* __restrict__ msB,
    float* __restrict__ cuA, float* __restrict__ cuB) {
  __shared__ unsigned short t1s[TILE_E][136];  // t1 (bf16), later reused for m
  __shared__ float r2A[TILE_E], sA[TILE_E], dirA[TILE_E][3], gA[TILE_E];
  __shared__ float gpart[2][TILE_E];
  __shared__ int srcA[TILE_E], dstA[TILE_E];
  __shared__ float wrs[H], b2s[H], cws[H];

  int tid = threadIdx.x;
  int P0 = blockIdx.x * TILE_E;
  int P1 = P0 + TILE_E;

  if (tid < H) { wrs[tid] = wr[tid]; b2s[tid] = eb2[tid]; cws[tid] = cw[tid]; }
  if (tid < TILE_E) {
    int e = tid;
    int edge = eid[P0 + e];
    int src = edge >> 4;  // edge / KNN
    int d = dstof[P0 + e];
    srcA[e] = src;
    dstA[e] = d;
    float dx = p[d * 3 + 0] - p[src * 3 + 0];
    float dy = p[d * 3 + 1] - p[src * 3 + 1];
    float dz = p[d * 3 + 2] - p[src * 3 + 2];
    float r2 = dx * dx + dy * dy + dz * dz;
    r2A[e] = r2;
    float rinv = 1.0f / sqrtf(r2 + 1e-8f);
    dirA[e][0] = dx * rinv;
    dirA[e][1] = dy * rinv;
    dirA[e][2] = dz * rinv;
    sA[e] = s[src];
  }
  __syncthreads();

  int nA = dstA[0], nB = dstA[TILE_E - 1];
  int nn = nB - nA + 1;

  // stage 1: t1 tile (bf16); 8 cols per thread per iter, uint4 gathers
  for (int idx = tid; idx < TILE_E * 16; idx += 256) {
    int e = idx >> 4, cp = (idx & 15) * 8;
    uint4 au = *(const uint4*)&Abf[dstA[e] * H + cp];
    uint4 bu = *(const uint4*)&Bbf[srcA[e] * H + cp];
    float r2v = r2A[e];
    unsigned int as[4] = {au.x, au.y, au.z, au.w};
    unsigned int bs[4] = {bu.x, bu.y, bu.z, bu.w};
    unsigned int res[4];
#pragma unroll
    for (int q = 0; q < 4; ++q) {
      float pr0 = silu(bf2f((unsigned short)(as[q] & 0xffffu)) +
                       bf2f((unsigned short)(bs[q] & 0xffffu)) +
                       r2v * wrs[cp + 2 * q]);
      float pr1 = silu(bf2f((unsigned short)(as[q] >> 16)) +
                       bf2f((unsigned short)(bs[q] >> 16)) +
                       r2v * wrs[cp + 2 * q + 1]);
      res[q] = ((unsigned int)f2bf(pr1) << 16) | (unsigned int)f2bf(pr0);
    }
    *(uint4*)&t1s[e][cp] = make_uint4(res[0], res[1], res[2], res[3]);
  }
  __syncthreads();

  // stage 2: GEMM m_pre = t1 @ w2. Wave w -> out cols [w*32, w*32+32).
  int w = tid >> 6, lane = tid & 63;
  int fr = lane & 15, kg = lane >> 4;
  f32x4 acc[8][2];
#pragma unroll
  for (int mt = 0; mt < 8; ++mt)
#pragma unroll
    for (int nt = 0; nt < 2; ++nt) acc[mt][nt] = (f32x4){0.f, 0.f, 0.f, 0.f};
#pragma unroll
  for (int ks = 0; ks < 4; ++ks) {
    int k = ks * 32 + kg * 8;
    short8 bf0 = *(const short8*)&w2T[(w * 32 + fr) * H + k];
    short8 bf1 = *(const short8*)&w2T[(w * 32 + 16 + fr) * H + k];
#pragma unroll
    for (int mt = 0; mt < 8; ++mt) {
      short8 a = *(const short8*)&t1s[mt * 16 + fr][k];
      acc[mt][0] = __builtin_amdgcn_mfma_f32_16x16x32_bf16(a, bf0, acc[mt][0], 0, 0, 0);
      acc[mt][1] = __builtin_amdgcn_mfma_f32_16x16x32_bf16(a, bf1, acc[mt][1], 0, 0, 0);
    }
  }
  __syncthreads();  // all t1s reads done

  // epilogue: m = silu(acc + b2) * s[src] -> back into t1s (bf16)
#pragma unroll
  for (int mt = 0; mt < 8; ++mt) {
#pragma unroll
    for (int nt = 0; nt < 2; ++nt) {
      int col = w * 32 + nt * 16 + fr;
      float b2v = b2s[col];
#pragma unroll
      for (int r = 0; r < 4; ++r) {
        int row = mt * 16 + kg * 4 + r;
        float mv = silu(acc[mt][nt][r] + b2v) * sA[row];
        t1s[row][col] = f2bf(mv);
      }
    }
  }
  __syncthreads();

  // gamma per edge: 2 threads/row (64 cols each), LDS combine
  {
    int e = tid & 127, half = tid >> 7;
    int c0 = half * 64;
    float g = 0.f;
    for (int c = c0; c < c0 + 64; c += 4) {
      uint2 u = *(const uint2*)&t1s[e][c];
      g = fmaf(bf2f((unsigned short)(u.x & 0xffffu)), cws[c], g);
      g = fmaf(bf2f((unsigned short)(u.x >> 16)), cws[c + 1], g);
      g = fmaf(bf2f((unsigned short)(u.y & 0xffffu)), cws[c + 2], g);
      g = fmaf(bf2f((unsigned short)(u.y >> 16)), cws[c + 3], g);
    }
    gpart[half][e] = g;
  }
  __syncthreads();
  if (tid < TILE_E) gA[tid] = gpart[0][tid] + gpart[1][tid] + cbp[0];
  __syncthreads();

  // per-node partial msum -> slots (4 cols per item, float4 writes)
  for (int idx = tid; idx < nn * 32; idx += 256) {
    int ni = idx >> 5, cq = (idx & 31) * 4;
    int n = nA + ni;
    int o0 = csr_off[n], o1 = csr_off[n + 1];
    int lo = max(o0, P0), hi = min(o1, P1);
    float s0 = 0.f, s1 = 0.f, s2 = 0.f, s3 = 0.f;
    for (int pos = lo; pos < hi; ++pos) {
      uint2 u = *(const uint2*)&t1s[pos - P0][cq];
      s0 += bf2f((unsigned short)(u.x & 0xffffu));
      s1 += bf2f((unsigned short)(u.x >> 16));
      s2 += bf2f((unsigned short)(u.y & 0xffffu));
      s3 += bf2f((unsigned short)(u.y >> 16));
    }
    float4 sv = make_float4(s0, s1, s2, s3);
    if (o0 >= P0) {
      *(float4*)&msA[n * H + cq] = sv;
      if (o1 <= P1) *(float4*)&msB[n * H + cq] = make_float4(0.f, 0.f, 0.f, 0.f);
    } else {
      *(float4*)&msB[n * H + cq] = sv;
    }
  }
  // per-node partial cu -> slots
  for (int idx = tid; idx < nn * 3; idx += 256) {
    int ni = idx / 3, comp = idx - ni * 3;
    int n = nA + ni;
    int o0 = csr_off[n], o1 = csr_off[n + 1];
    int lo = max(o0, P0), hi = min(o1, P1);
    float sum = 0.f;
    for (int pos = lo; pos < hi; ++pos)
      sum += gA[pos - P0] * dirA[pos - P0][comp];
    if (o0 >= P0) {
      cuA[n * 3 + comp] = sum;
      if (o1 <= P1) cuB[n * 3 + comp] = 0.0f;
    } else {
      cuB[n * 3 + comp] = sum;
    }
  }
}

// ---------------------------------------------------------------------------
// Node update via MFMA: 16 nodes/block, 4 waves. GEMM1 (K=256) -> silu ->
// GEMM2 (K=128) -> h_out; optional fused next-layer A/B GEMM.
// ---------------------------------------------------------------------------
__global__ __launch_bounds__(256) void node_mfma_kernel(
    const float* __restrict__ h, const float* __restrict__ msA,
    const float* __restrict__ msB, const int* __restrict__ degi,
    const float* __restrict__ cuA, const float* __restrict__ cuB,
    const float* __restrict__ p_in, const unsigned short* __restrict__ w1T,
    const float* __restrict__ nb1, const unsigned short* __restrict__ w2T,
    const float* __restrict__ nb2, const unsigned short* __restrict__ ew1Tn,
    const float* __restrict__ eb1n, int doab, float* __restrict__ h_out,
    float* __restrict__ p_out, unsigned short* __restrict__ Abf,
    unsigned short* __restrict__ Bbf) {
  __shared__ unsigned short insb[16][264];
  __shared__ unsigned short hnsb[16][136];
  int tid = threadIdx.x;
  int n0 = blockIdx.x * 16;
  // staging: float4 loads, uint2 bf16 LDS writes (2 iters/thread)
  for (int idx = tid; idx < 16 * 32; idx += 256) {
    int n = idx >> 5, cq = (idx & 31) * 4;
    int gn = n0 + n;
    float4 hv = *(const float4*)&h[gn * H + cq];
    int dg = degi[gn];
    float m0 = 0.f, m1 = 0.f, m2 = 0.f, m3 = 0.f;
    if (dg > 0) {
      float4 a = *(const float4*)&msA[gn * H + cq];
      float4 b = *(const float4*)&msB[gn * H + cq];
      float fdg = (float)dg;
      m0 = (a.x + b.x) / fdg;
      m1 = (a.y + b.y) / fdg;
      m2 = (a.z + b.z) / fdg;
      m3 = (a.w + b.w) / fdg;
    }
    uint2 uh, um;
    uh.x = ((unsigned int)f2bf(hv.y) << 16) | (unsigned int)f2bf(hv.x);
    uh.y = ((unsigned int)f2bf(hv.w) << 16) | (unsigned int)f2bf(hv.z);
    um.x = ((unsigned int)f2bf(m1) << 16) | (unsigned int)f2bf(m0);
    um.y = ((unsigned int)f2bf(m3) << 16) | (unsigned int)f2bf(m2);
    *(uint2*)&insb[n][cq] = uh;
    *(uint2*)&insb[n][H + cq] = um;
  }
  __syncthreads();
  int w = tid >> 6, lane = tid & 63, fr = lane & 15, kg = lane >> 4;
  f32x4 acc[2];
  acc[0] = (f32x4){0.f, 0.f, 0.f, 0.f};
  acc[1] = (f32x4){0.f, 0.f, 0.f, 0.f};
#pragma unroll
  for (int ks = 0; ks < 8; ++ks) {
    int k = ks * 32 + kg * 8;
    short8 a = *(const short8*)&insb[fr][k];
#pragma unroll
    for (int nt = 0; nt < 2; ++nt) {
      int col = w * 32 + nt * 16 + fr;
      short8 b = *(const short8*)&w1T[col * 256 + k];
      acc[nt] = __builtin_amdgcn_mfma_f32_16x16x32_bf16(a, b, acc[nt], 0, 0, 0);
    }
  }
#pragma unroll
  for (int nt = 0; nt < 2; ++nt) {
    int col = w * 32 + nt * 16 + fr;
    float b1 = nb1[col];
#pragma unroll
    for (int r = 0; r < 4; ++r) {
      int row = kg * 4 + r;
      hnsb[row][col] = f2bf(silu(acc[nt][r] + b1));
    }
  }
  __syncthreads();
  f32x4 acc2[2];
  acc2[0] = (f32x4){0.f, 0.f, 0.f, 0.f};
  acc2[1] = (f32x4){0.f, 0.f, 0.f, 0.f};
#pragma unroll
  for (int ks = 0; ks < 4; ++ks) {
    int k = ks * 32 + kg * 8;
    short8 a = *(const short8*)&hnsb[fr][k];
#pragma unroll
    for (int nt = 0; nt < 2; ++nt) {
      int col = w * 32 + nt * 16 + fr;
      short8 b = *(const short8*)&w2T[col * H + k];
      acc2[nt] = __builtin_amdgcn_mfma_f32_16x16x32_bf16(a, b, acc2[nt], 0, 0, 0);
    }
  }
  unsigned short (*hb)[136] = (unsigned short(*)[136])insb;
#pragma unroll
  for (int nt = 0; nt < 2; ++nt) {
    int col = w * 32 + nt * 16 + fr;
    float b2 = nb2[col];
#pragma unroll
    for (int r = 0; r < 4; ++r) {
      int row = kg * 4 + r;
      float hv = acc2[nt][r] + b2;
      h_out[(n0 + row) * H + col] = hv;
      hb[row][col] = f2bf(hv);
    }
  }
  if (tid < 48) {
    int nl = tid / 3, comp = tid - nl * 3;
    int gn = n0 + nl;
    int dg = degi[gn];
    float add = 0.0f;
    if (dg > 0)
      add = (cuA[gn * 3 + comp] + cuB[gn * 3 + comp]) / (float)dg;
    p_out[gn * 3 + comp] = p_in[gn * 3 + comp] + add;
  }
  if (doab) {
    __syncthreads();
    f32x4 acc3[4];
#pragma unroll
    for (int nt = 0; nt < 4; ++nt) acc3[nt] = (f32x4){0.f, 0.f, 0.f, 0.f};
#pragma unroll
    for (int ks = 0; ks < 4; ++ks) {
      int k = ks * 32 + kg * 8;
      short8 a = *(const short8*)&hb[fr][k];
#pragma unroll
      for (int nt = 0; nt < 4; ++nt) {
        int col = w * 64 + nt * 16 + fr;
        short8 b = *(const short8*)&ew1Tn[col * H + k];
        acc3[nt] = __builtin_amdgcn_mfma_f32_16x16x32_bf16(a, b, acc3[nt], 0, 0, 0);
      }
    }
#pragma unroll
    for (int nt = 0; nt < 4; ++nt) {
      int col = w * 64 + nt * 16 + fr;
      float bias = (col < H) ? eb1n[col] : 0.0f;
#pragma unroll
      for (int r = 0; r < 4; ++r) {
        int row = kg * 4 + r;
        float val = acc3[nt][r] + bias;
        if (col < H) Abf[(n0 + row) * H + col] = f2bf(val);
        else Bbf[(n0 + row) * H + (col - H)] = f2bf(val);
      }
    }
  }
}

// ---------------------------------------------------------------------------
// Output head via MFMA: 16 nodes/block.
// ---------------------------------------------------------------------------
__global__ __launch_bounds__(256) void out_mfma_kernel(
    const float* __restrict__ h, const float* __restrict__ p,
    const unsigned short* __restrict__ owT, const float* __restrict__ ecb,
    const float* __restrict__ efb, float* __restrict__ out) {
  __shared__ unsigned short hb[16][136];
  int tid = threadIdx.x;
  int n0 = blockIdx.x * 16;
  for (int idx = tid; idx < 16 * H; idx += 256) {
    int n = idx >> 7, c = idx & 127;
    hb[n][c] = f2bf(h[(n0 + n) * H + c]);
  }
  __syncthreads();
  int w = tid >> 6, lane = tid & 63, fr = lane & 15, kg = lane >> 4;
  int ntiles = (w == 0) ? 2 : 1;
  for (int tt = 0; tt < ntiles; ++tt) {
    int tile = (tt == 0) ? w : 4;
    f32x4 acc = (f32x4){0.f, 0.f, 0.f, 0.f};
    int col = tile * 16 + fr;
#pragma unroll
    for (int ks = 0; ks < 4; ++ks) {
      int k = ks * 32 + kg * 8;
      short8 a = *(const short8*)&hb[fr][k];
      short8 b = *(const short8*)&owT[col * H + k];
      acc = __builtin_amdgcn_mfma_f32_16x16x32_bf16(a, b, acc, 0, 0, 0);
    }
    if (col < 67) {
      float bias = (col < 3) ? ecb[col] : efb[col - 3];
#pragma unroll
      for (int r = 0; r < 4; ++r) {
        int row = kg * 4 + r;
        out[(n0 + row) * 70 + col] = acc[r] + bias;
      }
    }
  }
  if (tid < 48) {
    int nl = tid / 3, comp = tid - nl * 3;
    int gn = n0 + nl;
    out[gn * 70 + 67 + comp] = p[gn * 3 + comp];
  }
}

// ---------------------------------------------------------------------------
extern "C" void kernel_launch(void* const* d_in, const int* in_sizes, int n_in,
                              void* d_out, int out_size, void* d_ws, size_t ws_size,
                              hipStream_t stream) {
  const float* x = (const float*)d_in[0];
  const float* pos = (const float*)d_in[1];
  const float* t = (const float*)d_in[2];
  const float* s = (const float*)d_in[3];
  const float* pw = (const float*)d_in[4];
  const float* pb = (const float*)d_in[5];
  const float* ew1 = (const float*)d_in[6];
  const float* eb1 = (const float*)d_in[7];
  const float* ew2 = (const float*)d_in[8];
  const float* eb2 = (const float*)d_in[9];
  const float* nw1 = (const float*)d_in[10];
  const float* nb1 = (const float*)d_in[11];
  const float* nw2 = (const float*)d_in[12];
  const float* nb2 = (const float*)d_in[13];
  const float* cw = (const float*)d_in[14];
  const float* cb = (const float*)d_in[15];
  const float* ecw = (const float*)d_in[16];
  const float* ecb = (const float*)d_in[17];
  const float* efw = (const float*)d_in[18];
  const float* efb = (const float*)d_in[19];

  char* wp = (char*)d_ws;
  auto alloc = [&](size_t bytes) {
    char* r = wp;
    wp += (bytes + 255) & ~(size_t)255;
    return r;
  };
  float* h0 = (float*)alloc((size_t)N_NODES * H * 4);
  float* h1 = (float*)alloc((size_t)N_NODES * H * 4);
  unsigned short* Abf = (unsigned short*)alloc((size_t)N_NODES * H * 2);
  unsigned short* Bbf = (unsigned short*)alloc((size_t)N_NODES * H * 2);
  float* msAb = (float*)alloc((size_t)N_NODES * H * 4);
  float* msBb = (float*)alloc((size_t)N_NODES * H * 4);
  float* cuAb = (float*)alloc((size_t)N_NODES * 3 * 4);
  float* cuBb = (float*)alloc((size_t)N_NODES * 3 * 4);
  float* p0 = (float*)alloc((size_t)N_NODES * 3 * 4);
  float* p1 = (float*)alloc((size_t)N_NODES * 3 * 4);
  int* degi = (int*)alloc((size_t)N_NODES * 4);
  int* nbr = (int*)alloc((size_t)E_EDGES * 4);
  int* off = (int*)alloc((size_t)(N_NODES + 1) * 4);
  int* cursor = (int*)alloc((size_t)N_NODES * 4);
  int* eid = (int*)alloc((size_t)E_EDGES * 4);
  int* dstof = (int*)alloc((size_t)E_EDGES * 4);
  unsigned short* w2Tb = (unsigned short*)alloc((size_t)LAYERS * H * H * 2);
  unsigned short* nw1Tb = (unsigned short*)alloc((size_t)LAYERS * 2 * H * H * 2);
  unsigned short* nw2Tb = (unsigned short*)alloc((size_t)LAYERS * H * H * 2);
  unsigned short* ew1Tb = (unsigned short*)alloc((size_t)LAYERS * 2 * H * H * 2);
  unsigned short* pwTb = (unsigned short*)alloc((size_t)H * 96 * 2);
  unsigned short* owTb = (unsigned short*)alloc((size_t)80 * H * 2);

  // pos4 aliases msAb (first written by edge_mfma, after KNN is done)
  float4* pos4 = (float4*)msAb;

  init_kernel<<<1664, 256, 0, stream>>>(ew2, nw1, nw2, ew1, pw, ecw, efw,
                                        w2Tb, nw1Tb, nw2Tb, ew1Tb, pwTb, owTb,
                                        pos, pos4, p0, degi);
  knn_kernel<<<N_NODES / 4, 256, 0, stream>>>(pos4, nbr, degi);
  scan_kernel<<<1, 1024, 0, stream>>>(degi, off, cursor);
  scatter_kernel<<<(E_EDGES + 255) / 256, 256, 0, stream>>>(nbr, cursor, eid, dstof);
  sort_proj_kernel<<<665, 256, 0, stream>>>(x, s, t, pwTb, pb, ew1Tb, eb1,
                                            h0, Abf, Bbf, off, eid);

  float* hc = h0;
  float* hn = h1;
  float* pc = p0;
  float* pn = p1;
  for (int l = 0; l < LAYERS; ++l) {
    const float* ew1l = ew1 + (size_t)l * 257 * H;
    int doab = (l < LAYERS - 1) ? 1 : 0;
    edge_mfma_kernel<<<E_EDGES / TILE_E, 256, 0, stream>>>(
        Abf, Bbf, pc, s, off, eid, dstof, ew1l + 256 * H,
        w2Tb + (size_t)l * H * H, eb2 + l * H, cw + l * H, cb + l,
        msAb, msBb, cuAb, cuBb);
    node_mfma_kernel<<<N_NODES / 16, 256, 0, stream>>>(
        hc, msAb, msBb, degi, cuAb, cuBb, pc, nw1Tb + (size_t)l * 2 * H * H,
        nb1 + l * H, nw2Tb + (size_t)l * H * H, nb2 + l * H,
        ew1Tb + (size_t)(l + doab) * 2 * H * H, eb1 + (size_t)(l + doab) * H,
        doab, hn, pn, Abf, Bbf);
    float* tmp = hc; hc = hn; hn = tmp;
    tmp = pc; pc = pn; pn = tmp;
  }
  out_mfma_kernel<<<N_NODES / 16, 256, 0, stream>>>(hc, pc, owTb, ecb, efb,
                                                    (float*)d_out);
}